// Round 2
// baseline (735.482 us; speedup 1.0000x reference)
//
#include <hip/hip_runtime.h>
#include <hip/hip_bf16.h>
#include <math.h>

#define NN_DIN 512
#define NN_HF  256
#define NN_H   8
#define NN_F   32
#define NN_C   40

// ---------------- GEMM1: h1 = x @ W1   (M x 512)(512 x 256) ----------------
#define T1M 64
#define T1N 64
#define T1K 32

__global__ __launch_bounds__(256) void gemm1_kernel(
    const float* __restrict__ A, const float* __restrict__ B,
    float* __restrict__ C, int M)
{
    __shared__ float As[T1K][T1M + 4];   // transposed: As[k][m]
    __shared__ float Bs[T1K][T1N + 4];
    const int K = NN_DIN, N = NN_HF;
    int m0 = blockIdx.x * T1M;
    int n0 = blockIdx.y * T1N;
    int tid = threadIdx.x;
    int tm = tid >> 4, tn = tid & 15;
    float acc[4][4] = {};
    for (int k0 = 0; k0 < K; k0 += T1K) {
        #pragma unroll
        for (int i = 0; i < 2; ++i) {
            int g = tid + i * 256;          // 512 float4 groups of A tile
            int m = g >> 3;                 // 0..63
            int k4 = (g & 7) << 2;          // 0,4,..,28
            float4 v = make_float4(0.f, 0.f, 0.f, 0.f);
            if (m0 + m < M) v = *(const float4*)(A + (size_t)(m0 + m) * K + k0 + k4);
            As[k4 + 0][m] = v.x; As[k4 + 1][m] = v.y;
            As[k4 + 2][m] = v.z; As[k4 + 3][m] = v.w;
        }
        #pragma unroll
        for (int i = 0; i < 2; ++i) {
            int g = tid + i * 256;          // 512 float4 groups of B tile
            int k = g >> 4;                 // 0..31
            int n4 = (g & 15) << 2;         // 0..60
            *(float4*)&Bs[k][n4] = *(const float4*)(B + (size_t)(k0 + k) * N + n0 + n4);
        }
        __syncthreads();
        #pragma unroll
        for (int kk = 0; kk < T1K; ++kk) {
            float4 av = *(const float4*)&As[kk][tm << 2];
            float4 bv = *(const float4*)&Bs[kk][tn << 2];
            float a[4] = {av.x, av.y, av.z, av.w};
            float b[4] = {bv.x, bv.y, bv.z, bv.w};
            #pragma unroll
            for (int i = 0; i < 4; ++i)
                #pragma unroll
                for (int j = 0; j < 4; ++j) acc[i][j] += a[i] * b[j];
        }
        __syncthreads();
    }
    #pragma unroll
    for (int i = 0; i < 4; ++i) {
        int m = m0 + (tm << 2) + i;
        if (m < M) {
            #pragma unroll
            for (int j = 0; j < 4; ++j)
                C[(size_t)m * N + n0 + (tn << 2) + j] = acc[i][j];
        }
    }
}

// ---------------- attention coefficients layer 1 ----------------
__global__ __launch_bounds__(256) void attn1_kernel(
    const float* __restrict__ h1, const float* __restrict__ att_s,
    const float* __restrict__ att_d, float* __restrict__ a1s,
    float* __restrict__ a1d)
{
    int n = blockIdx.x;
    int t = threadIdx.x;            // t = h*32 + f
    float hv = h1[(size_t)n * NN_HF + t];
    float ps = hv * att_s[t];
    float pd = hv * att_d[t];
    #pragma unroll
    for (int off = 16; off >= 1; off >>= 1) {
        ps += __shfl_down(ps, off, 32);
        pd += __shfl_down(pd, off, 32);
    }
    if ((t & 31) == 0) {
        a1s[n * NN_H + (t >> 5)] = ps;
        a1d[n * NN_H + (t >> 5)] = pd;
    }
}

// ---------------- CSR build ----------------
__global__ void count_kernel(const int* __restrict__ dst, int* __restrict__ deg,
                             int E, int Nn)
{
    int e = blockIdx.x * blockDim.x + threadIdx.x;
    int Et = E + Nn;
    if (e >= Et) return;
    int d = (e < E) ? dst[e] : (e - E);     // self-loops appended
    atomicAdd(&deg[d], 1);
}

#define SCAN_CHUNK 1024
__global__ __launch_bounds__(256) void scan1_kernel(
    const int* __restrict__ deg, int* __restrict__ offs,
    int* __restrict__ bsums, int Nn)
{
    __shared__ int sh[256];
    int b = blockIdx.x, t = threadIdx.x;
    int base = b * SCAN_CHUNK + t * 4;
    int v[4];
    int tot = 0;
    #pragma unroll
    for (int i = 0; i < 4; ++i) {
        v[i] = (base + i < Nn) ? deg[base + i] : 0;
        tot += v[i];
    }
    sh[t] = tot;
    __syncthreads();
    for (int off = 1; off < 256; off <<= 1) {
        int y = (t >= off) ? sh[t - off] : 0;
        __syncthreads();
        sh[t] += y;
        __syncthreads();
    }
    int p = sh[t] - tot;   // exclusive base within chunk
    #pragma unroll
    for (int i = 0; i < 4; ++i) {
        if (base + i < Nn) offs[base + i] = p;
        p += v[i];
    }
    if (t == 255) bsums[b] = sh[255];
}

__global__ void scan2_kernel(int* __restrict__ bsums, int nb)
{
    if (threadIdx.x == 0) {
        int run = 0;
        for (int i = 0; i < nb; ++i) {
            int tmp = bsums[i];
            bsums[i] = run;
            run += tmp;
        }
    }
}

__global__ void scan3_kernel(int* __restrict__ offs, const int* __restrict__ bsums,
                             int Nn, int Et)
{
    int i = blockIdx.x * blockDim.x + threadIdx.x;
    if (i < Nn) offs[i] += bsums[i >> 10];
    if (i == 0) offs[Nn] = Et;
}

__global__ void fill_kernel(const int* __restrict__ src, const int* __restrict__ dst,
                            const int* __restrict__ offs, int* __restrict__ cursor,
                            int* __restrict__ srcs, int E, int Nn)
{
    int e = blockIdx.x * blockDim.x + threadIdx.x;
    int Et = E + Nn;
    if (e >= Et) return;
    int d, s;
    if (e < E) { d = dst[e]; s = src[e]; }
    else       { d = e - E;  s = e - E;  }
    int pos = offs[d] + atomicAdd(&cursor[d], 1);
    srcs[pos] = s;
}

// ---------------- layer-1 aggregate: online softmax + gather + bias + ELU ----------------
__global__ __launch_bounds__(256) void agg1_kernel(
    const float* __restrict__ h1, const float* __restrict__ a1s,
    const float* __restrict__ a1d, const int* __restrict__ offs,
    const int* __restrict__ srcs, const float* __restrict__ b1,
    float* __restrict__ hp1)
{
    int n = blockIdx.x;
    int t = threadIdx.x;            // t = h*32 + f
    int h = t >> 5;
    float adn = a1d[n * NN_H + h];
    int beg = offs[n], end = offs[n + 1];
    float m = -INFINITY, s = 0.f, acc = 0.f;
    for (int k = beg; k < end; ++k) {
        int sN = srcs[k];
        float e = a1s[sN * NN_H + h] + adn;
        e = e > 0.f ? e : 0.2f * e;                 // leaky_relu 0.2
        float hv = h1[(size_t)sN * NN_HF + t];
        float nm = fmaxf(m, e);
        float scale = __expf(m - nm);               // exp(-inf)=0 on first iter
        float w = __expf(e - nm);
        s = s * scale + w;
        acc = acc * scale + w * hv;
        m = nm;
    }
    float v = acc / (s + 1e-16f) + b1[t];
    v = v > 0.f ? v : __expf(v) - 1.f;              // ELU
    hp1[(size_t)n * NN_HF + t] = v;
}

// ---------------- GEMM2: h2 = hp1 @ W2  (M x 256)(256 x 40), fused a2s/a2d ----------------
#define G2_ROWS 64
#define G2_KC   64

__global__ __launch_bounds__(256) void gemm2_kernel(
    const float* __restrict__ A, const float* __restrict__ W2,
    const float* __restrict__ att_s, const float* __restrict__ att_d,
    float* __restrict__ h2, float* __restrict__ a2s, float* __restrict__ a2d,
    int M)
{
    __shared__ float As[G2_ROWS][G2_KC + 1];   // 64 x 65
    __shared__ float Ws[G2_KC][NN_C];          // 64 x 40
    int m0 = blockIdx.x * G2_ROWS;
    int t = threadIdx.x;
    int rp = t >> 3;            // 0..31 -> rows 2*rp, 2*rp+1
    int cg = t & 7;             // col group: 5 cols
    int c0 = cg * 5;
    int r0 = rp * 2, r1 = r0 + 1;
    float acc[2][5] = {};
    for (int kc = 0; kc < NN_HF; kc += G2_KC) {
        // load A chunk: 64 rows x 64 cols
        #pragma unroll
        for (int i = 0; i < 4; ++i) {
            int g = t + i * 256;            // 0..1023 float4 groups
            int r = g >> 4;
            int k4 = (g & 15) << 2;
            float4 v = make_float4(0.f, 0.f, 0.f, 0.f);
            if (m0 + r < M) v = *(const float4*)(A + (size_t)(m0 + r) * NN_HF + kc + k4);
            As[r][k4 + 0] = v.x; As[r][k4 + 1] = v.y;
            As[r][k4 + 2] = v.z; As[r][k4 + 3] = v.w;
        }
        // load W chunk: 64 x 40 = 2560
        #pragma unroll
        for (int i = 0; i < 10; ++i) {
            int g = t + i * 256;
            int k = g / NN_C, c = g % NN_C;
            Ws[k][c] = W2[(size_t)(kc + k) * NN_C + c];
        }
        __syncthreads();
        #pragma unroll 4
        for (int k = 0; k < G2_KC; ++k) {
            float a0 = As[r0][k];
            float a1 = As[r1][k];
            #pragma unroll
            for (int j = 0; j < 5; ++j) {
                float w = Ws[k][c0 + j];
                acc[0][j] += a0 * w;
                acc[1][j] += a1 * w;
            }
        }
        __syncthreads();
    }
    #pragma unroll
    for (int i = 0; i < 2; ++i) {
        int m = m0 + r0 + i;
        float ps = 0.f, pd = 0.f;
        #pragma unroll
        for (int j = 0; j < 5; ++j) {
            float v = acc[i][j];
            ps += v * att_s[c0 + j];
            pd += v * att_d[c0 + j];
            if (m < M) h2[(size_t)m * NN_C + c0 + j] = v;
        }
        #pragma unroll
        for (int off = 4; off >= 1; off >>= 1) {
            ps += __shfl_down(ps, off, 8);
            pd += __shfl_down(pd, off, 8);
        }
        if (cg == 0 && m < M) { a2s[m] = ps; a2d[m] = pd; }
    }
}

// ---------------- layer-2 aggregate + bias + log_softmax ----------------
__global__ __launch_bounds__(64) void agg2_kernel(
    const float* __restrict__ h2, const float* __restrict__ a2s,
    const float* __restrict__ a2d, const int* __restrict__ offs,
    const int* __restrict__ srcs, const float* __restrict__ b2,
    float* __restrict__ out)
{
    int n = blockIdx.x;
    int f = threadIdx.x;            // 0..63, active f<40
    float adn = a2d[n];
    int beg = offs[n], end = offs[n + 1];
    float m = -INFINITY, s = 0.f, acc = 0.f;
    for (int k = beg; k < end; ++k) {
        int sN = srcs[k];
        float e = a2s[sN] + adn;
        e = e > 0.f ? e : 0.2f * e;
        float hv = (f < NN_C) ? h2[(size_t)sN * NN_C + f] : 0.f;
        float nm = fmaxf(m, e);
        float scale = __expf(m - nm);
        float w = __expf(e - nm);
        s = s * scale + w;
        acc = acc * scale + w * hv;
        m = nm;
    }
    float v = acc / (s + 1e-16f) + ((f < NN_C) ? b2[f] : 0.f);
    float lg = (f < NN_C) ? v : -INFINITY;
    float mx = lg;
    #pragma unroll
    for (int off = 32; off >= 1; off >>= 1) mx = fmaxf(mx, __shfl_xor(mx, off));
    float w2 = (f < NN_C) ? __expf(lg - mx) : 0.f;
    float sum = w2;
    #pragma unroll
    for (int off = 32; off >= 1; off >>= 1) sum += __shfl_xor(sum, off);
    if (f < NN_C) out[(size_t)n * NN_C + f] = lg - mx - __logf(sum);
}

// ---------------- launcher ----------------
extern "C" void kernel_launch(void* const* d_in, const int* in_sizes, int n_in,
                              void* d_out, int out_size, void* d_ws, size_t ws_size,
                              hipStream_t stream)
{
    const float* x    = (const float*)d_in[0];
    const int*   ei   = (const int*)d_in[1];
    const float* W1   = (const float*)d_in[2];
    const float* as1  = (const float*)d_in[3];
    const float* ad1  = (const float*)d_in[4];
    const float* b1   = (const float*)d_in[5];
    const float* W2   = (const float*)d_in[6];
    const float* as2  = (const float*)d_in[7];
    const float* ad2  = (const float*)d_in[8];
    const float* b2   = (const float*)d_in[9];
    float* out = (float*)d_out;

    int Nn = in_sizes[0] / NN_DIN;      // 50000
    int E  = in_sizes[1] / 2;           // 800000
    int Et = E + Nn;
    const int* srcIdx = ei;
    const int* dstIdx = ei + E;

    char* ws = (char*)d_ws;
    size_t off = 0;
    auto alloc = [&](size_t bytes) {
        void* p = ws + off;
        off = (off + bytes + 255) & ~(size_t)255;
        return p;
    };
    float* h1   = (float*)alloc((size_t)Nn * NN_HF * 4);
    float* hp1  = (float*)alloc((size_t)Nn * NN_HF * 4);
    float* a1s  = (float*)alloc((size_t)Nn * NN_H * 4);
    float* a1d  = (float*)alloc((size_t)Nn * NN_H * 4);
    float* h2   = (float*)alloc((size_t)Nn * NN_C * 4);
    float* a2s  = (float*)alloc((size_t)Nn * 4);
    float* a2d  = (float*)alloc((size_t)Nn * 4);
    int*   deg  = (int*)alloc((size_t)Nn * 4);
    int*   offs = (int*)alloc((size_t)(Nn + 1) * 4);
    int*   bsums= (int*)alloc(1024 * 4);
    int*   curs = (int*)alloc((size_t)Nn * 4);
    int*   srcs = (int*)alloc((size_t)Et * 4);

    hipMemsetAsync(deg, 0, (size_t)Nn * 4, stream);
    hipMemsetAsync(curs, 0, (size_t)Nn * 4, stream);

    // GEMM1
    dim3 g1((Nn + T1M - 1) / T1M, NN_HF / T1N);
    gemm1_kernel<<<g1, 256, 0, stream>>>(x, W1, h1, Nn);

    // attention coefficients
    attn1_kernel<<<Nn, 256, 0, stream>>>(h1, as1, ad1, a1s, a1d);

    // CSR build
    count_kernel<<<(Et + 255) / 256, 256, 0, stream>>>(dstIdx, deg, E, Nn);
    int nb = (Nn + SCAN_CHUNK - 1) / SCAN_CHUNK;
    scan1_kernel<<<nb, 256, 0, stream>>>(deg, offs, bsums, Nn);
    scan2_kernel<<<1, 64, 0, stream>>>(bsums, nb);
    scan3_kernel<<<(Nn + 255) / 256, 256, 0, stream>>>(offs, bsums, Nn, Et);
    fill_kernel<<<(Et + 255) / 256, 256, 0, stream>>>(srcIdx, dstIdx, offs, curs, srcs, E, Nn);

    // layer-1 aggregate (+bias+ELU)
    agg1_kernel<<<Nn, 256, 0, stream>>>(h1, a1s, a1d, offs, srcs, b1, hp1);

    // GEMM2 (+fused a2s/a2d)
    gemm2_kernel<<<(Nn + G2_ROWS - 1) / G2_ROWS, 256, 0, stream>>>(
        hp1, W2, as2, ad2, h2, a2s, a2d, Nn);

    // layer-2 aggregate + bias + log_softmax
    agg2_kernel<<<Nn, 64, 0, stream>>>(h2, a2s, a2d, offs, srcs, b2, out);
}

// Round 3
// 656.846 us; speedup vs baseline: 1.1197x; 1.1197x over previous
//
#include <hip/hip_runtime.h>
#include <hip/hip_bf16.h>
#include <math.h>

#define NN_DIN 512
#define NN_HF  256
#define NN_H   8
#define NN_F   32
#define NN_C   40

typedef short bf16x8 __attribute__((ext_vector_type(8)));
typedef float f32x4 __attribute__((ext_vector_type(4)));

__device__ __forceinline__ unsigned short f2bf_rne(float x) {
    unsigned u = __builtin_bit_cast(unsigned, x);
    unsigned r = u + 0x7FFFu + ((u >> 16) & 1u);
    return (unsigned short)(r >> 16);
}
__device__ __forceinline__ float bfu2f(unsigned short s) {
    unsigned u = ((unsigned)s) << 16;
    return __builtin_bit_cast(float, u);
}
// truncation split: x ~= hi + lo with |err| <= 2^-16 |x|
__device__ __forceinline__ void fsplit(float x, unsigned short& hi, unsigned short& lo) {
    unsigned u = __builtin_bit_cast(unsigned, x);
    hi = (unsigned short)(u >> 16);
    float hif = __builtin_bit_cast(float, u & 0xFFFF0000u);
    float rem = x - hif;
    lo = (unsigned short)(__builtin_bit_cast(unsigned, rem) >> 16);
}

// ---------------- W1 transpose + split: [512][256] f32 -> [256][512] bf16 hi/lo ----
__global__ __launch_bounds__(256) void w1split_kernel(
    const float* __restrict__ W1, unsigned short* __restrict__ Wh,
    unsigned short* __restrict__ Wl)
{
    __shared__ float tile[32][33];
    int bk = blockIdx.x * 32;
    int bn = blockIdx.y * 32;
    int tx = threadIdx.x & 31, ty = threadIdx.x >> 5;   // ty 0..7
    #pragma unroll
    for (int i = 0; i < 32; i += 8)
        tile[ty + i][tx] = W1[(size_t)(bk + ty + i) * NN_HF + bn + tx];
    __syncthreads();
    #pragma unroll
    for (int i = 0; i < 32; i += 8) {
        float v = tile[tx][ty + i];
        unsigned short h, l;
        fsplit(v, h, l);
        Wh[(size_t)(bn + ty + i) * NN_DIN + bk + tx] = h;
        Wl[(size_t)(bn + ty + i) * NN_DIN + bk + tx] = l;
    }
}

// ---------------- GEMM1 (MFMA): h1b = bf16(x @ W1) ----------------
// x: [M][512] f32; W1T hi/lo: [256][512] bf16; out h1b: [M][256] bf16
// 3-term split product: Ah*Bh + Ah*Bl + Al*Bh  (~fp32 accuracy)
#define G1_BM 128
#define G1_BN 128
#define G1_BK 64
#define G1_LDK 72   // padded row length (shorts): stride 144B -> 2-way bank alias (free)

__global__ __launch_bounds__(256) void gemm1_kernel(
    const float* __restrict__ A, const unsigned short* __restrict__ BTh,
    const unsigned short* __restrict__ BTl, unsigned short* __restrict__ Cb, int M)
{
    __shared__ unsigned short Ah[G1_BM][G1_LDK];
    __shared__ unsigned short Al[G1_BM][G1_LDK];
    __shared__ unsigned short Bh[G1_BN][G1_LDK];
    __shared__ unsigned short Bl[G1_BN][G1_LDK];
    const int m0 = blockIdx.x * G1_BM;
    const int n0 = blockIdx.y * G1_BN;
    const int tid = threadIdx.x;
    const int wave = tid >> 6, lane = tid & 63;
    const int wm = wave >> 1, wn = wave & 1;     // 2x2 wave grid, each wave 64x64
    const int lr = lane & 15, lg = lane >> 4;    // frag index, k-group

    f32x4 acc[4][4];
    #pragma unroll
    for (int i = 0; i < 4; ++i)
        #pragma unroll
        for (int j = 0; j < 4; ++j) acc[i][j] = (f32x4){0.f, 0.f, 0.f, 0.f};

    for (int k0 = 0; k0 < NN_DIN; k0 += G1_BK) {
        // stage A: 128x64 f32 -> split bf16 (2048 float4, 8 per thread)
        #pragma unroll
        for (int i = 0; i < 8; ++i) {
            int g = tid + i * 256;
            int m = g >> 4;
            int k4 = (g & 15) << 2;
            float4 v = make_float4(0.f, 0.f, 0.f, 0.f);
            if (m0 + m < M) v = *(const float4*)(A + (size_t)(m0 + m) * NN_DIN + k0 + k4);
            ushort4 hv, lv;
            fsplit(v.x, hv.x, lv.x); fsplit(v.y, hv.y, lv.y);
            fsplit(v.z, hv.z, lv.z); fsplit(v.w, hv.w, lv.w);
            *reinterpret_cast<ushort4*>(&Ah[m][k4]) = hv;
            *reinterpret_cast<ushort4*>(&Al[m][k4]) = lv;
        }
        // stage B: pre-split bf16 rows, contiguous copies (1024 short8 per array)
        #pragma unroll
        for (int i = 0; i < 4; ++i) {
            int g = tid + i * 256;
            int n = g >> 3;
            int k8 = (g & 7) << 3;
            *reinterpret_cast<bf16x8*>(&Bh[n][k8]) =
                *reinterpret_cast<const bf16x8*>(BTh + (size_t)(n0 + n) * NN_DIN + k0 + k8);
            *reinterpret_cast<bf16x8*>(&Bl[n][k8]) =
                *reinterpret_cast<const bf16x8*>(BTl + (size_t)(n0 + n) * NN_DIN + k0 + k8);
        }
        __syncthreads();
        #pragma unroll
        for (int ks = 0; ks < 2; ++ks) {
            const int kb = (ks << 5) + (lg << 3);
            bf16x8 fah[4], fal[4], fbh[4], fbl[4];
            #pragma unroll
            for (int mi = 0; mi < 4; ++mi) {
                int m = (wm << 6) + (mi << 4) + lr;
                fah[mi] = *reinterpret_cast<const bf16x8*>(&Ah[m][kb]);
                fal[mi] = *reinterpret_cast<const bf16x8*>(&Al[m][kb]);
            }
            #pragma unroll
            for (int ni = 0; ni < 4; ++ni) {
                int n = (wn << 6) + (ni << 4) + lr;
                fbh[ni] = *reinterpret_cast<const bf16x8*>(&Bh[n][kb]);
                fbl[ni] = *reinterpret_cast<const bf16x8*>(&Bl[n][kb]);
            }
            #pragma unroll
            for (int mi = 0; mi < 4; ++mi)
                #pragma unroll
                for (int ni = 0; ni < 4; ++ni) {
                    acc[mi][ni] = __builtin_amdgcn_mfma_f32_16x16x32_bf16(
                        fah[mi], fbh[ni], acc[mi][ni], 0, 0, 0);
                    acc[mi][ni] = __builtin_amdgcn_mfma_f32_16x16x32_bf16(
                        fah[mi], fbl[ni], acc[mi][ni], 0, 0, 0);
                    acc[mi][ni] = __builtin_amdgcn_mfma_f32_16x16x32_bf16(
                        fal[mi], fbh[ni], acc[mi][ni], 0, 0, 0);
                }
        }
        __syncthreads();
    }
    // epilogue: C/D frag mapping row=(lane>>4)*4+r, col=lane&15
    #pragma unroll
    for (int mi = 0; mi < 4; ++mi)
        #pragma unroll
        for (int ni = 0; ni < 4; ++ni)
            #pragma unroll
            for (int r = 0; r < 4; ++r) {
                int row = m0 + (wm << 6) + (mi << 4) + (lg << 2) + r;
                int col = n0 + (wn << 6) + (ni << 4) + lr;
                if (row < M)
                    Cb[(size_t)row * NN_HF + col] = f2bf_rne(acc[mi][ni][r]);
            }
}

// ---------------- attention coefficients layer 1 (reads bf16 h1) ----------------
__global__ __launch_bounds__(256) void attn1_kernel(
    const unsigned short* __restrict__ h1b, const float* __restrict__ att_s,
    const float* __restrict__ att_d, float* __restrict__ a1s,
    float* __restrict__ a1d)
{
    int n = blockIdx.x;
    int t = threadIdx.x;            // t = h*32 + f
    float hv = bfu2f(h1b[(size_t)n * NN_HF + t]);
    float ps = hv * att_s[t];
    float pd = hv * att_d[t];
    #pragma unroll
    for (int off = 16; off >= 1; off >>= 1) {
        ps += __shfl_down(ps, off, 32);
        pd += __shfl_down(pd, off, 32);
    }
    if ((t & 31) == 0) {
        a1s[n * NN_H + (t >> 5)] = ps;
        a1d[n * NN_H + (t >> 5)] = pd;
    }
}

// ---------------- CSR build ----------------
__global__ void count_kernel(const int* __restrict__ dst, int* __restrict__ deg,
                             int E, int Nn)
{
    int e = blockIdx.x * blockDim.x + threadIdx.x;
    int Et = E + Nn;
    if (e >= Et) return;
    int d = (e < E) ? dst[e] : (e - E);     // self-loops appended
    atomicAdd(&deg[d], 1);
}

#define SCAN_CHUNK 1024
__global__ __launch_bounds__(256) void scan1_kernel(
    const int* __restrict__ deg, int* __restrict__ offs,
    int* __restrict__ bsums, int Nn)
{
    __shared__ int sh[256];
    int b = blockIdx.x, t = threadIdx.x;
    int base = b * SCAN_CHUNK + t * 4;
    int v[4];
    int tot = 0;
    #pragma unroll
    for (int i = 0; i < 4; ++i) {
        v[i] = (base + i < Nn) ? deg[base + i] : 0;
        tot += v[i];
    }
    sh[t] = tot;
    __syncthreads();
    for (int off = 1; off < 256; off <<= 1) {
        int y = (t >= off) ? sh[t - off] : 0;
        __syncthreads();
        sh[t] += y;
        __syncthreads();
    }
    int p = sh[t] - tot;
    #pragma unroll
    for (int i = 0; i < 4; ++i) {
        if (base + i < Nn) offs[base + i] = p;
        p += v[i];
    }
    if (t == 255) bsums[b] = sh[255];
}

__global__ void scan2_kernel(int* __restrict__ bsums, int nb)
{
    if (threadIdx.x == 0) {
        int run = 0;
        for (int i = 0; i < nb; ++i) {
            int tmp = bsums[i];
            bsums[i] = run;
            run += tmp;
        }
    }
}

__global__ void scan3_kernel(int* __restrict__ offs, const int* __restrict__ bsums,
                             int Nn, int Et)
{
    int i = blockIdx.x * blockDim.x + threadIdx.x;
    if (i < Nn) offs[i] += bsums[i >> 10];
    if (i == 0) offs[Nn] = Et;
}

__global__ void fill_kernel(const int* __restrict__ src, const int* __restrict__ dst,
                            const int* __restrict__ offs, int* __restrict__ cursor,
                            int* __restrict__ srcs, int E, int Nn)
{
    int e = blockIdx.x * blockDim.x + threadIdx.x;
    int Et = E + Nn;
    if (e >= Et) return;
    int d, s;
    if (e < E) { d = dst[e]; s = src[e]; }
    else       { d = e - E;  s = e - E;  }
    int pos = offs[d] + atomicAdd(&cursor[d], 1);
    srcs[pos] = s;
}

// ---------------- layer-1 aggregate: online softmax + bf16 gather + bias + ELU ----
__global__ __launch_bounds__(256) void agg1_kernel(
    const unsigned short* __restrict__ h1b, const float* __restrict__ a1s,
    const float* __restrict__ a1d, const int* __restrict__ offs,
    const int* __restrict__ srcs, const float* __restrict__ b1,
    float* __restrict__ hp1)
{
    int n = blockIdx.x;
    int t = threadIdx.x;            // t = h*32 + f
    int h = t >> 5;
    float adn = a1d[n * NN_H + h];
    int beg = offs[n], end = offs[n + 1];
    float m = -INFINITY, s = 0.f, acc = 0.f;
    for (int k = beg; k < end; ++k) {
        int sN = srcs[k];
        float e = a1s[sN * NN_H + h] + adn;
        e = e > 0.f ? e : 0.2f * e;                 // leaky_relu 0.2
        float hv = bfu2f(h1b[(size_t)sN * NN_HF + t]);
        float nm = fmaxf(m, e);
        float scale = __expf(m - nm);               // exp(-inf)=0 on first iter
        float w = __expf(e - nm);
        s = s * scale + w;
        acc = acc * scale + w * hv;
        m = nm;
    }
    float v = acc / (s + 1e-16f) + b1[t];
    v = v > 0.f ? v : __expf(v) - 1.f;              // ELU
    hp1[(size_t)n * NN_HF + t] = v;
}

// ---------------- GEMM2: h2 = hp1 @ W2  (M x 256)(256 x 40), fused a2s/a2d ----------------
#define G2_ROWS 64
#define G2_KC   64

__global__ __launch_bounds__(256) void gemm2_kernel(
    const float* __restrict__ A, const float* __restrict__ W2,
    const float* __restrict__ att_s, const float* __restrict__ att_d,
    float* __restrict__ h2, float* __restrict__ a2s, float* __restrict__ a2d,
    int M)
{
    __shared__ float As[G2_ROWS][G2_KC + 1];
    __shared__ float Ws[G2_KC][NN_C];
    int m0 = blockIdx.x * G2_ROWS;
    int t = threadIdx.x;
    int rp = t >> 3;
    int cg = t & 7;
    int c0 = cg * 5;
    int r0 = rp * 2, r1 = r0 + 1;
    float acc[2][5] = {};
    for (int kc = 0; kc < NN_HF; kc += G2_KC) {
        #pragma unroll
        for (int i = 0; i < 4; ++i) {
            int g = t + i * 256;
            int r = g >> 4;
            int k4 = (g & 15) << 2;
            float4 v = make_float4(0.f, 0.f, 0.f, 0.f);
            if (m0 + r < M) v = *(const float4*)(A + (size_t)(m0 + r) * NN_HF + kc + k4);
            As[r][k4 + 0] = v.x; As[r][k4 + 1] = v.y;
            As[r][k4 + 2] = v.z; As[r][k4 + 3] = v.w;
        }
        #pragma unroll
        for (int i = 0; i < 10; ++i) {
            int g = t + i * 256;
            int k = g / NN_C, c = g % NN_C;
            Ws[k][c] = W2[(size_t)(kc + k) * NN_C + c];
        }
        __syncthreads();
        #pragma unroll 4
        for (int k = 0; k < G2_KC; ++k) {
            float a0 = As[r0][k];
            float a1 = As[r1][k];
            #pragma unroll
            for (int j = 0; j < 5; ++j) {
                float w = Ws[k][c0 + j];
                acc[0][j] += a0 * w;
                acc[1][j] += a1 * w;
            }
        }
        __syncthreads();
    }
    #pragma unroll
    for (int i = 0; i < 2; ++i) {
        int m = m0 + r0 + i;
        float ps = 0.f, pd = 0.f;
        #pragma unroll
        for (int j = 0; j < 5; ++j) {
            float v = acc[i][j];
            ps += v * att_s[c0 + j];
            pd += v * att_d[c0 + j];
            if (m < M) h2[(size_t)m * NN_C + c0 + j] = v;
        }
        #pragma unroll
        for (int off = 4; off >= 1; off >>= 1) {
            ps += __shfl_down(ps, off, 8);
            pd += __shfl_down(pd, off, 8);
        }
        if (cg == 0 && m < M) { a2s[m] = ps; a2d[m] = pd; }
    }
}

// ---------------- layer-2 aggregate + bias + log_softmax ----------------
__global__ __launch_bounds__(64) void agg2_kernel(
    const float* __restrict__ h2, const float* __restrict__ a2s,
    const float* __restrict__ a2d, const int* __restrict__ offs,
    const int* __restrict__ srcs, const float* __restrict__ b2,
    float* __restrict__ out)
{
    int n = blockIdx.x;
    int f = threadIdx.x;
    float adn = a2d[n];
    int beg = offs[n], end = offs[n + 1];
    float m = -INFINITY, s = 0.f, acc = 0.f;
    for (int k = beg; k < end; ++k) {
        int sN = srcs[k];
        float e = a2s[sN] + adn;
        e = e > 0.f ? e : 0.2f * e;
        float hv = (f < NN_C) ? h2[(size_t)sN * NN_C + f] : 0.f;
        float nm = fmaxf(m, e);
        float scale = __expf(m - nm);
        float w = __expf(e - nm);
        s = s * scale + w;
        acc = acc * scale + w * hv;
        m = nm;
    }
    float v = acc / (s + 1e-16f) + ((f < NN_C) ? b2[f] : 0.f);
    float lg = (f < NN_C) ? v : -INFINITY;
    float mx = lg;
    #pragma unroll
    for (int off = 32; off >= 1; off >>= 1) mx = fmaxf(mx, __shfl_xor(mx, off));
    float w2 = (f < NN_C) ? __expf(lg - mx) : 0.f;
    float sum = w2;
    #pragma unroll
    for (int off = 32; off >= 1; off >>= 1) sum += __shfl_xor(sum, off);
    if (f < NN_C) out[(size_t)n * NN_C + f] = lg - mx - __logf(sum);
}

// ---------------- launcher ----------------
extern "C" void kernel_launch(void* const* d_in, const int* in_sizes, int n_in,
                              void* d_out, int out_size, void* d_ws, size_t ws_size,
                              hipStream_t stream)
{
    const float* x    = (const float*)d_in[0];
    const int*   ei   = (const int*)d_in[1];
    const float* W1   = (const float*)d_in[2];
    const float* as1  = (const float*)d_in[3];
    const float* ad1  = (const float*)d_in[4];
    const float* b1   = (const float*)d_in[5];
    const float* W2   = (const float*)d_in[6];
    const float* as2  = (const float*)d_in[7];
    const float* ad2  = (const float*)d_in[8];
    const float* b2   = (const float*)d_in[9];
    float* out = (float*)d_out;

    int Nn = in_sizes[0] / NN_DIN;      // 50000
    int E  = in_sizes[1] / 2;           // 800000
    int Et = E + Nn;
    const int* srcIdx = ei;
    const int* dstIdx = ei + E;

    char* ws = (char*)d_ws;
    size_t off = 0;
    auto alloc = [&](size_t bytes) {
        void* p = ws + off;
        off = (off + bytes + 255) & ~(size_t)255;
        return p;
    };
    unsigned short* h1b  = (unsigned short*)alloc((size_t)Nn * NN_HF * 2);
    unsigned short* W1Th = (unsigned short*)alloc((size_t)NN_HF * NN_DIN * 2);
    unsigned short* W1Tl = (unsigned short*)alloc((size_t)NN_HF * NN_DIN * 2);
    float* hp1  = (float*)alloc((size_t)Nn * NN_HF * 4);
    float* a1s  = (float*)alloc((size_t)Nn * NN_H * 4);
    float* a1d  = (float*)alloc((size_t)Nn * NN_H * 4);
    float* h2   = (float*)alloc((size_t)Nn * NN_C * 4);
    float* a2s  = (float*)alloc((size_t)Nn * 4);
    float* a2d  = (float*)alloc((size_t)Nn * 4);
    int*   deg  = (int*)alloc((size_t)Nn * 4);
    int*   offs = (int*)alloc((size_t)(Nn + 1) * 4);
    int*   bsums= (int*)alloc(1024 * 4);
    int*   curs = (int*)alloc((size_t)Nn * 4);
    int*   srcs = (int*)alloc((size_t)Et * 4);

    hipMemsetAsync(deg, 0, (size_t)Nn * 4, stream);
    hipMemsetAsync(curs, 0, (size_t)Nn * 4, stream);

    // W1 transpose + split (one pass, 0.5 MB)
    w1split_kernel<<<dim3(NN_DIN / 32, NN_HF / 32), 256, 0, stream>>>(W1, W1Th, W1Tl);

    // GEMM1 (MFMA, split-bf16) -> h1b
    dim3 g1((Nn + G1_BM - 1) / G1_BM, NN_HF / G1_BN);
    gemm1_kernel<<<g1, 256, 0, stream>>>(x, W1Th, W1Tl, h1b, Nn);

    // attention coefficients
    attn1_kernel<<<Nn, 256, 0, stream>>>(h1b, as1, ad1, a1s, a1d);

    // CSR build
    count_kernel<<<(Et + 255) / 256, 256, 0, stream>>>(dstIdx, deg, E, Nn);
    int nb = (Nn + SCAN_CHUNK - 1) / SCAN_CHUNK;
    scan1_kernel<<<nb, 256, 0, stream>>>(deg, offs, bsums, Nn);
    scan2_kernel<<<1, 64, 0, stream>>>(bsums, nb);
    scan3_kernel<<<(Nn + 255) / 256, 256, 0, stream>>>(offs, bsums, Nn, Et);
    fill_kernel<<<(Et + 255) / 256, 256, 0, stream>>>(srcIdx, dstIdx, offs, curs, srcs, E, Nn);

    // layer-1 aggregate (+bias+ELU)
    agg1_kernel<<<Nn, 256, 0, stream>>>(h1b, a1s, a1d, offs, srcs, b1, hp1);

    // GEMM2 (+fused a2s/a2d)
    gemm2_kernel<<<(Nn + G2_ROWS - 1) / G2_ROWS, 256, 0, stream>>>(
        hp1, W2, as2, ad2, h2, a2s, a2d, Nn);

    // layer-2 aggregate + bias + log_softmax
    agg2_kernel<<<Nn, 64, 0, stream>>>(h2, a2s, a2d, offs, srcs, b2, out);
}

// Round 4
// 656.567 us; speedup vs baseline: 1.1202x; 1.0004x over previous
//
#include <hip/hip_runtime.h>
#include <hip/hip_bf16.h>
#include <math.h>

#define NN_DIN 512
#define NN_HF  256
#define NN_H   8
#define NN_F   32
#define NN_C   40

typedef short bf16x8 __attribute__((ext_vector_type(8)));
typedef float f32x4 __attribute__((ext_vector_type(4)));

__device__ __forceinline__ unsigned short f2bf_rne(float x) {
    unsigned u = __builtin_bit_cast(unsigned, x);
    unsigned r = u + 0x7FFFu + ((u >> 16) & 1u);
    return (unsigned short)(r >> 16);
}
__device__ __forceinline__ float bfu2f(unsigned short s) {
    unsigned u = ((unsigned)s) << 16;
    return __builtin_bit_cast(float, u);
}
// truncation split: x ~= hi + lo with |err| <= 2^-16 |x|
__device__ __forceinline__ void fsplit(float x, unsigned short& hi, unsigned short& lo) {
    unsigned u = __builtin_bit_cast(unsigned, x);
    hi = (unsigned short)(u >> 16);
    float hif = __builtin_bit_cast(float, u & 0xFFFF0000u);
    float rem = x - hif;
    lo = (unsigned short)(__builtin_bit_cast(unsigned, rem) >> 16);
}

// ---------------- W1 transpose + split: [512][256] f32 -> [256][512] bf16 hi/lo ----
__global__ __launch_bounds__(256) void w1split_kernel(
    const float* __restrict__ W1, unsigned short* __restrict__ Wh,
    unsigned short* __restrict__ Wl)
{
    __shared__ float tile[32][33];
    int bk = blockIdx.x * 32;
    int bn = blockIdx.y * 32;
    int tx = threadIdx.x & 31, ty = threadIdx.x >> 5;   // ty 0..7
    #pragma unroll
    for (int i = 0; i < 32; i += 8)
        tile[ty + i][tx] = W1[(size_t)(bk + ty + i) * NN_HF + bn + tx];
    __syncthreads();
    #pragma unroll
    for (int i = 0; i < 32; i += 8) {
        float v = tile[tx][ty + i];
        unsigned short h, l;
        fsplit(v, h, l);
        Wh[(size_t)(bn + ty + i) * NN_DIN + bk + tx] = h;
        Wl[(size_t)(bn + ty + i) * NN_DIN + bk + tx] = l;
    }
}

// ---------------- GEMM1 (MFMA): h1b = bf16(x @ W1) ----------------
#define G1_BM 128
#define G1_BN 128
#define G1_BK 64
#define G1_LDK 72   // padded row length (shorts): stride 144B -> 2-way bank alias (free)

__global__ __launch_bounds__(256) void gemm1_kernel(
    const float* __restrict__ A, const unsigned short* __restrict__ BTh,
    const unsigned short* __restrict__ BTl, unsigned short* __restrict__ Cb, int M)
{
    __shared__ unsigned short Ah[G1_BM][G1_LDK];
    __shared__ unsigned short Al[G1_BM][G1_LDK];
    __shared__ unsigned short Bh[G1_BN][G1_LDK];
    __shared__ unsigned short Bl[G1_BN][G1_LDK];
    const int m0 = blockIdx.x * G1_BM;
    const int n0 = blockIdx.y * G1_BN;
    const int tid = threadIdx.x;
    const int wave = tid >> 6, lane = tid & 63;
    const int wm = wave >> 1, wn = wave & 1;     // 2x2 wave grid, each wave 64x64
    const int lr = lane & 15, lg = lane >> 4;    // frag index, k-group

    f32x4 acc[4][4];
    #pragma unroll
    for (int i = 0; i < 4; ++i)
        #pragma unroll
        for (int j = 0; j < 4; ++j) acc[i][j] = (f32x4){0.f, 0.f, 0.f, 0.f};

    for (int k0 = 0; k0 < NN_DIN; k0 += G1_BK) {
        #pragma unroll
        for (int i = 0; i < 8; ++i) {
            int g = tid + i * 256;
            int m = g >> 4;
            int k4 = (g & 15) << 2;
            float4 v = make_float4(0.f, 0.f, 0.f, 0.f);
            if (m0 + m < M) v = *(const float4*)(A + (size_t)(m0 + m) * NN_DIN + k0 + k4);
            ushort4 hv, lv;
            fsplit(v.x, hv.x, lv.x); fsplit(v.y, hv.y, lv.y);
            fsplit(v.z, hv.z, lv.z); fsplit(v.w, hv.w, lv.w);
            *reinterpret_cast<ushort4*>(&Ah[m][k4]) = hv;
            *reinterpret_cast<ushort4*>(&Al[m][k4]) = lv;
        }
        #pragma unroll
        for (int i = 0; i < 4; ++i) {
            int g = tid + i * 256;
            int n = g >> 3;
            int k8 = (g & 7) << 3;
            *reinterpret_cast<bf16x8*>(&Bh[n][k8]) =
                *reinterpret_cast<const bf16x8*>(BTh + (size_t)(n0 + n) * NN_DIN + k0 + k8);
            *reinterpret_cast<bf16x8*>(&Bl[n][k8]) =
                *reinterpret_cast<const bf16x8*>(BTl + (size_t)(n0 + n) * NN_DIN + k0 + k8);
        }
        __syncthreads();
        #pragma unroll
        for (int ks = 0; ks < 2; ++ks) {
            const int kb = (ks << 5) + (lg << 3);
            bf16x8 fah[4], fal[4], fbh[4], fbl[4];
            #pragma unroll
            for (int mi = 0; mi < 4; ++mi) {
                int m = (wm << 6) + (mi << 4) + lr;
                fah[mi] = *reinterpret_cast<const bf16x8*>(&Ah[m][kb]);
                fal[mi] = *reinterpret_cast<const bf16x8*>(&Al[m][kb]);
            }
            #pragma unroll
            for (int ni = 0; ni < 4; ++ni) {
                int n = (wn << 6) + (ni << 4) + lr;
                fbh[ni] = *reinterpret_cast<const bf16x8*>(&Bh[n][kb]);
                fbl[ni] = *reinterpret_cast<const bf16x8*>(&Bl[n][kb]);
            }
            #pragma unroll
            for (int mi = 0; mi < 4; ++mi)
                #pragma unroll
                for (int ni = 0; ni < 4; ++ni) {
                    acc[mi][ni] = __builtin_amdgcn_mfma_f32_16x16x32_bf16(
                        fah[mi], fbh[ni], acc[mi][ni], 0, 0, 0);
                    acc[mi][ni] = __builtin_amdgcn_mfma_f32_16x16x32_bf16(
                        fah[mi], fbl[ni], acc[mi][ni], 0, 0, 0);
                    acc[mi][ni] = __builtin_amdgcn_mfma_f32_16x16x32_bf16(
                        fal[mi], fbh[ni], acc[mi][ni], 0, 0, 0);
                }
        }
        __syncthreads();
    }
    #pragma unroll
    for (int mi = 0; mi < 4; ++mi)
        #pragma unroll
        for (int ni = 0; ni < 4; ++ni)
            #pragma unroll
            for (int r = 0; r < 4; ++r) {
                int row = m0 + (wm << 6) + (mi << 4) + (lg << 2) + r;
                int col = n0 + (wn << 6) + (ni << 4) + lr;
                if (row < M)
                    Cb[(size_t)row * NN_HF + col] = f2bf_rne(acc[mi][ni][r]);
            }
}

// ---------------- attention coefficients layer 1 (reads bf16 h1) ----------------
__global__ __launch_bounds__(256) void attn1_kernel(
    const unsigned short* __restrict__ h1b, const float* __restrict__ att_s,
    const float* __restrict__ att_d, float* __restrict__ a1s,
    float* __restrict__ a1d)
{
    int n = blockIdx.x;
    int t = threadIdx.x;            // t = h*32 + f
    float hv = bfu2f(h1b[(size_t)n * NN_HF + t]);
    float ps = hv * att_s[t];
    float pd = hv * att_d[t];
    #pragma unroll
    for (int off = 16; off >= 1; off >>= 1) {
        ps += __shfl_down(ps, off, 32);
        pd += __shfl_down(pd, off, 32);
    }
    if ((t & 31) == 0) {
        a1s[n * NN_H + (t >> 5)] = ps;
        a1d[n * NN_H + (t >> 5)] = pd;
    }
}

// ---------------- CSR build ----------------
__global__ void count_kernel(const int* __restrict__ dst, int* __restrict__ deg,
                             int E, int Nn)
{
    int e = blockIdx.x * blockDim.x + threadIdx.x;
    int Et = E + Nn;
    if (e >= Et) return;
    int d = (e < E) ? dst[e] : (e - E);     // self-loops appended
    atomicAdd(&deg[d], 1);
}

#define SCAN_CHUNK 1024
__global__ __launch_bounds__(256) void scan1_kernel(
    const int* __restrict__ deg, int* __restrict__ offs,
    int* __restrict__ bsums, int Nn)
{
    __shared__ int sh[256];
    int b = blockIdx.x, t = threadIdx.x;
    int base = b * SCAN_CHUNK + t * 4;
    int v[4];
    int tot = 0;
    #pragma unroll
    for (int i = 0; i < 4; ++i) {
        v[i] = (base + i < Nn) ? deg[base + i] : 0;
        tot += v[i];
    }
    sh[t] = tot;
    __syncthreads();
    for (int off = 1; off < 256; off <<= 1) {
        int y = (t >= off) ? sh[t - off] : 0;
        __syncthreads();
        sh[t] += y;
        __syncthreads();
    }
    int p = sh[t] - tot;
    #pragma unroll
    for (int i = 0; i < 4; ++i) {
        if (base + i < Nn) offs[base + i] = p;
        p += v[i];
    }
    if (t == 255) bsums[b] = sh[255];
}

__global__ void scan2_kernel(int* __restrict__ bsums, int nb)
{
    if (threadIdx.x == 0) {
        int run = 0;
        for (int i = 0; i < nb; ++i) {
            int tmp = bsums[i];
            bsums[i] = run;
            run += tmp;
        }
    }
}

__global__ void scan3_kernel(int* __restrict__ offs, const int* __restrict__ bsums,
                             int Nn, int Et)
{
    int i = blockIdx.x * blockDim.x + threadIdx.x;
    if (i < Nn) offs[i] += bsums[i >> 10];
    if (i == 0) offs[Nn] = Et;
}

__global__ void fill_kernel(const int* __restrict__ src, const int* __restrict__ dst,
                            const int* __restrict__ offs, int* __restrict__ cursor,
                            int* __restrict__ srcs, int E, int Nn)
{
    int e = blockIdx.x * blockDim.x + threadIdx.x;
    int Et = E + Nn;
    if (e >= Et) return;
    int d, s;
    if (e < E) { d = dst[e]; s = src[e]; }
    else       { d = e - E;  s = e - E;  }
    int pos = offs[d] + atomicAdd(&cursor[d], 1);
    srcs[pos] = s;
}

// ---------------- layer-1 edge weights: alpha1[k][h] = softmax ----------------
__global__ __launch_bounds__(64) void attw1_kernel(
    const float* __restrict__ a1s, const float* __restrict__ a1d,
    const int* __restrict__ offs, const int* __restrict__ srcs,
    float* __restrict__ alpha1)
{
    int n = blockIdx.x;
    int lane = threadIdx.x;
    int g = lane >> 3, h = lane & 7;        // 8 edge groups x 8 heads
    int beg = offs[n], end = offs[n + 1];
    float adn = a1d[n * NN_H + h];
    float m = -3.0e38f, s = 0.f;
    for (int k = beg + g; k < end; k += 8) {
        int sN = srcs[k];
        float e = a1s[sN * NN_H + h] + adn;
        e = e > 0.f ? e : 0.2f * e;
        float nm = fmaxf(m, e);
        float sc = __expf(m - nm);
        s = s * sc + __expf(e - nm);
        m = nm;
    }
    #pragma unroll
    for (int off = 8; off < 64; off <<= 1) {
        float mo = __shfl_xor(m, off);
        float so = __shfl_xor(s, off);
        float nm = fmaxf(m, mo);
        s = s * __expf(m - nm) + so * __expf(mo - nm);
        m = nm;
    }
    float inv = 1.f / (s + 1e-16f);
    for (int k = beg + g; k < end; k += 8) {
        int sN = srcs[k];
        float e = a1s[sN * NN_H + h] + adn;
        e = e > 0.f ? e : 0.2f * e;
        alpha1[(size_t)k * NN_H + h] = __expf(e - m) * inv;
    }
}

// ---------------- layer-1 aggregate: weighted gather + bias + ELU -> bf16 ----
__global__ __launch_bounds__(256) void agg1_kernel(
    const unsigned short* __restrict__ h1b, const float* __restrict__ alpha1,
    const int* __restrict__ offs, const int* __restrict__ srcs,
    const float* __restrict__ b1, unsigned short* __restrict__ hp1b)
{
    int n = blockIdx.x;
    int t = threadIdx.x;            // t = h*32 + f
    int h = t >> 5;
    int beg = offs[n], end = offs[n + 1];
    float acc = 0.f;
    for (int k = beg; k < end; ++k) {
        int sN = srcs[k];
        float w = alpha1[(size_t)k * NN_H + h];
        float hv = bfu2f(h1b[(size_t)sN * NN_HF + t]);
        acc = fmaf(w, hv, acc);
    }
    float v = acc + b1[t];
    v = v > 0.f ? v : __expf(v) - 1.f;              // ELU
    hp1b[(size_t)n * NN_HF + t] = f2bf_rne(v);
}

// ---------------- GEMM2: h2 = hp1 @ W2  (bf16 in, fp32 math), fused a2s/a2d ----
#define G2_ROWS 64
#define G2_KC   64

__global__ __launch_bounds__(256) void gemm2_kernel(
    const unsigned short* __restrict__ Ab, const float* __restrict__ W2,
    const float* __restrict__ att_s, const float* __restrict__ att_d,
    float* __restrict__ h2, float* __restrict__ a2s, float* __restrict__ a2d,
    int M)
{
    __shared__ float As[G2_ROWS][G2_KC + 1];
    __shared__ float Ws[G2_KC][NN_C];
    int m0 = blockIdx.x * G2_ROWS;
    int t = threadIdx.x;
    int rp = t >> 3;
    int cg = t & 7;
    int c0 = cg * 5;
    int r0 = rp * 2, r1 = r0 + 1;
    float acc[2][5] = {};
    for (int kc = 0; kc < NN_HF; kc += G2_KC) {
        #pragma unroll
        for (int i = 0; i < 4; ++i) {
            int g = t + i * 256;
            int r = g >> 4;
            int k4 = (g & 15) << 2;
            ushort4 v = make_ushort4(0, 0, 0, 0);
            if (m0 + r < M)
                v = *(const ushort4*)(Ab + (size_t)(m0 + r) * NN_HF + kc + k4);
            As[r][k4 + 0] = bfu2f(v.x); As[r][k4 + 1] = bfu2f(v.y);
            As[r][k4 + 2] = bfu2f(v.z); As[r][k4 + 3] = bfu2f(v.w);
        }
        #pragma unroll
        for (int i = 0; i < 10; ++i) {
            int g = t + i * 256;
            int k = g / NN_C, c = g % NN_C;
            Ws[k][c] = W2[(size_t)(kc + k) * NN_C + c];
        }
        __syncthreads();
        #pragma unroll 4
        for (int k = 0; k < G2_KC; ++k) {
            float a0 = As[r0][k];
            float a1 = As[r1][k];
            #pragma unroll
            for (int j = 0; j < 5; ++j) {
                float w = Ws[k][c0 + j];
                acc[0][j] += a0 * w;
                acc[1][j] += a1 * w;
            }
        }
        __syncthreads();
    }
    #pragma unroll
    for (int i = 0; i < 2; ++i) {
        int m = m0 + r0 + i;
        float ps = 0.f, pd = 0.f;
        #pragma unroll
        for (int j = 0; j < 5; ++j) {
            float v = acc[i][j];
            ps += v * att_s[c0 + j];
            pd += v * att_d[c0 + j];
            if (m < M) h2[(size_t)m * NN_C + c0 + j] = v;
        }
        #pragma unroll
        for (int off = 4; off >= 1; off >>= 1) {
            ps += __shfl_down(ps, off, 8);
            pd += __shfl_down(pd, off, 8);
        }
        if (cg == 0 && m < M) { a2s[m] = ps; a2d[m] = pd; }
    }
}

// ---------------- layer-2 edge weights (H=1) ----------------
__global__ __launch_bounds__(64) void attw2_kernel(
    const float* __restrict__ a2s, const float* __restrict__ a2d,
    const int* __restrict__ offs, const int* __restrict__ srcs,
    float* __restrict__ alpha2)
{
    int n = blockIdx.x;
    int lane = threadIdx.x;
    int beg = offs[n], end = offs[n + 1];
    float adn = a2d[n];
    float m = -3.0e38f, s = 0.f;
    for (int k = beg + lane; k < end; k += 64) {
        int sN = srcs[k];
        float e = a2s[sN] + adn;
        e = e > 0.f ? e : 0.2f * e;
        float nm = fmaxf(m, e);
        float sc = __expf(m - nm);
        s = s * sc + __expf(e - nm);
        m = nm;
    }
    #pragma unroll
    for (int off = 1; off < 64; off <<= 1) {
        float mo = __shfl_xor(m, off);
        float so = __shfl_xor(s, off);
        float nm = fmaxf(m, mo);
        s = s * __expf(m - nm) + so * __expf(mo - nm);
        m = nm;
    }
    float inv = 1.f / (s + 1e-16f);
    for (int k = beg + lane; k < end; k += 64) {
        int sN = srcs[k];
        float e = a2s[sN] + adn;
        e = e > 0.f ? e : 0.2f * e;
        alpha2[k] = __expf(e - m) * inv;
    }
}

// ---------------- layer-2 aggregate + bias + log_softmax ----------------
__global__ __launch_bounds__(64) void agg2_kernel(
    const float* __restrict__ h2, const float* __restrict__ alpha2,
    const int* __restrict__ offs, const int* __restrict__ srcs,
    const float* __restrict__ b2, float* __restrict__ out)
{
    int n = blockIdx.x;
    int f = threadIdx.x;
    int beg = offs[n], end = offs[n + 1];
    float acc = 0.f;
    for (int k = beg; k < end; ++k) {
        int sN = srcs[k];
        float w = alpha2[k];
        float hv = (f < NN_C) ? h2[(size_t)sN * NN_C + f] : 0.f;
        acc = fmaf(w, hv, acc);
    }
    float v = acc + ((f < NN_C) ? b2[f] : 0.f);
    float lg = (f < NN_C) ? v : -INFINITY;
    float mx = lg;
    #pragma unroll
    for (int off = 32; off >= 1; off >>= 1) mx = fmaxf(mx, __shfl_xor(mx, off));
    float w2 = (f < NN_C) ? __expf(lg - mx) : 0.f;
    float sum = w2;
    #pragma unroll
    for (int off = 32; off >= 1; off >>= 1) sum += __shfl_xor(sum, off);
    if (f < NN_C) out[(size_t)n * NN_C + f] = lg - mx - __logf(sum);
}

// ---------------- launcher ----------------
extern "C" void kernel_launch(void* const* d_in, const int* in_sizes, int n_in,
                              void* d_out, int out_size, void* d_ws, size_t ws_size,
                              hipStream_t stream)
{
    const float* x    = (const float*)d_in[0];
    const int*   ei   = (const int*)d_in[1];
    const float* W1   = (const float*)d_in[2];
    const float* as1  = (const float*)d_in[3];
    const float* ad1  = (const float*)d_in[4];
    const float* b1   = (const float*)d_in[5];
    const float* W2   = (const float*)d_in[6];
    const float* as2  = (const float*)d_in[7];
    const float* ad2  = (const float*)d_in[8];
    const float* b2   = (const float*)d_in[9];
    float* out = (float*)d_out;

    int Nn = in_sizes[0] / NN_DIN;      // 50000
    int E  = in_sizes[1] / 2;           // 800000
    int Et = E + Nn;
    const int* srcIdx = ei;
    const int* dstIdx = ei + E;

    char* ws = (char*)d_ws;
    size_t off = 0;
    auto alloc = [&](size_t bytes) {
        void* p = ws + off;
        off = (off + bytes + 255) & ~(size_t)255;
        return p;
    };
    unsigned short* h1b  = (unsigned short*)alloc((size_t)Nn * NN_HF * 2);
    unsigned short* W1Th = (unsigned short*)alloc((size_t)NN_HF * NN_DIN * 2);
    unsigned short* W1Tl = (unsigned short*)alloc((size_t)NN_HF * NN_DIN * 2);
    unsigned short* hp1b = (unsigned short*)alloc((size_t)Nn * NN_HF * 2);
    float* a1s  = (float*)alloc((size_t)Nn * NN_H * 4);
    float* a1d  = (float*)alloc((size_t)Nn * NN_H * 4);
    float* h2   = (float*)alloc((size_t)Nn * NN_C * 4);
    float* a2s  = (float*)alloc((size_t)Nn * 4);
    float* a2d  = (float*)alloc((size_t)Nn * 4);
    float* alpha1 = (float*)alloc((size_t)Et * NN_H * 4);
    float* alpha2 = (float*)alloc((size_t)Et * 4);
    int*   deg  = (int*)alloc((size_t)Nn * 4);
    int*   offs = (int*)alloc((size_t)(Nn + 1) * 4);
    int*   bsums= (int*)alloc(1024 * 4);
    int*   curs = (int*)alloc((size_t)Nn * 4);
    int*   srcs = (int*)alloc((size_t)Et * 4);

    hipMemsetAsync(deg, 0, (size_t)Nn * 4, stream);
    hipMemsetAsync(curs, 0, (size_t)Nn * 4, stream);

    // W1 transpose + split
    w1split_kernel<<<dim3(NN_DIN / 32, NN_HF / 32), 256, 0, stream>>>(W1, W1Th, W1Tl);

    // GEMM1 (MFMA, split-bf16) -> h1b
    dim3 g1((Nn + G1_BM - 1) / G1_BM, NN_HF / G1_BN);
    gemm1_kernel<<<g1, 256, 0, stream>>>(x, W1Th, W1Tl, h1b, Nn);

    // attention coefficients
    attn1_kernel<<<Nn, 256, 0, stream>>>(h1b, as1, ad1, a1s, a1d);

    // CSR build
    count_kernel<<<(Et + 255) / 256, 256, 0, stream>>>(dstIdx, deg, E, Nn);
    int nb = (Nn + SCAN_CHUNK - 1) / SCAN_CHUNK;
    scan1_kernel<<<nb, 256, 0, stream>>>(deg, offs, bsums, Nn);
    scan2_kernel<<<1, 64, 0, stream>>>(bsums, nb);
    scan3_kernel<<<(Nn + 255) / 256, 256, 0, stream>>>(offs, bsums, Nn, Et);
    fill_kernel<<<(Et + 255) / 256, 256, 0, stream>>>(srcIdx, dstIdx, offs, curs, srcs, E, Nn);

    // layer-1 edge weights, then weighted aggregate (+bias+ELU) -> bf16
    attw1_kernel<<<Nn, 64, 0, stream>>>(a1s, a1d, offs, srcs, alpha1);
    agg1_kernel<<<Nn, 256, 0, stream>>>(h1b, alpha1, offs, srcs, b1, hp1b);

    // GEMM2 (+fused a2s/a2d)
    gemm2_kernel<<<(Nn + G2_ROWS - 1) / G2_ROWS, 256, 0, stream>>>(
        hp1b, W2, as2, ad2, h2, a2s, a2d, Nn);

    // layer-2 edge weights, then aggregate + bias + log_softmax
    attw2_kernel<<<Nn, 64, 0, stream>>>(a2s, a2d, offs, srcs, alpha2);
    agg2_kernel<<<Nn, 64, 0, stream>>>(h2, alpha2, offs, srcs, b2, out);
}

// Round 5
// 547.123 us; speedup vs baseline: 1.3443x; 1.2000x over previous
//
#include <hip/hip_runtime.h>
#include <hip/hip_bf16.h>
#include <math.h>

#define NN_DIN 512
#define NN_HF  256
#define NN_H   8
#define NN_F   32
#define NN_C   40

typedef short bf16x8 __attribute__((ext_vector_type(8)));
typedef float f32x4 __attribute__((ext_vector_type(4)));

__device__ __forceinline__ unsigned short f2bf_rne(float x) {
    unsigned u = __builtin_bit_cast(unsigned, x);
    unsigned r = u + 0x7FFFu + ((u >> 16) & 1u);
    return (unsigned short)(r >> 16);
}
__device__ __forceinline__ float bfu2f(unsigned short s) {
    unsigned u = ((unsigned)s) << 16;
    return __builtin_bit_cast(float, u);
}
// truncation split: x ~= hi + lo with |err| <= 2^-16 |x|
__device__ __forceinline__ void fsplit(float x, unsigned short& hi, unsigned short& lo) {
    unsigned u = __builtin_bit_cast(unsigned, x);
    hi = (unsigned short)(u >> 16);
    float hif = __builtin_bit_cast(float, u & 0xFFFF0000u);
    float rem = x - hif;
    lo = (unsigned short)(__builtin_bit_cast(unsigned, rem) >> 16);
}

// ---------------- W1 transpose + split: [512][256] f32 -> [256][512] bf16 hi/lo ----
__global__ __launch_bounds__(256) void w1split_kernel(
    const float* __restrict__ W1, unsigned short* __restrict__ Wh,
    unsigned short* __restrict__ Wl)
{
    __shared__ float tile[32][33];
    int bk = blockIdx.x * 32;
    int bn = blockIdx.y * 32;
    int tx = threadIdx.x & 31, ty = threadIdx.x >> 5;   // ty 0..7
    #pragma unroll
    for (int i = 0; i < 32; i += 8)
        tile[ty + i][tx] = W1[(size_t)(bk + ty + i) * NN_HF + bn + tx];
    __syncthreads();
    #pragma unroll
    for (int i = 0; i < 32; i += 8) {
        float v = tile[tx][ty + i];
        unsigned short h, l;
        fsplit(v, h, l);
        Wh[(size_t)(bn + ty + i) * NN_DIN + bk + tx] = h;
        Wl[(size_t)(bn + ty + i) * NN_DIN + bk + tx] = l;
    }
}

// ---------------- GEMM1 (MFMA): h1b = bf16(x @ W1) ----------------
#define G1_BM 128
#define G1_BN 128
#define G1_BK 64
#define G1_LDK 72   // padded row length (shorts): stride 144B -> 2-way bank alias (free)

__global__ __launch_bounds__(256) void gemm1_kernel(
    const float* __restrict__ A, const unsigned short* __restrict__ BTh,
    const unsigned short* __restrict__ BTl, unsigned short* __restrict__ Cb, int M)
{
    __shared__ unsigned short Ah[G1_BM][G1_LDK];
    __shared__ unsigned short Al[G1_BM][G1_LDK];
    __shared__ unsigned short Bh[G1_BN][G1_LDK];
    __shared__ unsigned short Bl[G1_BN][G1_LDK];
    const int m0 = blockIdx.x * G1_BM;
    const int n0 = blockIdx.y * G1_BN;
    const int tid = threadIdx.x;
    const int wave = tid >> 6, lane = tid & 63;
    const int wm = wave >> 1, wn = wave & 1;     // 2x2 wave grid, each wave 64x64
    const int lr = lane & 15, lg = lane >> 4;    // frag index, k-group

    f32x4 acc[4][4];
    #pragma unroll
    for (int i = 0; i < 4; ++i)
        #pragma unroll
        for (int j = 0; j < 4; ++j) acc[i][j] = (f32x4){0.f, 0.f, 0.f, 0.f};

    for (int k0 = 0; k0 < NN_DIN; k0 += G1_BK) {
        #pragma unroll
        for (int i = 0; i < 8; ++i) {
            int g = tid + i * 256;
            int m = g >> 4;
            int k4 = (g & 15) << 2;
            float4 v = make_float4(0.f, 0.f, 0.f, 0.f);
            if (m0 + m < M) v = *(const float4*)(A + (size_t)(m0 + m) * NN_DIN + k0 + k4);
            ushort4 hv, lv;
            fsplit(v.x, hv.x, lv.x); fsplit(v.y, hv.y, lv.y);
            fsplit(v.z, hv.z, lv.z); fsplit(v.w, hv.w, lv.w);
            *reinterpret_cast<ushort4*>(&Ah[m][k4]) = hv;
            *reinterpret_cast<ushort4*>(&Al[m][k4]) = lv;
        }
        #pragma unroll
        for (int i = 0; i < 4; ++i) {
            int g = tid + i * 256;
            int n = g >> 3;
            int k8 = (g & 7) << 3;
            *reinterpret_cast<bf16x8*>(&Bh[n][k8]) =
                *reinterpret_cast<const bf16x8*>(BTh + (size_t)(n0 + n) * NN_DIN + k0 + k8);
            *reinterpret_cast<bf16x8*>(&Bl[n][k8]) =
                *reinterpret_cast<const bf16x8*>(BTl + (size_t)(n0 + n) * NN_DIN + k0 + k8);
        }
        __syncthreads();
        #pragma unroll
        for (int ks = 0; ks < 2; ++ks) {
            const int kb = (ks << 5) + (lg << 3);
            bf16x8 fah[4], fal[4], fbh[4], fbl[4];
            #pragma unroll
            for (int mi = 0; mi < 4; ++mi) {
                int m = (wm << 6) + (mi << 4) + lr;
                fah[mi] = *reinterpret_cast<const bf16x8*>(&Ah[m][kb]);
                fal[mi] = *reinterpret_cast<const bf16x8*>(&Al[m][kb]);
            }
            #pragma unroll
            for (int ni = 0; ni < 4; ++ni) {
                int n = (wn << 6) + (ni << 4) + lr;
                fbh[ni] = *reinterpret_cast<const bf16x8*>(&Bh[n][kb]);
                fbl[ni] = *reinterpret_cast<const bf16x8*>(&Bl[n][kb]);
            }
            #pragma unroll
            for (int mi = 0; mi < 4; ++mi)
                #pragma unroll
                for (int ni = 0; ni < 4; ++ni) {
                    acc[mi][ni] = __builtin_amdgcn_mfma_f32_16x16x32_bf16(
                        fah[mi], fbh[ni], acc[mi][ni], 0, 0, 0);
                    acc[mi][ni] = __builtin_amdgcn_mfma_f32_16x16x32_bf16(
                        fah[mi], fbl[ni], acc[mi][ni], 0, 0, 0);
                    acc[mi][ni] = __builtin_amdgcn_mfma_f32_16x16x32_bf16(
                        fal[mi], fbh[ni], acc[mi][ni], 0, 0, 0);
                }
        }
        __syncthreads();
    }
    #pragma unroll
    for (int mi = 0; mi < 4; ++mi)
        #pragma unroll
        for (int ni = 0; ni < 4; ++ni)
            #pragma unroll
            for (int r = 0; r < 4; ++r) {
                int row = m0 + (wm << 6) + (mi << 4) + (lg << 2) + r;
                int col = n0 + (wn << 6) + (ni << 4) + lr;
                if (row < M)
                    Cb[(size_t)row * NN_HF + col] = f2bf_rne(acc[mi][ni][r]);
            }
}

// ---------------- attention coefficients layer 1 (reads bf16 h1) ----------------
__global__ __launch_bounds__(256) void attn1_kernel(
    const unsigned short* __restrict__ h1b, const float* __restrict__ att_s,
    const float* __restrict__ att_d, float* __restrict__ a1s,
    float* __restrict__ a1d)
{
    int n = blockIdx.x;
    int t = threadIdx.x;            // t = h*32 + f
    float hv = bfu2f(h1b[(size_t)n * NN_HF + t]);
    float ps = hv * att_s[t];
    float pd = hv * att_d[t];
    #pragma unroll
    for (int off = 16; off >= 1; off >>= 1) {
        ps += __shfl_down(ps, off, 32);
        pd += __shfl_down(pd, off, 32);
    }
    if ((t & 31) == 0) {
        a1s[n * NN_H + (t >> 5)] = ps;
        a1d[n * NN_H + (t >> 5)] = pd;
    }
}

// ---------------- CSR build ----------------
__global__ void count_kernel(const int* __restrict__ dst, int* __restrict__ deg,
                             int E, int Nn)
{
    int e = blockIdx.x * blockDim.x + threadIdx.x;
    int Et = E + Nn;
    if (e >= Et) return;
    int d = (e < E) ? dst[e] : (e - E);     // self-loops appended
    atomicAdd(&deg[d], 1);
}

#define SCAN_CHUNK 1024
__global__ __launch_bounds__(256) void scan1_kernel(
    const int* __restrict__ deg, int* __restrict__ offs,
    int* __restrict__ bsums, int Nn)
{
    __shared__ int sh[256];
    int b = blockIdx.x, t = threadIdx.x;
    int base = b * SCAN_CHUNK + t * 4;
    int v[4];
    int tot = 0;
    #pragma unroll
    for (int i = 0; i < 4; ++i) {
        v[i] = (base + i < Nn) ? deg[base + i] : 0;
        tot += v[i];
    }
    sh[t] = tot;
    __syncthreads();
    for (int off = 1; off < 256; off <<= 1) {
        int y = (t >= off) ? sh[t - off] : 0;
        __syncthreads();
        sh[t] += y;
        __syncthreads();
    }
    int p = sh[t] - tot;
    #pragma unroll
    for (int i = 0; i < 4; ++i) {
        if (base + i < Nn) offs[base + i] = p;
        p += v[i];
    }
    if (t == 255) bsums[b] = sh[255];
}

__global__ void scan2_kernel(int* __restrict__ bsums, int nb)
{
    if (threadIdx.x == 0) {
        int run = 0;
        for (int i = 0; i < nb; ++i) {
            int tmp = bsums[i];
            bsums[i] = run;
            run += tmp;
        }
    }
}

__global__ void scan3_kernel(int* __restrict__ offs, const int* __restrict__ bsums,
                             int Nn, int Et)
{
    int i = blockIdx.x * blockDim.x + threadIdx.x;
    if (i < Nn) offs[i] += bsums[i >> 10];
    if (i == 0) offs[Nn] = Et;
}

__global__ void fill_kernel(const int* __restrict__ src, const int* __restrict__ dst,
                            const int* __restrict__ offs, int* __restrict__ cursor,
                            int* __restrict__ srcs, int E, int Nn)
{
    int e = blockIdx.x * blockDim.x + threadIdx.x;
    int Et = E + Nn;
    if (e >= Et) return;
    int d, s;
    if (e < E) { d = dst[e]; s = src[e]; }
    else       { d = e - E;  s = e - E;  }
    int pos = offs[d] + atomicAdd(&cursor[d], 1);
    srcs[pos] = s;
}

// ---------------- layer-1 edge weights: alpha1[k][h] = softmax ----------------
__global__ __launch_bounds__(64) void attw1_kernel(
    const float* __restrict__ a1s, const float* __restrict__ a1d,
    const int* __restrict__ offs, const int* __restrict__ srcs,
    float* __restrict__ alpha1)
{
    int n = blockIdx.x;
    int lane = threadIdx.x;
    int g = lane >> 3, h = lane & 7;        // 8 edge groups x 8 heads
    int beg = offs[n], end = offs[n + 1];
    float adn = a1d[n * NN_H + h];
    float m = -3.0e38f, s = 0.f;
    for (int k = beg + g; k < end; k += 8) {
        int sN = srcs[k];
        float e = a1s[sN * NN_H + h] + adn;
        e = e > 0.f ? e : 0.2f * e;
        float nm = fmaxf(m, e);
        float sc = __expf(m - nm);
        s = s * sc + __expf(e - nm);
        m = nm;
    }
    #pragma unroll
    for (int off = 8; off < 64; off <<= 1) {
        float mo = __shfl_xor(m, off);
        float so = __shfl_xor(s, off);
        float nm = fmaxf(m, mo);
        s = s * __expf(m - nm) + so * __expf(mo - nm);
        m = nm;
    }
    float inv = 1.f / (s + 1e-16f);
    for (int k = beg + g; k < end; k += 8) {
        int sN = srcs[k];
        float e = a1s[sN * NN_H + h] + adn;
        e = e > 0.f ? e : 0.2f * e;
        alpha1[(size_t)k * NN_H + h] = __expf(e - m) * inv;
    }
}

// ---------------- layer-1 aggregate: wave-per-node weighted gather + bias + ELU ----
// lane l covers features 4l..4l+3 (ushort4 = whole 512B row per wave); head = l>>3
__global__ __launch_bounds__(256) void agg1_kernel(
    const unsigned short* __restrict__ h1b, const float* __restrict__ alpha1,
    const int* __restrict__ offs, const int* __restrict__ srcs,
    const float* __restrict__ b1, unsigned short* __restrict__ hp1b, int Nn)
{
    int n = blockIdx.x * 4 + (threadIdx.x >> 6);
    if (n >= Nn) return;
    int lane = threadIdx.x & 63;
    int h = lane >> 3;
    int beg = offs[n], end = offs[n + 1];
    f32x4 a0 = {0.f,0.f,0.f,0.f}, a1 = a0, a2 = a0, a3 = a0;
    int k = beg;
    for (; k + 3 < end; k += 4) {
        int s0 = srcs[k], s1 = srcs[k+1], s2 = srcs[k+2], s3 = srcs[k+3];
        float w0 = alpha1[(size_t)k * NN_H + h];
        float w1 = alpha1[(size_t)(k+1) * NN_H + h];
        float w2 = alpha1[(size_t)(k+2) * NN_H + h];
        float w3 = alpha1[(size_t)(k+3) * NN_H + h];
        ushort4 v0 = *(const ushort4*)(h1b + (size_t)s0 * NN_HF + lane * 4);
        ushort4 v1 = *(const ushort4*)(h1b + (size_t)s1 * NN_HF + lane * 4);
        ushort4 v2 = *(const ushort4*)(h1b + (size_t)s2 * NN_HF + lane * 4);
        ushort4 v3 = *(const ushort4*)(h1b + (size_t)s3 * NN_HF + lane * 4);
        a0.x = fmaf(w0, bfu2f(v0.x), a0.x); a0.y = fmaf(w0, bfu2f(v0.y), a0.y);
        a0.z = fmaf(w0, bfu2f(v0.z), a0.z); a0.w = fmaf(w0, bfu2f(v0.w), a0.w);
        a1.x = fmaf(w1, bfu2f(v1.x), a1.x); a1.y = fmaf(w1, bfu2f(v1.y), a1.y);
        a1.z = fmaf(w1, bfu2f(v1.z), a1.z); a1.w = fmaf(w1, bfu2f(v1.w), a1.w);
        a2.x = fmaf(w2, bfu2f(v2.x), a2.x); a2.y = fmaf(w2, bfu2f(v2.y), a2.y);
        a2.z = fmaf(w2, bfu2f(v2.z), a2.z); a2.w = fmaf(w2, bfu2f(v2.w), a2.w);
        a3.x = fmaf(w3, bfu2f(v3.x), a3.x); a3.y = fmaf(w3, bfu2f(v3.y), a3.y);
        a3.z = fmaf(w3, bfu2f(v3.z), a3.z); a3.w = fmaf(w3, bfu2f(v3.w), a3.w);
    }
    for (; k < end; ++k) {
        int s0 = srcs[k];
        float w0 = alpha1[(size_t)k * NN_H + h];
        ushort4 v0 = *(const ushort4*)(h1b + (size_t)s0 * NN_HF + lane * 4);
        a0.x = fmaf(w0, bfu2f(v0.x), a0.x); a0.y = fmaf(w0, bfu2f(v0.y), a0.y);
        a0.z = fmaf(w0, bfu2f(v0.z), a0.z); a0.w = fmaf(w0, bfu2f(v0.w), a0.w);
    }
    f32x4 acc;
    acc[0] = (a0.x + a1.x) + (a2.x + a3.x);
    acc[1] = (a0.y + a1.y) + (a2.y + a3.y);
    acc[2] = (a0.z + a1.z) + (a2.z + a3.z);
    acc[3] = (a0.w + a1.w) + (a2.w + a3.w);
    float4 bb = *(const float4*)(b1 + lane * 4);
    float r0 = acc[0] + bb.x, r1 = acc[1] + bb.y;
    float r2 = acc[2] + bb.z, r3 = acc[3] + bb.w;
    r0 = r0 > 0.f ? r0 : __expf(r0) - 1.f;
    r1 = r1 > 0.f ? r1 : __expf(r1) - 1.f;
    r2 = r2 > 0.f ? r2 : __expf(r2) - 1.f;
    r3 = r3 > 0.f ? r3 : __expf(r3) - 1.f;
    ushort4 o = make_ushort4(f2bf_rne(r0), f2bf_rne(r1), f2bf_rne(r2), f2bf_rne(r3));
    *(ushort4*)(hp1b + (size_t)n * NN_HF + lane * 4) = o;
}

// ---------------- GEMM2: h2 = hp1 @ W2  (bf16 in, fp32 math), fused a2s/a2d ----
#define G2_ROWS 64
#define G2_KC   64

__global__ __launch_bounds__(256) void gemm2_kernel(
    const unsigned short* __restrict__ Ab, const float* __restrict__ W2,
    const float* __restrict__ att_s, const float* __restrict__ att_d,
    float* __restrict__ h2, float* __restrict__ a2s, float* __restrict__ a2d,
    int M)
{
    __shared__ float As[G2_ROWS][G2_KC + 1];
    __shared__ float Ws[G2_KC][NN_C];
    int m0 = blockIdx.x * G2_ROWS;
    int t = threadIdx.x;
    int rp = t >> 3;
    int cg = t & 7;
    int c0 = cg * 5;
    int r0 = rp * 2, r1 = r0 + 1;
    float acc[2][5] = {};
    for (int kc = 0; kc < NN_HF; kc += G2_KC) {
        #pragma unroll
        for (int i = 0; i < 4; ++i) {
            int g = t + i * 256;
            int r = g >> 4;
            int k4 = (g & 15) << 2;
            ushort4 v = make_ushort4(0, 0, 0, 0);
            if (m0 + r < M)
                v = *(const ushort4*)(Ab + (size_t)(m0 + r) * NN_HF + kc + k4);
            As[r][k4 + 0] = bfu2f(v.x); As[r][k4 + 1] = bfu2f(v.y);
            As[r][k4 + 2] = bfu2f(v.z); As[r][k4 + 3] = bfu2f(v.w);
        }
        #pragma unroll
        for (int i = 0; i < 10; ++i) {
            int g = t + i * 256;
            int k = g / NN_C, c = g % NN_C;
            Ws[k][c] = W2[(size_t)(kc + k) * NN_C + c];
        }
        __syncthreads();
        #pragma unroll 4
        for (int k = 0; k < G2_KC; ++k) {
            float a0 = As[r0][k];
            float a1 = As[r1][k];
            #pragma unroll
            for (int j = 0; j < 5; ++j) {
                float w = Ws[k][c0 + j];
                acc[0][j] += a0 * w;
                acc[1][j] += a1 * w;
            }
        }
        __syncthreads();
    }
    #pragma unroll
    for (int i = 0; i < 2; ++i) {
        int m = m0 + r0 + i;
        float ps = 0.f, pd = 0.f;
        #pragma unroll
        for (int j = 0; j < 5; ++j) {
            float v = acc[i][j];
            ps += v * att_s[c0 + j];
            pd += v * att_d[c0 + j];
            if (m < M) h2[(size_t)m * NN_C + c0 + j] = v;
        }
        #pragma unroll
        for (int off = 4; off >= 1; off >>= 1) {
            ps += __shfl_down(ps, off, 8);
            pd += __shfl_down(pd, off, 8);
        }
        if (cg == 0 && m < M) { a2s[m] = ps; a2d[m] = pd; }
    }
}

// ---------------- layer-2 edge weights (H=1) ----------------
__global__ __launch_bounds__(64) void attw2_kernel(
    const float* __restrict__ a2s, const float* __restrict__ a2d,
    const int* __restrict__ offs, const int* __restrict__ srcs,
    float* __restrict__ alpha2)
{
    int n = blockIdx.x;
    int lane = threadIdx.x;
    int beg = offs[n], end = offs[n + 1];
    float adn = a2d[n];
    float m = -3.0e38f, s = 0.f;
    for (int k = beg + lane; k < end; k += 64) {
        int sN = srcs[k];
        float e = a2s[sN] + adn;
        e = e > 0.f ? e : 0.2f * e;
        float nm = fmaxf(m, e);
        float sc = __expf(m - nm);
        s = s * sc + __expf(e - nm);
        m = nm;
    }
    #pragma unroll
    for (int off = 1; off < 64; off <<= 1) {
        float mo = __shfl_xor(m, off);
        float so = __shfl_xor(s, off);
        float nm = fmaxf(m, mo);
        s = s * __expf(m - nm) + so * __expf(mo - nm);
        m = nm;
    }
    float inv = 1.f / (s + 1e-16f);
    for (int k = beg + lane; k < end; k += 64) {
        int sN = srcs[k];
        float e = a2s[sN] + adn;
        e = e > 0.f ? e : 0.2f * e;
        alpha2[k] = __expf(e - m) * inv;
    }
}

// ---------------- layer-2 aggregate: wave-per-node + bias + log_softmax ----------
__global__ __launch_bounds__(256) void agg2_kernel(
    const float* __restrict__ h2, const float* __restrict__ alpha2,
    const int* __restrict__ offs, const int* __restrict__ srcs,
    const float* __restrict__ b2, float* __restrict__ out, int Nn)
{
    int n = blockIdx.x * 4 + (threadIdx.x >> 6);
    if (n >= Nn) return;
    int f = threadIdx.x & 63;
    int beg = offs[n], end = offs[n + 1];
    float a0 = 0.f, a1 = 0.f, a2 = 0.f, a3 = 0.f;
    int k = beg;
    for (; k + 3 < end; k += 4) {
        int s0 = srcs[k], s1 = srcs[k+1], s2 = srcs[k+2], s3 = srcs[k+3];
        float w0 = alpha2[k], w1 = alpha2[k+1], w2 = alpha2[k+2], w3 = alpha2[k+3];
        float h0 = (f < NN_C) ? h2[(size_t)s0 * NN_C + f] : 0.f;
        float h1 = (f < NN_C) ? h2[(size_t)s1 * NN_C + f] : 0.f;
        float h2v = (f < NN_C) ? h2[(size_t)s2 * NN_C + f] : 0.f;
        float h3 = (f < NN_C) ? h2[(size_t)s3 * NN_C + f] : 0.f;
        a0 = fmaf(w0, h0, a0); a1 = fmaf(w1, h1, a1);
        a2 = fmaf(w2, h2v, a2); a3 = fmaf(w3, h3, a3);
    }
    for (; k < end; ++k) {
        int s0 = srcs[k];
        float w0 = alpha2[k];
        float h0 = (f < NN_C) ? h2[(size_t)s0 * NN_C + f] : 0.f;
        a0 = fmaf(w0, h0, a0);
    }
    float acc = (a0 + a1) + (a2 + a3);
    float v = acc + ((f < NN_C) ? b2[f] : 0.f);
    float lg = (f < NN_C) ? v : -INFINITY;
    float mx = lg;
    #pragma unroll
    for (int off = 32; off >= 1; off >>= 1) mx = fmaxf(mx, __shfl_xor(mx, off));
    float w2e = (f < NN_C) ? __expf(lg - mx) : 0.f;
    float sum = w2e;
    #pragma unroll
    for (int off = 32; off >= 1; off >>= 1) sum += __shfl_xor(sum, off);
    if (f < NN_C) out[(size_t)n * NN_C + f] = lg - mx - __logf(sum);
}

// ---------------- launcher ----------------
extern "C" void kernel_launch(void* const* d_in, const int* in_sizes, int n_in,
                              void* d_out, int out_size, void* d_ws, size_t ws_size,
                              hipStream_t stream)
{
    const float* x    = (const float*)d_in[0];
    const int*   ei   = (const int*)d_in[1];
    const float* W1   = (const float*)d_in[2];
    const float* as1  = (const float*)d_in[3];
    const float* ad1  = (const float*)d_in[4];
    const float* b1   = (const float*)d_in[5];
    const float* W2   = (const float*)d_in[6];
    const float* as2  = (const float*)d_in[7];
    const float* ad2  = (const float*)d_in[8];
    const float* b2   = (const float*)d_in[9];
    float* out = (float*)d_out;

    int Nn = in_sizes[0] / NN_DIN;      // 50000
    int E  = in_sizes[1] / 2;           // 800000
    int Et = E + Nn;
    const int* srcIdx = ei;
    const int* dstIdx = ei + E;

    char* ws = (char*)d_ws;
    size_t off = 0;
    auto alloc = [&](size_t bytes) {
        void* p = ws + off;
        off = (off + bytes + 255) & ~(size_t)255;
        return p;
    };
    unsigned short* h1b  = (unsigned short*)alloc((size_t)Nn * NN_HF * 2);
    unsigned short* W1Th = (unsigned short*)alloc((size_t)NN_HF * NN_DIN * 2);
    unsigned short* W1Tl = (unsigned short*)alloc((size_t)NN_HF * NN_DIN * 2);
    unsigned short* hp1b = (unsigned short*)alloc((size_t)Nn * NN_HF * 2);
    float* a1s  = (float*)alloc((size_t)Nn * NN_H * 4);
    float* a1d  = (float*)alloc((size_t)Nn * NN_H * 4);
    float* h2   = (float*)alloc((size_t)Nn * NN_C * 4);
    float* a2s  = (float*)alloc((size_t)Nn * 4);
    float* a2d  = (float*)alloc((size_t)Nn * 4);
    float* alpha1 = (float*)alloc((size_t)Et * NN_H * 4);
    float* alpha2 = (float*)alloc((size_t)Et * 4);
    int*   deg  = (int*)alloc((size_t)Nn * 4);
    int*   offs = (int*)alloc((size_t)(Nn + 1) * 4);
    int*   bsums= (int*)alloc(1024 * 4);
    int*   curs = (int*)alloc((size_t)Nn * 4);
    int*   srcs = (int*)alloc((size_t)Et * 4);

    hipMemsetAsync(deg, 0, (size_t)Nn * 4, stream);
    hipMemsetAsync(curs, 0, (size_t)Nn * 4, stream);

    // W1 transpose + split
    w1split_kernel<<<dim3(NN_DIN / 32, NN_HF / 32), 256, 0, stream>>>(W1, W1Th, W1Tl);

    // GEMM1 (MFMA, split-bf16) -> h1b
    dim3 g1((Nn + G1_BM - 1) / G1_BM, NN_HF / G1_BN);
    gemm1_kernel<<<g1, 256, 0, stream>>>(x, W1Th, W1Tl, h1b, Nn);

    // attention coefficients
    attn1_kernel<<<Nn, 256, 0, stream>>>(h1b, as1, ad1, a1s, a1d);

    // CSR build
    count_kernel<<<(Et + 255) / 256, 256, 0, stream>>>(dstIdx, deg, E, Nn);
    int nb = (Nn + SCAN_CHUNK - 1) / SCAN_CHUNK;
    scan1_kernel<<<nb, 256, 0, stream>>>(deg, offs, bsums, Nn);
    scan2_kernel<<<1, 64, 0, stream>>>(bsums, nb);
    scan3_kernel<<<(Nn + 255) / 256, 256, 0, stream>>>(offs, bsums, Nn, Et);
    fill_kernel<<<(Et + 255) / 256, 256, 0, stream>>>(srcIdx, dstIdx, offs, curs, srcs, E, Nn);

    // layer-1 edge weights, then weighted aggregate (+bias+ELU) -> bf16
    attw1_kernel<<<Nn, 64, 0, stream>>>(a1s, a1d, offs, srcs, alpha1);
    agg1_kernel<<<(Nn + 3) / 4, 256, 0, stream>>>(h1b, alpha1, offs, srcs, b1, hp1b, Nn);

    // GEMM2 (+fused a2s/a2d)
    gemm2_kernel<<<(Nn + G2_ROWS - 1) / G2_ROWS, 256, 0, stream>>>(
        hp1b, W2, as2, ad2, h2, a2s, a2d, Nn);

    // layer-2 edge weights, then aggregate + bias + log_softmax
    attw2_kernel<<<Nn, 64, 0, stream>>>(a2s, a2d, offs, srcs, alpha2);
    agg2_kernel<<<(Nn + 3) / 4, 256, 0, stream>>>(h2, alpha2, offs, srcs, b2, out, Nn);
}

// Round 6
// 529.194 us; speedup vs baseline: 1.3898x; 1.0339x over previous
//
#include <hip/hip_runtime.h>
#include <hip/hip_bf16.h>
#include <math.h>

#define NN_DIN 512
#define NN_HF  256
#define NN_H   8
#define NN_F   32
#define NN_C   40

typedef short bf16x8 __attribute__((ext_vector_type(8)));
typedef float f32x4 __attribute__((ext_vector_type(4)));

__device__ __forceinline__ unsigned short f2bf_rne(float x) {
    unsigned u = __builtin_bit_cast(unsigned, x);
    unsigned r = u + 0x7FFFu + ((u >> 16) & 1u);
    return (unsigned short)(r >> 16);
}
__device__ __forceinline__ float bfu2f(unsigned short s) {
    unsigned u = ((unsigned)s) << 16;
    return __builtin_bit_cast(float, u);
}

// ---------------- W1 transpose + RNE bf16: [512][256] f32 -> [256][512] bf16 ----
__global__ __launch_bounds__(256) void w1rne_kernel(
    const float* __restrict__ W1, unsigned short* __restrict__ Wh)
{
    __shared__ float tile[32][33];
    int bk = blockIdx.x * 32;
    int bn = blockIdx.y * 32;
    int tx = threadIdx.x & 31, ty = threadIdx.x >> 5;   // ty 0..7
    #pragma unroll
    for (int i = 0; i < 32; i += 8)
        tile[ty + i][tx] = W1[(size_t)(bk + ty + i) * NN_HF + bn + tx];
    __syncthreads();
    #pragma unroll
    for (int i = 0; i < 32; i += 8) {
        float v = tile[tx][ty + i];
        Wh[(size_t)(bn + ty + i) * NN_DIN + bk + tx] = f2bf_rne(v);
    }
}

// ---------------- GEMM1 (MFMA, single bf16 term): h1b = bf16(x @ W1) ----------------
#define G1_BM 128
#define G1_BN 128
#define G1_BK 64
#define G1_LDK 72   // must be mult of 8 (16B-aligned b128 frag reads)

__global__ __launch_bounds__(256) void gemm1_kernel(
    const float* __restrict__ A, const unsigned short* __restrict__ BT,
    unsigned short* __restrict__ Cb, int M)
{
    __shared__ unsigned short Ah[G1_BM][G1_LDK];
    __shared__ unsigned short Bh[G1_BN][G1_LDK];
    const int m0 = blockIdx.x * G1_BM;
    const int n0 = blockIdx.y * G1_BN;
    const int tid = threadIdx.x;
    const int wave = tid >> 6, lane = tid & 63;
    const int wm = wave >> 1, wn = wave & 1;     // 2x2 wave grid, each wave 64x64
    const int lr = lane & 15, lg = lane >> 4;    // frag index, k-group

    f32x4 acc[4][4];
    #pragma unroll
    for (int i = 0; i < 4; ++i)
        #pragma unroll
        for (int j = 0; j < 4; ++j) acc[i][j] = (f32x4){0.f, 0.f, 0.f, 0.f};

    for (int k0 = 0; k0 < NN_DIN; k0 += G1_BK) {
        // stage A: 128x64 f32 -> RNE bf16 (2048 float4, 8 per thread)
        #pragma unroll
        for (int i = 0; i < 8; ++i) {
            int g = tid + i * 256;
            int m = g >> 4;
            int k4 = (g & 15) << 2;
            float4 v = make_float4(0.f, 0.f, 0.f, 0.f);
            if (m0 + m < M) v = *(const float4*)(A + (size_t)(m0 + m) * NN_DIN + k0 + k4);
            ushort4 hv;
            hv.x = f2bf_rne(v.x); hv.y = f2bf_rne(v.y);
            hv.z = f2bf_rne(v.z); hv.w = f2bf_rne(v.w);
            *reinterpret_cast<ushort4*>(&Ah[m][k4]) = hv;
        }
        // stage B: pre-rounded bf16 rows, contiguous short8 copies
        #pragma unroll
        for (int i = 0; i < 4; ++i) {
            int g = tid + i * 256;
            int n = g >> 3;
            int k8 = (g & 7) << 3;
            *reinterpret_cast<bf16x8*>(&Bh[n][k8]) =
                *reinterpret_cast<const bf16x8*>(BT + (size_t)(n0 + n) * NN_DIN + k0 + k8);
        }
        __syncthreads();
        #pragma unroll
        for (int ks = 0; ks < 2; ++ks) {
            const int kb = (ks << 5) + (lg << 3);
            bf16x8 fah[4], fbh[4];
            #pragma unroll
            for (int mi = 0; mi < 4; ++mi) {
                int m = (wm << 6) + (mi << 4) + lr;
                fah[mi] = *reinterpret_cast<const bf16x8*>(&Ah[m][kb]);
            }
            #pragma unroll
            for (int ni = 0; ni < 4; ++ni) {
                int n = (wn << 6) + (ni << 4) + lr;
                fbh[ni] = *reinterpret_cast<const bf16x8*>(&Bh[n][kb]);
            }
            #pragma unroll
            for (int mi = 0; mi < 4; ++mi)
                #pragma unroll
                for (int ni = 0; ni < 4; ++ni)
                    acc[mi][ni] = __builtin_amdgcn_mfma_f32_16x16x32_bf16(
                        fah[mi], fbh[ni], acc[mi][ni], 0, 0, 0);
        }
        __syncthreads();
    }
    // epilogue: C/D frag mapping row=(lane>>4)*4+r, col=lane&15
    #pragma unroll
    for (int mi = 0; mi < 4; ++mi)
        #pragma unroll
        for (int ni = 0; ni < 4; ++ni)
            #pragma unroll
            for (int r = 0; r < 4; ++r) {
                int row = m0 + (wm << 6) + (mi << 4) + (lg << 2) + r;
                int col = n0 + (wn << 6) + (ni << 4) + lr;
                if (row < M)
                    Cb[(size_t)row * NN_HF + col] = f2bf_rne(acc[mi][ni][r]);
            }
}

// ---------------- attention coefficients layer 1 (reads bf16 h1) ----------------
__global__ __launch_bounds__(256) void attn1_kernel(
    const unsigned short* __restrict__ h1b, const float* __restrict__ att_s,
    const float* __restrict__ att_d, float* __restrict__ a1s,
    float* __restrict__ a1d)
{
    int n = blockIdx.x;
    int t = threadIdx.x;            // t = h*32 + f
    float hv = bfu2f(h1b[(size_t)n * NN_HF + t]);
    float ps = hv * att_s[t];
    float pd = hv * att_d[t];
    #pragma unroll
    for (int off = 16; off >= 1; off >>= 1) {
        ps += __shfl_down(ps, off, 32);
        pd += __shfl_down(pd, off, 32);
    }
    if ((t & 31) == 0) {
        a1s[n * NN_H + (t >> 5)] = ps;
        a1d[n * NN_H + (t >> 5)] = pd;
    }
}

// ---------------- CSR build ----------------
__global__ void count_kernel(const int* __restrict__ dst, int* __restrict__ deg,
                             int E, int Nn)
{
    int e = blockIdx.x * blockDim.x + threadIdx.x;
    int Et = E + Nn;
    if (e >= Et) return;
    int d = (e < E) ? dst[e] : (e - E);     // self-loops appended
    atomicAdd(&deg[d], 1);
}

#define SCAN_CHUNK 1024
__global__ __launch_bounds__(256) void scan1_kernel(
    const int* __restrict__ deg, int* __restrict__ offs,
    int* __restrict__ bsums, int Nn)
{
    __shared__ int sh[256];
    int b = blockIdx.x, t = threadIdx.x;
    int base = b * SCAN_CHUNK + t * 4;
    int v[4];
    int tot = 0;
    #pragma unroll
    for (int i = 0; i < 4; ++i) {
        v[i] = (base + i < Nn) ? deg[base + i] : 0;
        tot += v[i];
    }
    sh[t] = tot;
    __syncthreads();
    for (int off = 1; off < 256; off <<= 1) {
        int y = (t >= off) ? sh[t - off] : 0;
        __syncthreads();
        sh[t] += y;
        __syncthreads();
    }
    int p = sh[t] - tot;
    #pragma unroll
    for (int i = 0; i < 4; ++i) {
        if (base + i < Nn) offs[base + i] = p;
        p += v[i];
    }
    if (t == 255) bsums[b] = sh[255];
}

__global__ void scan2_kernel(int* __restrict__ bsums, int nb)
{
    if (threadIdx.x == 0) {
        int run = 0;
        for (int i = 0; i < nb; ++i) {
            int tmp = bsums[i];
            bsums[i] = run;
            run += tmp;
        }
    }
}

__global__ void scan3_kernel(int* __restrict__ offs, const int* __restrict__ bsums,
                             int Nn, int Et)
{
    int i = blockIdx.x * blockDim.x + threadIdx.x;
    if (i < Nn) offs[i] += bsums[i >> 10];
    if (i == 0) offs[Nn] = Et;
}

__global__ void fill_kernel(const int* __restrict__ src, const int* __restrict__ dst,
                            const int* __restrict__ offs, int* __restrict__ cursor,
                            int* __restrict__ srcs, int E, int Nn)
{
    int e = blockIdx.x * blockDim.x + threadIdx.x;
    int Et = E + Nn;
    if (e >= Et) return;
    int d, s;
    if (e < E) { d = dst[e]; s = src[e]; }
    else       { d = e - E;  s = e - E;  }
    int pos = offs[d] + atomicAdd(&cursor[d], 1);
    srcs[pos] = s;
}

// ---------------- layer-1 edge weights: alpha1[k][h] = softmax (4 nodes/block) ----
__global__ __launch_bounds__(256) void attw1_kernel(
    const float* __restrict__ a1s, const float* __restrict__ a1d,
    const int* __restrict__ offs, const int* __restrict__ srcs,
    float* __restrict__ alpha1, int Nn)
{
    int n = blockIdx.x * 4 + (threadIdx.x >> 6);
    if (n >= Nn) return;
    int lane = threadIdx.x & 63;
    int g = lane >> 3, h = lane & 7;        // 8 edge groups x 8 heads
    int beg = offs[n], end = offs[n + 1];
    float adn = a1d[n * NN_H + h];
    float m = -3.0e38f, s = 0.f;
    for (int k = beg + g; k < end; k += 8) {
        int sN = srcs[k];
        float e = a1s[sN * NN_H + h] + adn;
        e = e > 0.f ? e : 0.2f * e;
        float nm = fmaxf(m, e);
        float sc = __expf(m - nm);
        s = s * sc + __expf(e - nm);
        m = nm;
    }
    #pragma unroll
    for (int off = 8; off < 64; off <<= 1) {
        float mo = __shfl_xor(m, off);
        float so = __shfl_xor(s, off);
        float nm = fmaxf(m, mo);
        s = s * __expf(m - nm) + so * __expf(mo - nm);
        m = nm;
    }
    float inv = 1.f / (s + 1e-16f);
    for (int k = beg + g; k < end; k += 8) {
        int sN = srcs[k];
        float e = a1s[sN * NN_H + h] + adn;
        e = e > 0.f ? e : 0.2f * e;
        alpha1[(size_t)k * NN_H + h] = __expf(e - m) * inv;
    }
}

// ---------------- layer-1 aggregate: wave-per-node weighted gather + bias + ELU ----
// lane l covers features 4l..4l+3 (ushort4 = whole 512B row per wave); head = l>>3
__global__ __launch_bounds__(256) void agg1_kernel(
    const unsigned short* __restrict__ h1b, const float* __restrict__ alpha1,
    const int* __restrict__ offs, const int* __restrict__ srcs,
    const float* __restrict__ b1, unsigned short* __restrict__ hp1b, int Nn)
{
    int n = blockIdx.x * 4 + (threadIdx.x >> 6);
    if (n >= Nn) return;
    int lane = threadIdx.x & 63;
    int h = lane >> 3;
    int beg = offs[n], end = offs[n + 1];
    f32x4 a0 = {0.f,0.f,0.f,0.f}, a1 = a0, a2 = a0, a3 = a0;
    int k = beg;
    for (; k + 3 < end; k += 4) {
        int s0 = srcs[k], s1 = srcs[k+1], s2 = srcs[k+2], s3 = srcs[k+3];
        float w0 = alpha1[(size_t)k * NN_H + h];
        float w1 = alpha1[(size_t)(k+1) * NN_H + h];
        float w2 = alpha1[(size_t)(k+2) * NN_H + h];
        float w3 = alpha1[(size_t)(k+3) * NN_H + h];
        ushort4 v0 = *(const ushort4*)(h1b + (size_t)s0 * NN_HF + lane * 4);
        ushort4 v1 = *(const ushort4*)(h1b + (size_t)s1 * NN_HF + lane * 4);
        ushort4 v2 = *(const ushort4*)(h1b + (size_t)s2 * NN_HF + lane * 4);
        ushort4 v3 = *(const ushort4*)(h1b + (size_t)s3 * NN_HF + lane * 4);
        a0.x = fmaf(w0, bfu2f(v0.x), a0.x); a0.y = fmaf(w0, bfu2f(v0.y), a0.y);
        a0.z = fmaf(w0, bfu2f(v0.z), a0.z); a0.w = fmaf(w0, bfu2f(v0.w), a0.w);
        a1.x = fmaf(w1, bfu2f(v1.x), a1.x); a1.y = fmaf(w1, bfu2f(v1.y), a1.y);
        a1.z = fmaf(w1, bfu2f(v1.z), a1.z); a1.w = fmaf(w1, bfu2f(v1.w), a1.w);
        a2.x = fmaf(w2, bfu2f(v2.x), a2.x); a2.y = fmaf(w2, bfu2f(v2.y), a2.y);
        a2.z = fmaf(w2, bfu2f(v2.z), a2.z); a2.w = fmaf(w2, bfu2f(v2.w), a2.w);
        a3.x = fmaf(w3, bfu2f(v3.x), a3.x); a3.y = fmaf(w3, bfu2f(v3.y), a3.y);
        a3.z = fmaf(w3, bfu2f(v3.z), a3.z); a3.w = fmaf(w3, bfu2f(v3.w), a3.w);
    }
    for (; k < end; ++k) {
        int s0 = srcs[k];
        float w0 = alpha1[(size_t)k * NN_H + h];
        ushort4 v0 = *(const ushort4*)(h1b + (size_t)s0 * NN_HF + lane * 4);
        a0.x = fmaf(w0, bfu2f(v0.x), a0.x); a0.y = fmaf(w0, bfu2f(v0.y), a0.y);
        a0.z = fmaf(w0, bfu2f(v0.z), a0.z); a0.w = fmaf(w0, bfu2f(v0.w), a0.w);
    }
    f32x4 acc;
    acc[0] = (a0.x + a1.x) + (a2.x + a3.x);
    acc[1] = (a0.y + a1.y) + (a2.y + a3.y);
    acc[2] = (a0.z + a1.z) + (a2.z + a3.z);
    acc[3] = (a0.w + a1.w) + (a2.w + a3.w);
    float4 bb = *(const float4*)(b1 + lane * 4);
    float r0 = acc[0] + bb.x, r1 = acc[1] + bb.y;
    float r2 = acc[2] + bb.z, r3 = acc[3] + bb.w;
    r0 = r0 > 0.f ? r0 : __expf(r0) - 1.f;
    r1 = r1 > 0.f ? r1 : __expf(r1) - 1.f;
    r2 = r2 > 0.f ? r2 : __expf(r2) - 1.f;
    r3 = r3 > 0.f ? r3 : __expf(r3) - 1.f;
    ushort4 o = make_ushort4(f2bf_rne(r0), f2bf_rne(r1), f2bf_rne(r2), f2bf_rne(r3));
    *(ushort4*)(hp1b + (size_t)n * NN_HF + lane * 4) = o;
}

// ---------------- GEMM2: h2 = hp1 @ W2  (bf16 in, fp32 math), fused a2s/a2d ----
#define G2_ROWS 64
#define G2_KC   64

__global__ __launch_bounds__(256) void gemm2_kernel(
    const unsigned short* __restrict__ Ab, const float* __restrict__ W2,
    const float* __restrict__ att_s, const float* __restrict__ att_d,
    float* __restrict__ h2, float* __restrict__ a2s, float* __restrict__ a2d,
    int M)
{
    __shared__ float As[G2_ROWS][G2_KC + 1];
    __shared__ float Ws[G2_KC][NN_C];
    int m0 = blockIdx.x * G2_ROWS;
    int t = threadIdx.x;
    int rp = t >> 3;
    int cg = t & 7;
    int c0 = cg * 5;
    int r0 = rp * 2, r1 = r0 + 1;
    float acc[2][5] = {};
    for (int kc = 0; kc < NN_HF; kc += G2_KC) {
        #pragma unroll
        for (int i = 0; i < 4; ++i) {
            int g = t + i * 256;
            int r = g >> 4;
            int k4 = (g & 15) << 2;
            ushort4 v = make_ushort4(0, 0, 0, 0);
            if (m0 + r < M)
                v = *(const ushort4*)(Ab + (size_t)(m0 + r) * NN_HF + kc + k4);
            As[r][k4 + 0] = bfu2f(v.x); As[r][k4 + 1] = bfu2f(v.y);
            As[r][k4 + 2] = bfu2f(v.z); As[r][k4 + 3] = bfu2f(v.w);
        }
        #pragma unroll
        for (int i = 0; i < 10; ++i) {
            int g = t + i * 256;
            int k = g / NN_C, c = g % NN_C;
            Ws[k][c] = W2[(size_t)(kc + k) * NN_C + c];
        }
        __syncthreads();
        #pragma unroll 4
        for (int k = 0; k < G2_KC; ++k) {
            float a0 = As[r0][k];
            float a1 = As[r1][k];
            #pragma unroll
            for (int j = 0; j < 5; ++j) {
                float w = Ws[k][c0 + j];
                acc[0][j] += a0 * w;
                acc[1][j] += a1 * w;
            }
        }
        __syncthreads();
    }
    #pragma unroll
    for (int i = 0; i < 2; ++i) {
        int m = m0 + r0 + i;
        float ps = 0.f, pd = 0.f;
        #pragma unroll
        for (int j = 0; j < 5; ++j) {
            float v = acc[i][j];
            ps += v * att_s[c0 + j];
            pd += v * att_d[c0 + j];
            if (m < M) h2[(size_t)m * NN_C + c0 + j] = v;
        }
        #pragma unroll
        for (int off = 4; off >= 1; off >>= 1) {
            ps += __shfl_down(ps, off, 8);
            pd += __shfl_down(pd, off, 8);
        }
        if (cg == 0 && m < M) { a2s[m] = ps; a2d[m] = pd; }
    }
}

// ---------------- layer-2 edge weights (H=1, 4 nodes/block) ----------------
__global__ __launch_bounds__(256) void attw2_kernel(
    const float* __restrict__ a2s, const float* __restrict__ a2d,
    const int* __restrict__ offs, const int* __restrict__ srcs,
    float* __restrict__ alpha2, int Nn)
{
    int n = blockIdx.x * 4 + (threadIdx.x >> 6);
    if (n >= Nn) return;
    int lane = threadIdx.x & 63;
    int beg = offs[n], end = offs[n + 1];
    float adn = a2d[n];
    float m = -3.0e38f, s = 0.f;
    for (int k = beg + lane; k < end; k += 64) {
        int sN = srcs[k];
        float e = a2s[sN] + adn;
        e = e > 0.f ? e : 0.2f * e;
        float nm = fmaxf(m, e);
        float sc = __expf(m - nm);
        s = s * sc + __expf(e - nm);
        m = nm;
    }
    #pragma unroll
    for (int off = 1; off < 64; off <<= 1) {
        float mo = __shfl_xor(m, off);
        float so = __shfl_xor(s, off);
        float nm = fmaxf(m, mo);
        s = s * __expf(m - nm) + so * __expf(mo - nm);
        m = nm;
    }
    float inv = 1.f / (s + 1e-16f);
    for (int k = beg + lane; k < end; k += 64) {
        int sN = srcs[k];
        float e = a2s[sN] + adn;
        e = e > 0.f ? e : 0.2f * e;
        alpha2[k] = __expf(e - m) * inv;
    }
}

// ---------------- layer-2 aggregate: wave-per-node + bias + log_softmax ----------
__global__ __launch_bounds__(256) void agg2_kernel(
    const float* __restrict__ h2, const float* __restrict__ alpha2,
    const int* __restrict__ offs, const int* __restrict__ srcs,
    const float* __restrict__ b2, float* __restrict__ out, int Nn)
{
    int n = blockIdx.x * 4 + (threadIdx.x >> 6);
    if (n >= Nn) return;
    int f = threadIdx.x & 63;
    int beg = offs[n], end = offs[n + 1];
    float a0 = 0.f, a1 = 0.f, a2 = 0.f, a3 = 0.f;
    int k = beg;
    for (; k + 3 < end; k += 4) {
        int s0 = srcs[k], s1 = srcs[k+1], s2 = srcs[k+2], s3 = srcs[k+3];
        float w0 = alpha2[k], w1 = alpha2[k+1], w2 = alpha2[k+2], w3 = alpha2[k+3];
        float h0 = (f < NN_C) ? h2[(size_t)s0 * NN_C + f] : 0.f;
        float h1 = (f < NN_C) ? h2[(size_t)s1 * NN_C + f] : 0.f;
        float h2v = (f < NN_C) ? h2[(size_t)s2 * NN_C + f] : 0.f;
        float h3 = (f < NN_C) ? h2[(size_t)s3 * NN_C + f] : 0.f;
        a0 = fmaf(w0, h0, a0); a1 = fmaf(w1, h1, a1);
        a2 = fmaf(w2, h2v, a2); a3 = fmaf(w3, h3, a3);
    }
    for (; k < end; ++k) {
        int s0 = srcs[k];
        float w0 = alpha2[k];
        float h0 = (f < NN_C) ? h2[(size_t)s0 * NN_C + f] : 0.f;
        a0 = fmaf(w0, h0, a0);
    }
    float acc = (a0 + a1) + (a2 + a3);
    float v = acc + ((f < NN_C) ? b2[f] : 0.f);
    float lg = (f < NN_C) ? v : -INFINITY;
    float mx = lg;
    #pragma unroll
    for (int off = 32; off >= 1; off >>= 1) mx = fmaxf(mx, __shfl_xor(mx, off));
    float w2e = (f < NN_C) ? __expf(lg - mx) : 0.f;
    float sum = w2e;
    #pragma unroll
    for (int off = 32; off >= 1; off >>= 1) sum += __shfl_xor(sum, off);
    if (f < NN_C) out[(size_t)n * NN_C + f] = lg - mx - __logf(sum);
}

// ---------------- launcher ----------------
extern "C" void kernel_launch(void* const* d_in, const int* in_sizes, int n_in,
                              void* d_out, int out_size, void* d_ws, size_t ws_size,
                              hipStream_t stream)
{
    const float* x    = (const float*)d_in[0];
    const int*   ei   = (const int*)d_in[1];
    const float* W1   = (const float*)d_in[2];
    const float* as1  = (const float*)d_in[3];
    const float* ad1  = (const float*)d_in[4];
    const float* b1   = (const float*)d_in[5];
    const float* W2   = (const float*)d_in[6];
    const float* as2  = (const float*)d_in[7];
    const float* ad2  = (const float*)d_in[8];
    const float* b2   = (const float*)d_in[9];
    float* out = (float*)d_out;

    int Nn = in_sizes[0] / NN_DIN;      // 50000
    int E  = in_sizes[1] / 2;           // 800000
    int Et = E + Nn;
    const int* srcIdx = ei;
    const int* dstIdx = ei + E;

    char* ws = (char*)d_ws;
    size_t off = 0;
    auto alloc = [&](size_t bytes) {
        void* p = ws + off;
        off = (off + bytes + 255) & ~(size_t)255;
        return p;
    };
    unsigned short* h1b  = (unsigned short*)alloc((size_t)Nn * NN_HF * 2);
    unsigned short* W1T  = (unsigned short*)alloc((size_t)NN_HF * NN_DIN * 2);
    unsigned short* hp1b = (unsigned short*)alloc((size_t)Nn * NN_HF * 2);
    float* a1s  = (float*)alloc((size_t)Nn * NN_H * 4);
    float* a1d  = (float*)alloc((size_t)Nn * NN_H * 4);
    float* h2   = (float*)alloc((size_t)Nn * NN_C * 4);
    float* a2s  = (float*)alloc((size_t)Nn * 4);
    float* a2d  = (float*)alloc((size_t)Nn * 4);
    float* alpha1 = (float*)alloc((size_t)Et * NN_H * 4);
    float* alpha2 = (float*)alloc((size_t)Et * 4);
    int*   deg  = (int*)alloc((size_t)Nn * 4);
    int*   offs = (int*)alloc((size_t)(Nn + 1) * 4);
    int*   bsums= (int*)alloc(1024 * 4);
    int*   curs = (int*)alloc((size_t)Nn * 4);
    int*   srcs = (int*)alloc((size_t)Et * 4);

    hipMemsetAsync(deg, 0, (size_t)Nn * 4, stream);
    hipMemsetAsync(curs, 0, (size_t)Nn * 4, stream);

    // W1 transpose + RNE bf16
    w1rne_kernel<<<dim3(NN_DIN / 32, NN_HF / 32), 256, 0, stream>>>(W1, W1T);

    // GEMM1 (MFMA, single bf16 term) -> h1b
    dim3 g1((Nn + G1_BM - 1) / G1_BM, NN_HF / G1_BN);
    gemm1_kernel<<<g1, 256, 0, stream>>>(x, W1T, h1b, Nn);

    // attention coefficients
    attn1_kernel<<<Nn, 256, 0, stream>>>(h1b, as1, ad1, a1s, a1d);

    // CSR build
    count_kernel<<<(Et + 255) / 256, 256, 0, stream>>>(dstIdx, deg, E, Nn);
    int nb = (Nn + SCAN_CHUNK - 1) / SCAN_CHUNK;
    scan1_kernel<<<nb, 256, 0, stream>>>(deg, offs, bsums, Nn);
    scan2_kernel<<<1, 64, 0, stream>>>(bsums, nb);
    scan3_kernel<<<(Nn + 255) / 256, 256, 0, stream>>>(offs, bsums, Nn, Et);
    fill_kernel<<<(Et + 255) / 256, 256, 0, stream>>>(srcIdx, dstIdx, offs, curs, srcs, E, Nn);

    // layer-1 edge weights, then weighted aggregate (+bias+ELU) -> bf16
    attw1_kernel<<<(Nn + 3) / 4, 256, 0, stream>>>(a1s, a1d, offs, srcs, alpha1, Nn);
    agg1_kernel<<<(Nn + 3) / 4, 256, 0, stream>>>(h1b, alpha1, offs, srcs, b1, hp1b, Nn);

    // GEMM2 (+fused a2s/a2d)
    gemm2_kernel<<<(Nn + G2_ROWS - 1) / G2_ROWS, 256, 0, stream>>>(
        hp1b, W2, as2, ad2, h2, a2s, a2d, Nn);

    // layer-2 edge weights, then aggregate + bias + log_softmax
    attw2_kernel<<<(Nn + 3) / 4, 256, 0, stream>>>(a2s, a2d, offs, srcs, alpha2, Nn);
    agg2_kernel<<<(Nn + 3) / 4, 256, 0, stream>>>(h2, alpha2, offs, srcs, b2, out, Nn);
}

// Round 7
// 516.837 us; speedup vs baseline: 1.4230x; 1.0239x over previous
//
#include <hip/hip_runtime.h>
#include <hip/hip_bf16.h>
#include <math.h>

#define NN_DIN 512
#define NN_HF  256
#define NN_H   8
#define NN_F   32
#define NN_C   40

typedef short bf16x8 __attribute__((ext_vector_type(8)));
typedef float f32x4 __attribute__((ext_vector_type(4)));

__device__ __forceinline__ unsigned short f2bf_rne(float x) {
    unsigned u = __builtin_bit_cast(unsigned, x);
    unsigned r = u + 0x7FFFu + ((u >> 16) & 1u);
    return (unsigned short)(r >> 16);
}
__device__ __forceinline__ float bfu2f(unsigned short s) {
    unsigned u = ((unsigned)s) << 16;
    return __builtin_bit_cast(float, u);
}

// ---------------- W1 transpose + RNE bf16: [512][256] f32 -> [256][512] bf16 ----
__global__ __launch_bounds__(256) void w1rne_kernel(
    const float* __restrict__ W1, unsigned short* __restrict__ Wh)
{
    __shared__ float tile[32][33];
    int bk = blockIdx.x * 32;
    int bn = blockIdx.y * 32;
    int tx = threadIdx.x & 31, ty = threadIdx.x >> 5;   // ty 0..7
    #pragma unroll
    for (int i = 0; i < 32; i += 8)
        tile[ty + i][tx] = W1[(size_t)(bk + ty + i) * NN_HF + bn + tx];
    __syncthreads();
    #pragma unroll
    for (int i = 0; i < 32; i += 8) {
        float v = tile[tx][ty + i];
        Wh[(size_t)(bn + ty + i) * NN_DIN + bk + tx] = f2bf_rne(v);
    }
}

// ---------------- GEMM1 (MFMA, reg-prefetch dbuf): h1b = bf16(x @ W1) ----------
// tile 128x64, BK=64, 4 waves (2x2), each wave 64x32
#define G1_BM 128
#define G1_BN 64
#define G1_BK 64
#define G1_LDK 72   // padded row length (shorts); mult of 8 for 16B-aligned b128 reads

__global__ __launch_bounds__(256) void gemm1_kernel(
    const float* __restrict__ A, const unsigned short* __restrict__ BT,
    unsigned short* __restrict__ Cb, int M)
{
    __shared__ unsigned short Ah[G1_BM][G1_LDK];
    __shared__ unsigned short Bh[G1_BN][G1_LDK];
    const int m0 = blockIdx.x * G1_BM;
    const int n0 = blockIdx.y * G1_BN;
    const int tid = threadIdx.x;
    const int wave = tid >> 6, lane = tid & 63;
    const int wm = wave >> 1, wn = wave & 1;     // 2x2 wave grid, wave = 64 rows x 32 cols
    const int lr = lane & 15, lg = lane >> 4;    // frag index, k-group

    // per-thread staging coords (A: 8 float4 groups, B: 2 short8 groups)
    const int amr[8] = { (tid + 0*256) >> 4, (tid + 1*256) >> 4, (tid + 2*256) >> 4,
                         (tid + 3*256) >> 4, (tid + 4*256) >> 4, (tid + 5*256) >> 4,
                         (tid + 6*256) >> 4, (tid + 7*256) >> 4 };
    const int akc = (tid & 15) << 2;
    const int bnr0 = tid >> 3, bnr1 = (tid + 256) >> 3;
    const int bkc = (tid & 7) << 3;

    f32x4 acc[4][2];
    #pragma unroll
    for (int i = 0; i < 4; ++i)
        #pragma unroll
        for (int j = 0; j < 2; ++j) acc[i][j] = (f32x4){0.f, 0.f, 0.f, 0.f};

    float4 ra[8];
    bf16x8 rb[2];

    // prologue: fetch tile 0
    #pragma unroll
    for (int i = 0; i < 8; ++i) {
        ra[i] = make_float4(0.f, 0.f, 0.f, 0.f);
        if (m0 + amr[i] < M)
            ra[i] = *(const float4*)(A + (size_t)(m0 + amr[i]) * NN_DIN + akc);
    }
    rb[0] = *(const bf16x8*)(BT + (size_t)(n0 + bnr0) * NN_DIN + bkc);
    rb[1] = *(const bf16x8*)(BT + (size_t)(n0 + bnr1) * NN_DIN + bkc);
    #pragma unroll
    for (int i = 0; i < 8; ++i) {
        ushort4 hv;
        hv.x = f2bf_rne(ra[i].x); hv.y = f2bf_rne(ra[i].y);
        hv.z = f2bf_rne(ra[i].z); hv.w = f2bf_rne(ra[i].w);
        *reinterpret_cast<ushort4*>(&Ah[amr[i]][akc]) = hv;
    }
    *reinterpret_cast<bf16x8*>(&Bh[bnr0][bkc]) = rb[0];
    *reinterpret_cast<bf16x8*>(&Bh[bnr1][bkc]) = rb[1];
    __syncthreads();

    const int NSTEP = NN_DIN / G1_BK;   // 8
    for (int step = 0; step < NSTEP; ++step) {
        const bool last = (step == NSTEP - 1);
        // issue next tile's global loads early (latency hides under compute)
        if (!last) {
            int k0 = (step + 1) * G1_BK;
            #pragma unroll
            for (int i = 0; i < 8; ++i) {
                ra[i] = make_float4(0.f, 0.f, 0.f, 0.f);
                if (m0 + amr[i] < M)
                    ra[i] = *(const float4*)(A + (size_t)(m0 + amr[i]) * NN_DIN + k0 + akc);
            }
            rb[0] = *(const bf16x8*)(BT + (size_t)(n0 + bnr0) * NN_DIN + k0 + bkc);
            rb[1] = *(const bf16x8*)(BT + (size_t)(n0 + bnr1) * NN_DIN + k0 + bkc);
        }
        // compute current tile from LDS
        #pragma unroll
        for (int ks = 0; ks < 2; ++ks) {
            const int kb = (ks << 5) + (lg << 3);
            bf16x8 fah[4], fbh[2];
            #pragma unroll
            for (int mi = 0; mi < 4; ++mi) {
                int m = (wm << 6) + (mi << 4) + lr;
                fah[mi] = *reinterpret_cast<const bf16x8*>(&Ah[m][kb]);
            }
            #pragma unroll
            for (int ni = 0; ni < 2; ++ni) {
                int n = (wn << 5) + (ni << 4) + lr;
                fbh[ni] = *reinterpret_cast<const bf16x8*>(&Bh[n][kb]);
            }
            #pragma unroll
            for (int mi = 0; mi < 4; ++mi)
                #pragma unroll
                for (int ni = 0; ni < 2; ++ni)
                    acc[mi][ni] = __builtin_amdgcn_mfma_f32_16x16x32_bf16(
                        fah[mi], fbh[ni], acc[mi][ni], 0, 0, 0);
        }
        __syncthreads();
        // write next tile into LDS
        if (!last) {
            #pragma unroll
            for (int i = 0; i < 8; ++i) {
                ushort4 hv;
                hv.x = f2bf_rne(ra[i].x); hv.y = f2bf_rne(ra[i].y);
                hv.z = f2bf_rne(ra[i].z); hv.w = f2bf_rne(ra[i].w);
                *reinterpret_cast<ushort4*>(&Ah[amr[i]][akc]) = hv;
            }
            *reinterpret_cast<bf16x8*>(&Bh[bnr0][bkc]) = rb[0];
            *reinterpret_cast<bf16x8*>(&Bh[bnr1][bkc]) = rb[1];
            __syncthreads();
        }
    }
    // epilogue: C/D frag mapping row=(lane>>4)*4+r, col=lane&15
    #pragma unroll
    for (int mi = 0; mi < 4; ++mi)
        #pragma unroll
        for (int ni = 0; ni < 2; ++ni)
            #pragma unroll
            for (int r = 0; r < 4; ++r) {
                int row = m0 + (wm << 6) + (mi << 4) + (lg << 2) + r;
                int col = n0 + (wn << 5) + (ni << 4) + lr;
                if (row < M)
                    Cb[(size_t)row * NN_HF + col] = f2bf_rne(acc[mi][ni][r]);
            }
}

// ---------------- attention coefficients layer 1 (reads bf16 h1) ----------------
__global__ __launch_bounds__(256) void attn1_kernel(
    const unsigned short* __restrict__ h1b, const float* __restrict__ att_s,
    const float* __restrict__ att_d, float* __restrict__ a1s,
    float* __restrict__ a1d)
{
    int n = blockIdx.x;
    int t = threadIdx.x;            // t = h*32 + f
    float hv = bfu2f(h1b[(size_t)n * NN_HF + t]);
    float ps = hv * att_s[t];
    float pd = hv * att_d[t];
    #pragma unroll
    for (int off = 16; off >= 1; off >>= 1) {
        ps += __shfl_down(ps, off, 32);
        pd += __shfl_down(pd, off, 32);
    }
    if ((t & 31) == 0) {
        a1s[n * NN_H + (t >> 5)] = ps;
        a1d[n * NN_H + (t >> 5)] = pd;
    }
}

// ---------------- CSR build ----------------
__global__ void count_kernel(const int* __restrict__ dst, int* __restrict__ deg,
                             int E, int Nn)
{
    int e = blockIdx.x * blockDim.x + threadIdx.x;
    int Et = E + Nn;
    if (e >= Et) return;
    int d = (e < E) ? dst[e] : (e - E);     // self-loops appended
    atomicAdd(&deg[d], 1);
}

#define SCAN_CHUNK 1024
__global__ __launch_bounds__(256) void scan1_kernel(
    const int* __restrict__ deg, int* __restrict__ offs,
    int* __restrict__ bsums, int Nn)
{
    __shared__ int sh[256];
    int b = blockIdx.x, t = threadIdx.x;
    int base = b * SCAN_CHUNK + t * 4;
    int v[4];
    int tot = 0;
    #pragma unroll
    for (int i = 0; i < 4; ++i) {
        v[i] = (base + i < Nn) ? deg[base + i] : 0;
        tot += v[i];
    }
    sh[t] = tot;
    __syncthreads();
    for (int off = 1; off < 256; off <<= 1) {
        int y = (t >= off) ? sh[t - off] : 0;
        __syncthreads();
        sh[t] += y;
        __syncthreads();
    }
    int p = sh[t] - tot;
    #pragma unroll
    for (int i = 0; i < 4; ++i) {
        if (base + i < Nn) offs[base + i] = p;
        p += v[i];
    }
    if (t == 255) bsums[b] = sh[255];
}

__global__ void scan2_kernel(int* __restrict__ bsums, int nb)
{
    if (threadIdx.x == 0) {
        int run = 0;
        for (int i = 0; i < nb; ++i) {
            int tmp = bsums[i];
            bsums[i] = run;
            run += tmp;
        }
    }
}

__global__ void scan3_kernel(int* __restrict__ offs, const int* __restrict__ bsums,
                             int Nn, int Et)
{
    int i = blockIdx.x * blockDim.x + threadIdx.x;
    if (i < Nn) offs[i] += bsums[i >> 10];
    if (i == 0) offs[Nn] = Et;
}

__global__ void fill_kernel(const int* __restrict__ src, const int* __restrict__ dst,
                            const int* __restrict__ offs, int* __restrict__ cursor,
                            int* __restrict__ srcs, int E, int Nn)
{
    int e = blockIdx.x * blockDim.x + threadIdx.x;
    int Et = E + Nn;
    if (e >= Et) return;
    int d, s;
    if (e < E) { d = dst[e]; s = src[e]; }
    else       { d = e - E;  s = e - E;  }
    int pos = offs[d] + atomicAdd(&cursor[d], 1);
    srcs[pos] = s;
}

// ---------------- layer-1 edge weights: alpha1[k][h] = softmax (4 nodes/block) ----
__global__ __launch_bounds__(256) void attw1_kernel(
    const float* __restrict__ a1s, const float* __restrict__ a1d,
    const int* __restrict__ offs, const int* __restrict__ srcs,
    float* __restrict__ alpha1, int Nn)
{
    int n = blockIdx.x * 4 + (threadIdx.x >> 6);
    if (n >= Nn) return;
    int lane = threadIdx.x & 63;
    int g = lane >> 3, h = lane & 7;        // 8 edge groups x 8 heads
    int beg = offs[n], end = offs[n + 1];
    float adn = a1d[n * NN_H + h];
    float m = -3.0e38f, s = 0.f;
    for (int k = beg + g; k < end; k += 8) {
        int sN = srcs[k];
        float e = a1s[sN * NN_H + h] + adn;
        e = e > 0.f ? e : 0.2f * e;
        float nm = fmaxf(m, e);
        float sc = __expf(m - nm);
        s = s * sc + __expf(e - nm);
        m = nm;
    }
    #pragma unroll
    for (int off = 8; off < 64; off <<= 1) {
        float mo = __shfl_xor(m, off);
        float so = __shfl_xor(s, off);
        float nm = fmaxf(m, mo);
        s = s * __expf(m - nm) + so * __expf(mo - nm);
        m = nm;
    }
    float inv = 1.f / (s + 1e-16f);
    for (int k = beg + g; k < end; k += 8) {
        int sN = srcs[k];
        float e = a1s[sN * NN_H + h] + adn;
        e = e > 0.f ? e : 0.2f * e;
        alpha1[(size_t)k * NN_H + h] = __expf(e - m) * inv;
    }
}

// ---------------- layer-1 aggregate: wave-per-node weighted gather + bias + ELU ----
// lane l covers features 4l..4l+3 (ushort4 = whole 512B row per wave); head = l>>3
__global__ __launch_bounds__(256) void agg1_kernel(
    const unsigned short* __restrict__ h1b, const float* __restrict__ alpha1,
    const int* __restrict__ offs, const int* __restrict__ srcs,
    const float* __restrict__ b1, unsigned short* __restrict__ hp1b, int Nn)
{
    int n = blockIdx.x * 4 + (threadIdx.x >> 6);
    if (n >= Nn) return;
    int lane = threadIdx.x & 63;
    int h = lane >> 3;
    int beg = offs[n], end = offs[n + 1];
    f32x4 a0 = {0.f,0.f,0.f,0.f}, a1 = a0, a2 = a0, a3 = a0;
    int k = beg;
    for (; k + 3 < end; k += 4) {
        int s0 = srcs[k], s1 = srcs[k+1], s2 = srcs[k+2], s3 = srcs[k+3];
        float w0 = alpha1[(size_t)k * NN_H + h];
        float w1 = alpha1[(size_t)(k+1) * NN_H + h];
        float w2 = alpha1[(size_t)(k+2) * NN_H + h];
        float w3 = alpha1[(size_t)(k+3) * NN_H + h];
        ushort4 v0 = *(const ushort4*)(h1b + (size_t)s0 * NN_HF + lane * 4);
        ushort4 v1 = *(const ushort4*)(h1b + (size_t)s1 * NN_HF + lane * 4);
        ushort4 v2 = *(const ushort4*)(h1b + (size_t)s2 * NN_HF + lane * 4);
        ushort4 v3 = *(const ushort4*)(h1b + (size_t)s3 * NN_HF + lane * 4);
        a0.x = fmaf(w0, bfu2f(v0.x), a0.x); a0.y = fmaf(w0, bfu2f(v0.y), a0.y);
        a0.z = fmaf(w0, bfu2f(v0.z), a0.z); a0.w = fmaf(w0, bfu2f(v0.w), a0.w);
        a1.x = fmaf(w1, bfu2f(v1.x), a1.x); a1.y = fmaf(w1, bfu2f(v1.y), a1.y);
        a1.z = fmaf(w1, bfu2f(v1.z), a1.z); a1.w = fmaf(w1, bfu2f(v1.w), a1.w);
        a2.x = fmaf(w2, bfu2f(v2.x), a2.x); a2.y = fmaf(w2, bfu2f(v2.y), a2.y);
        a2.z = fmaf(w2, bfu2f(v2.z), a2.z); a2.w = fmaf(w2, bfu2f(v2.w), a2.w);
        a3.x = fmaf(w3, bfu2f(v3.x), a3.x); a3.y = fmaf(w3, bfu2f(v3.y), a3.y);
        a3.z = fmaf(w3, bfu2f(v3.z), a3.z); a3.w = fmaf(w3, bfu2f(v3.w), a3.w);
    }
    for (; k < end; ++k) {
        int s0 = srcs[k];
        float w0 = alpha1[(size_t)k * NN_H + h];
        ushort4 v0 = *(const ushort4*)(h1b + (size_t)s0 * NN_HF + lane * 4);
        a0.x = fmaf(w0, bfu2f(v0.x), a0.x); a0.y = fmaf(w0, bfu2f(v0.y), a0.y);
        a0.z = fmaf(w0, bfu2f(v0.z), a0.z); a0.w = fmaf(w0, bfu2f(v0.w), a0.w);
    }
    f32x4 acc;
    acc[0] = (a0.x + a1.x) + (a2.x + a3.x);
    acc[1] = (a0.y + a1.y) + (a2.y + a3.y);
    acc[2] = (a0.z + a1.z) + (a2.z + a3.z);
    acc[3] = (a0.w + a1.w) + (a2.w + a3.w);
    float4 bb = *(const float4*)(b1 + lane * 4);
    float r0 = acc[0] + bb.x, r1 = acc[1] + bb.y;
    float r2 = acc[2] + bb.z, r3 = acc[3] + bb.w;
    r0 = r0 > 0.f ? r0 : __expf(r0) - 1.f;
    r1 = r1 > 0.f ? r1 : __expf(r1) - 1.f;
    r2 = r2 > 0.f ? r2 : __expf(r2) - 1.f;
    r3 = r3 > 0.f ? r3 : __expf(r3) - 1.f;
    ushort4 o = make_ushort4(f2bf_rne(r0), f2bf_rne(r1), f2bf_rne(r2), f2bf_rne(r3));
    *(ushort4*)(hp1b + (size_t)n * NN_HF + lane * 4) = o;
}

// ---------------- GEMM2: h2 = hp1 @ W2  (bf16 in, fp32 math), fused a2s/a2d ----
#define G2_ROWS 64
#define G2_KC   64

__global__ __launch_bounds__(256) void gemm2_kernel(
    const unsigned short* __restrict__ Ab, const float* __restrict__ W2,
    const float* __restrict__ att_s, const float* __restrict__ att_d,
    float* __restrict__ h2, float* __restrict__ a2s, float* __restrict__ a2d,
    int M)
{
    __shared__ float As[G2_ROWS][G2_KC + 1];
    __shared__ float Ws[G2_KC][NN_C];
    int m0 = blockIdx.x * G2_ROWS;
    int t = threadIdx.x;
    int rp = t >> 3;
    int cg = t & 7;
    int c0 = cg * 5;
    int r0 = rp * 2, r1 = r0 + 1;
    float acc[2][5] = {};
    for (int kc = 0; kc < NN_HF; kc += G2_KC) {
        #pragma unroll
        for (int i = 0; i < 4; ++i) {
            int g = t + i * 256;
            int r = g >> 4;
            int k4 = (g & 15) << 2;
            ushort4 v = make_ushort4(0, 0, 0, 0);
            if (m0 + r < M)
                v = *(const ushort4*)(Ab + (size_t)(m0 + r) * NN_HF + kc + k4);
            As[r][k4 + 0] = bfu2f(v.x); As[r][k4 + 1] = bfu2f(v.y);
            As[r][k4 + 2] = bfu2f(v.z); As[r][k4 + 3] = bfu2f(v.w);
        }
        #pragma unroll
        for (int i = 0; i < 10; ++i) {
            int g = t + i * 256;
            int k = g / NN_C, c = g % NN_C;
            Ws[k][c] = W2[(size_t)(kc + k) * NN_C + c];
        }
        __syncthreads();
        #pragma unroll 4
        for (int k = 0; k < G2_KC; ++k) {
            float a0 = As[r0][k];
            float a1 = As[r1][k];
            #pragma unroll
            for (int j = 0; j < 5; ++j) {
                float w = Ws[k][c0 + j];
                acc[0][j] += a0 * w;
                acc[1][j] += a1 * w;
            }
        }
        __syncthreads();
    }
    #pragma unroll
    for (int i = 0; i < 2; ++i) {
        int m = m0 + r0 + i;
        float ps = 0.f, pd = 0.f;
        #pragma unroll
        for (int j = 0; j < 5; ++j) {
            float v = acc[i][j];
            ps += v * att_s[c0 + j];
            pd += v * att_d[c0 + j];
            if (m < M) h2[(size_t)m * NN_C + c0 + j] = v;
        }
        #pragma unroll
        for (int off = 4; off >= 1; off >>= 1) {
            ps += __shfl_down(ps, off, 8);
            pd += __shfl_down(pd, off, 8);
        }
        if (cg == 0 && m < M) { a2s[m] = ps; a2d[m] = pd; }
    }
}

// ---------------- layer-2 edge weights (H=1, 4 nodes/block) ----------------
__global__ __launch_bounds__(256) void attw2_kernel(
    const float* __restrict__ a2s, const float* __restrict__ a2d,
    const int* __restrict__ offs, const int* __restrict__ srcs,
    float* __restrict__ alpha2, int Nn)
{
    int n = blockIdx.x * 4 + (threadIdx.x >> 6);
    if (n >= Nn) return;
    int lane = threadIdx.x & 63;
    int beg = offs[n], end = offs[n + 1];
    float adn = a2d[n];
    float m = -3.0e38f, s = 0.f;
    for (int k = beg + lane; k < end; k += 64) {
        int sN = srcs[k];
        float e = a2s[sN] + adn;
        e = e > 0.f ? e : 0.2f * e;
        float nm = fmaxf(m, e);
        float sc = __expf(m - nm);
        s = s * sc + __expf(e - nm);
        m = nm;
    }
    #pragma unroll
    for (int off = 1; off < 64; off <<= 1) {
        float mo = __shfl_xor(m, off);
        float so = __shfl_xor(s, off);
        float nm = fmaxf(m, mo);
        s = s * __expf(m - nm) + so * __expf(mo - nm);
        m = nm;
    }
    float inv = 1.f / (s + 1e-16f);
    for (int k = beg + lane; k < end; k += 64) {
        int sN = srcs[k];
        float e = a2s[sN] + adn;
        e = e > 0.f ? e : 0.2f * e;
        alpha2[k] = __expf(e - m) * inv;
    }
}

// ---------------- layer-2 aggregate: wave-per-node + bias + log_softmax ----------
__global__ __launch_bounds__(256) void agg2_kernel(
    const float* __restrict__ h2, const float* __restrict__ alpha2,
    const int* __restrict__ offs, const int* __restrict__ srcs,
    const float* __restrict__ b2, float* __restrict__ out, int Nn)
{
    int n = blockIdx.x * 4 + (threadIdx.x >> 6);
    if (n >= Nn) return;
    int f = threadIdx.x & 63;
    int beg = offs[n], end = offs[n + 1];
    float a0 = 0.f, a1 = 0.f, a2 = 0.f, a3 = 0.f;
    int k = beg;
    for (; k + 3 < end; k += 4) {
        int s0 = srcs[k], s1 = srcs[k+1], s2 = srcs[k+2], s3 = srcs[k+3];
        float w0 = alpha2[k], w1 = alpha2[k+1], w2 = alpha2[k+2], w3 = alpha2[k+3];
        float h0 = (f < NN_C) ? h2[(size_t)s0 * NN_C + f] : 0.f;
        float h1 = (f < NN_C) ? h2[(size_t)s1 * NN_C + f] : 0.f;
        float h2v = (f < NN_C) ? h2[(size_t)s2 * NN_C + f] : 0.f;
        float h3 = (f < NN_C) ? h2[(size_t)s3 * NN_C + f] : 0.f;
        a0 = fmaf(w0, h0, a0); a1 = fmaf(w1, h1, a1);
        a2 = fmaf(w2, h2v, a2); a3 = fmaf(w3, h3, a3);
    }
    for (; k < end; ++k) {
        int s0 = srcs[k];
        float w0 = alpha2[k];
        float h0 = (f < NN_C) ? h2[(size_t)s0 * NN_C + f] : 0.f;
        a0 = fmaf(w0, h0, a0);
    }
    float acc = (a0 + a1) + (a2 + a3);
    float v = acc + ((f < NN_C) ? b2[f] : 0.f);
    float lg = (f < NN_C) ? v : -INFINITY;
    float mx = lg;
    #pragma unroll
    for (int off = 32; off >= 1; off >>= 1) mx = fmaxf(mx, __shfl_xor(mx, off));
    float w2e = (f < NN_C) ? __expf(lg - mx) : 0.f;
    float sum = w2e;
    #pragma unroll
    for (int off = 32; off >= 1; off >>= 1) sum += __shfl_xor(sum, off);
    if (f < NN_C) out[(size_t)n * NN_C + f] = lg - mx - __logf(sum);
}

// ---------------- launcher ----------------
extern "C" void kernel_launch(void* const* d_in, const int* in_sizes, int n_in,
                              void* d_out, int out_size, void* d_ws, size_t ws_size,
                              hipStream_t stream)
{
    const float* x    = (const float*)d_in[0];
    const int*   ei   = (const int*)d_in[1];
    const float* W1   = (const float*)d_in[2];
    const float* as1  = (const float*)d_in[3];
    const float* ad1  = (const float*)d_in[4];
    const float* b1   = (const float*)d_in[5];
    const float* W2   = (const float*)d_in[6];
    const float* as2  = (const float*)d_in[7];
    const float* ad2  = (const float*)d_in[8];
    const float* b2   = (const float*)d_in[9];
    float* out = (float*)d_out;

    int Nn = in_sizes[0] / NN_DIN;      // 50000
    int E  = in_sizes[1] / 2;           // 800000
    int Et = E + Nn;
    const int* srcIdx = ei;
    const int* dstIdx = ei + E;

    char* ws = (char*)d_ws;
    size_t off = 0;
    auto alloc = [&](size_t bytes) {
        void* p = ws + off;
        off = (off + bytes + 255) & ~(size_t)255;
        return p;
    };
    unsigned short* h1b  = (unsigned short*)alloc((size_t)Nn * NN_HF * 2);
    unsigned short* W1T  = (unsigned short*)alloc((size_t)NN_HF * NN_DIN * 2);
    unsigned short* hp1b = (unsigned short*)alloc((size_t)Nn * NN_HF * 2);
    float* a1s  = (float*)alloc((size_t)Nn * NN_H * 4);
    float* a1d  = (float*)alloc((size_t)Nn * NN_H * 4);
    float* h2   = (float*)alloc((size_t)Nn * NN_C * 4);
    float* a2s  = (float*)alloc((size_t)Nn * 4);
    float* a2d  = (float*)alloc((size_t)Nn * 4);
    float* alpha1 = (float*)alloc((size_t)Et * NN_H * 4);
    float* alpha2 = (float*)alloc((size_t)Et * 4);
    int*   deg  = (int*)alloc((size_t)Nn * 4);
    int*   offs = (int*)alloc((size_t)(Nn + 1) * 4);
    int*   bsums= (int*)alloc(1024 * 4);
    int*   curs = (int*)alloc((size_t)Nn * 4);
    int*   srcs = (int*)alloc((size_t)Et * 4);

    hipMemsetAsync(deg, 0, (size_t)Nn * 4, stream);
    hipMemsetAsync(curs, 0, (size_t)Nn * 4, stream);

    // W1 transpose + RNE bf16
    w1rne_kernel<<<dim3(NN_DIN / 32, NN_HF / 32), 256, 0, stream>>>(W1, W1T);

    // GEMM1 (MFMA, reg-prefetch dbuf) -> h1b
    dim3 g1((Nn + G1_BM - 1) / G1_BM, NN_HF / G1_BN);
    gemm1_kernel<<<g1, 256, 0, stream>>>(x, W1T, h1b, Nn);

    // attention coefficients
    attn1_kernel<<<Nn, 256, 0, stream>>>(h1b, as1, ad1, a1s, a1d);

    // CSR build
    count_kernel<<<(Et + 255) / 256, 256, 0, stream>>>(dstIdx, deg, E, Nn);
    int nb = (Nn + SCAN_CHUNK - 1) / SCAN_CHUNK;
    scan1_kernel<<<nb, 256, 0, stream>>>(deg, offs, bsums, Nn);
    scan2_kernel<<<1, 64, 0, stream>>>(bsums, nb);
    scan3_kernel<<<(Nn + 255) / 256, 256, 0, stream>>>(offs, bsums, Nn, Et);
    fill_kernel<<<(Et + 255) / 256, 256, 0, stream>>>(srcIdx, dstIdx, offs, curs, srcs, E, Nn);

    // layer-1 edge weights, then weighted aggregate (+bias+ELU) -> bf16
    attw1_kernel<<<(Nn + 3) / 4, 256, 0, stream>>>(a1s, a1d, offs, srcs, alpha1, Nn);
    agg1_kernel<<<(Nn + 3) / 4, 256, 0, stream>>>(h1b, alpha1, offs, srcs, b1, hp1b, Nn);

    // GEMM2 (+fused a2s/a2d)
    gemm2_kernel<<<(Nn + G2_ROWS - 1) / G2_ROWS, 256, 0, stream>>>(
        hp1b, W2, as2, ad2, h2, a2s, a2d, Nn);

    // layer-2 edge weights, then aggregate + bias + log_softmax
    attw2_kernel<<<(Nn + 3) / 4, 256, 0, stream>>>(a2s, a2d, offs, srcs, alpha2, Nn);
    agg2_kernel<<<(Nn + 3) / 4, 256, 0, stream>>>(h2, alpha2, offs, srcs, b2, out, Nn);
}

// Round 8
// 494.318 us; speedup vs baseline: 1.4879x; 1.0456x over previous
//
#include <hip/hip_runtime.h>
#include <hip/hip_bf16.h>
#include <math.h>

#define NN_DIN 512
#define NN_HF  256
#define NN_H   8
#define NN_F   32
#define NN_C   40

typedef short bf16x8 __attribute__((ext_vector_type(8)));
typedef float f32x4 __attribute__((ext_vector_type(4)));

__device__ __forceinline__ unsigned short f2bf_rne(float x) {
    unsigned u = __builtin_bit_cast(unsigned, x);
    unsigned r = u + 0x7FFFu + ((u >> 16) & 1u);
    return (unsigned short)(r >> 16);
}
__device__ __forceinline__ float bfu2f(unsigned short s) {
    unsigned u = ((unsigned)s) << 16;
    return __builtin_bit_cast(float, u);
}

// ---------------- W1 transpose + RNE bf16: [512][256] f32 -> [256][512] bf16 ----
__global__ __launch_bounds__(256) void w1rne_kernel(
    const float* __restrict__ W1, unsigned short* __restrict__ Wh)
{
    __shared__ float tile[32][33];
    int bk = blockIdx.x * 32;
    int bn = blockIdx.y * 32;
    int tx = threadIdx.x & 31, ty = threadIdx.x >> 5;   // ty 0..7
    #pragma unroll
    for (int i = 0; i < 32; i += 8)
        tile[ty + i][tx] = W1[(size_t)(bk + ty + i) * NN_HF + bn + tx];
    __syncthreads();
    #pragma unroll
    for (int i = 0; i < 32; i += 8) {
        float v = tile[tx][ty + i];
        Wh[(size_t)(bn + ty + i) * NN_DIN + bk + tx] = f2bf_rne(v);
    }
}

// ---------------- GEMM1 (MFMA, reg-prefetch dbuf, x read ONCE): h1b = bf16(x@W1) ----
// tile 64x256 (full N), BK=64, 4 waves 1x4, each wave 64x64
#define G1_BM 64
#define G1_BN 256
#define G1_BK 64
#define G1_LDK 72   // padded row length (shorts); mult of 8 for 16B-aligned b128 reads

__global__ __launch_bounds__(256) void gemm1_kernel(
    const float* __restrict__ A, const unsigned short* __restrict__ BT,
    unsigned short* __restrict__ Cb, int M)
{
    __shared__ unsigned short Ah[G1_BM][G1_LDK];
    __shared__ unsigned short Bh[G1_BN][G1_LDK];
    const int m0 = blockIdx.x * G1_BM;
    const int tid = threadIdx.x;
    const int wave = tid >> 6, lane = tid & 63;
    const int wn = wave;                          // 1x4 wave grid, wave = 64 rows x 64 cols
    const int lr = lane & 15, lg = lane >> 4;     // frag index, k-group

    // per-thread staging coords (A: 4 float4 groups, B: 8 short8 groups)
    const int amr[4] = { (tid + 0*256) >> 4, (tid + 1*256) >> 4,
                         (tid + 2*256) >> 4, (tid + 3*256) >> 4 };
    const int akc = (tid & 15) << 2;
    const int bnr[8] = { (tid + 0*256) >> 3, (tid + 1*256) >> 3,
                         (tid + 2*256) >> 3, (tid + 3*256) >> 3,
                         (tid + 4*256) >> 3, (tid + 5*256) >> 3,
                         (tid + 6*256) >> 3, (tid + 7*256) >> 3 };
    const int bkc = (tid & 7) << 3;

    f32x4 acc[4][4];
    #pragma unroll
    for (int i = 0; i < 4; ++i)
        #pragma unroll
        for (int j = 0; j < 4; ++j) acc[i][j] = (f32x4){0.f, 0.f, 0.f, 0.f};

    float4 ra[4];
    bf16x8 rb[8];

    // prologue: fetch tile 0
    #pragma unroll
    for (int i = 0; i < 4; ++i) {
        ra[i] = make_float4(0.f, 0.f, 0.f, 0.f);
        if (m0 + amr[i] < M)
            ra[i] = *(const float4*)(A + (size_t)(m0 + amr[i]) * NN_DIN + akc);
    }
    #pragma unroll
    for (int i = 0; i < 8; ++i)
        rb[i] = *(const bf16x8*)(BT + (size_t)bnr[i] * NN_DIN + bkc);
    #pragma unroll
    for (int i = 0; i < 4; ++i) {
        ushort4 hv;
        hv.x = f2bf_rne(ra[i].x); hv.y = f2bf_rne(ra[i].y);
        hv.z = f2bf_rne(ra[i].z); hv.w = f2bf_rne(ra[i].w);
        *reinterpret_cast<ushort4*>(&Ah[amr[i]][akc]) = hv;
    }
    #pragma unroll
    for (int i = 0; i < 8; ++i)
        *reinterpret_cast<bf16x8*>(&Bh[bnr[i]][bkc]) = rb[i];
    __syncthreads();

    const int NSTEP = NN_DIN / G1_BK;   // 8
    for (int step = 0; step < NSTEP; ++step) {
        const bool last = (step == NSTEP - 1);
        // issue next tile's global loads early (latency hides under compute)
        if (!last) {
            int k0 = (step + 1) * G1_BK;
            #pragma unroll
            for (int i = 0; i < 4; ++i) {
                ra[i] = make_float4(0.f, 0.f, 0.f, 0.f);
                if (m0 + amr[i] < M)
                    ra[i] = *(const float4*)(A + (size_t)(m0 + amr[i]) * NN_DIN + k0 + akc);
            }
            #pragma unroll
            for (int i = 0; i < 8; ++i)
                rb[i] = *(const bf16x8*)(BT + (size_t)bnr[i] * NN_DIN + k0 + bkc);
        }
        // compute current tile from LDS
        #pragma unroll
        for (int ks = 0; ks < 2; ++ks) {
            const int kb = (ks << 5) + (lg << 3);
            bf16x8 fah[4], fbh[4];
            #pragma unroll
            for (int mi = 0; mi < 4; ++mi) {
                int m = (mi << 4) + lr;
                fah[mi] = *reinterpret_cast<const bf16x8*>(&Ah[m][kb]);
            }
            #pragma unroll
            for (int ni = 0; ni < 4; ++ni) {
                int n = (wn << 6) + (ni << 4) + lr;
                fbh[ni] = *reinterpret_cast<const bf16x8*>(&Bh[n][kb]);
            }
            #pragma unroll
            for (int mi = 0; mi < 4; ++mi)
                #pragma unroll
                for (int ni = 0; ni < 4; ++ni)
                    acc[mi][ni] = __builtin_amdgcn_mfma_f32_16x16x32_bf16(
                        fah[mi], fbh[ni], acc[mi][ni], 0, 0, 0);
        }
        __syncthreads();
        // write next tile into LDS
        if (!last) {
            #pragma unroll
            for (int i = 0; i < 4; ++i) {
                ushort4 hv;
                hv.x = f2bf_rne(ra[i].x); hv.y = f2bf_rne(ra[i].y);
                hv.z = f2bf_rne(ra[i].z); hv.w = f2bf_rne(ra[i].w);
                *reinterpret_cast<ushort4*>(&Ah[amr[i]][akc]) = hv;
            }
            #pragma unroll
            for (int i = 0; i < 8; ++i)
                *reinterpret_cast<bf16x8*>(&Bh[bnr[i]][bkc]) = rb[i];
            __syncthreads();
        }
    }
    // epilogue: C/D frag mapping row=(lane>>4)*4+r, col=lane&15
    #pragma unroll
    for (int mi = 0; mi < 4; ++mi)
        #pragma unroll
        for (int ni = 0; ni < 4; ++ni)
            #pragma unroll
            for (int r = 0; r < 4; ++r) {
                int row = m0 + (mi << 4) + (lg << 2) + r;
                int col = (wn << 6) + (ni << 4) + lr;
                if (row < M)
                    Cb[(size_t)row * NN_HF + col] = f2bf_rne(acc[mi][ni][r]);
            }
}

// ---------------- attention coefficients layer 1 (reads bf16 h1) ----------------
__global__ __launch_bounds__(256) void attn1_kernel(
    const unsigned short* __restrict__ h1b, const float* __restrict__ att_s,
    const float* __restrict__ att_d, float* __restrict__ a1s,
    float* __restrict__ a1d)
{
    int n = blockIdx.x;
    int t = threadIdx.x;            // t = h*32 + f
    float hv = bfu2f(h1b[(size_t)n * NN_HF + t]);
    float ps = hv * att_s[t];
    float pd = hv * att_d[t];
    #pragma unroll
    for (int off = 16; off >= 1; off >>= 1) {
        ps += __shfl_down(ps, off, 32);
        pd += __shfl_down(pd, off, 32);
    }
    if ((t & 31) == 0) {
        a1s[n * NN_H + (t >> 5)] = ps;
        a1d[n * NN_H + (t >> 5)] = pd;
    }
}

// ---------------- CSR build ----------------
__global__ void count_kernel(const int* __restrict__ dst, int* __restrict__ deg,
                             int E, int Nn)
{
    int e = blockIdx.x * blockDim.x + threadIdx.x;
    int Et = E + Nn;
    if (e >= Et) return;
    int d = (e < E) ? dst[e] : (e - E);     // self-loops appended
    atomicAdd(&deg[d], 1);
}

#define SCAN_CHUNK 1024
__global__ __launch_bounds__(256) void scan1_kernel(
    const int* __restrict__ deg, int* __restrict__ offs,
    int* __restrict__ bsums, int Nn)
{
    __shared__ int sh[256];
    int b = blockIdx.x, t = threadIdx.x;
    int base = b * SCAN_CHUNK + t * 4;
    int v[4];
    int tot = 0;
    #pragma unroll
    for (int i = 0; i < 4; ++i) {
        v[i] = (base + i < Nn) ? deg[base + i] : 0;
        tot += v[i];
    }
    sh[t] = tot;
    __syncthreads();
    for (int off = 1; off < 256; off <<= 1) {
        int y = (t >= off) ? sh[t - off] : 0;
        __syncthreads();
        sh[t] += y;
        __syncthreads();
    }
    int p = sh[t] - tot;
    #pragma unroll
    for (int i = 0; i < 4; ++i) {
        if (base + i < Nn) offs[base + i] = p;
        p += v[i];
    }
    if (t == 255) bsums[b] = sh[255];
}

__global__ void scan2_kernel(int* __restrict__ bsums, int nb)
{
    if (threadIdx.x == 0) {
        int run = 0;
        for (int i = 0; i < nb; ++i) {
            int tmp = bsums[i];
            bsums[i] = run;
            run += tmp;
        }
    }
}

__global__ void scan3_kernel(int* __restrict__ offs, const int* __restrict__ bsums,
                             int Nn, int Et)
{
    int i = blockIdx.x * blockDim.x + threadIdx.x;
    if (i < Nn) offs[i] += bsums[i >> 10];
    if (i == 0) offs[Nn] = Et;
}

__global__ void fill_kernel(const int* __restrict__ src, const int* __restrict__ dst,
                            const int* __restrict__ offs, int* __restrict__ cursor,
                            int* __restrict__ srcs, int E, int Nn)
{
    int e = blockIdx.x * blockDim.x + threadIdx.x;
    int Et = E + Nn;
    if (e >= Et) return;
    int d, s;
    if (e < E) { d = dst[e]; s = src[e]; }
    else       { d = e - E;  s = e - E;  }
    int pos = offs[d] + atomicAdd(&cursor[d], 1);
    srcs[pos] = s;
}

// ---------------- layer-1 edge weights: alpha1[k][h] = softmax (4 nodes/block) ----
__global__ __launch_bounds__(256) void attw1_kernel(
    const float* __restrict__ a1s, const float* __restrict__ a1d,
    const int* __restrict__ offs, const int* __restrict__ srcs,
    float* __restrict__ alpha1, int Nn)
{
    int n = blockIdx.x * 4 + (threadIdx.x >> 6);
    if (n >= Nn) return;
    int lane = threadIdx.x & 63;
    int g = lane >> 3, h = lane & 7;        // 8 edge groups x 8 heads
    int beg = offs[n], end = offs[n + 1];
    float adn = a1d[n * NN_H + h];
    float m = -3.0e38f, s = 0.f;
    for (int k = beg + g; k < end; k += 8) {
        int sN = srcs[k];
        float e = a1s[sN * NN_H + h] + adn;
        e = e > 0.f ? e : 0.2f * e;
        float nm = fmaxf(m, e);
        float sc = __expf(m - nm);
        s = s * sc + __expf(e - nm);
        m = nm;
    }
    #pragma unroll
    for (int off = 8; off < 64; off <<= 1) {
        float mo = __shfl_xor(m, off);
        float so = __shfl_xor(s, off);
        float nm = fmaxf(m, mo);
        s = s * __expf(m - nm) + so * __expf(mo - nm);
        m = nm;
    }
    float inv = 1.f / (s + 1e-16f);
    for (int k = beg + g; k < end; k += 8) {
        int sN = srcs[k];
        float e = a1s[sN * NN_H + h] + adn;
        e = e > 0.f ? e : 0.2f * e;
        alpha1[(size_t)k * NN_H + h] = __expf(e - m) * inv;
    }
}

// ---------------- layer-1 aggregate: wave-per-node weighted gather + bias + ELU ----
// lane l covers features 4l..4l+3 (ushort4 = whole 512B row per wave); head = l>>3
__global__ __launch_bounds__(256) void agg1_kernel(
    const unsigned short* __restrict__ h1b, const float* __restrict__ alpha1,
    const int* __restrict__ offs, const int* __restrict__ srcs,
    const float* __restrict__ b1, unsigned short* __restrict__ hp1b, int Nn)
{
    int n = blockIdx.x * 4 + (threadIdx.x >> 6);
    if (n >= Nn) return;
    int lane = threadIdx.x & 63;
    int h = lane >> 3;
    int beg = offs[n], end = offs[n + 1];
    f32x4 a0 = {0.f,0.f,0.f,0.f}, a1 = a0, a2 = a0, a3 = a0;
    int k = beg;
    for (; k + 3 < end; k += 4) {
        int s0 = srcs[k], s1 = srcs[k+1], s2 = srcs[k+2], s3 = srcs[k+3];
        float w0 = alpha1[(size_t)k * NN_H + h];
        float w1 = alpha1[(size_t)(k+1) * NN_H + h];
        float w2 = alpha1[(size_t)(k+2) * NN_H + h];
        float w3 = alpha1[(size_t)(k+3) * NN_H + h];
        ushort4 v0 = *(const ushort4*)(h1b + (size_t)s0 * NN_HF + lane * 4);
        ushort4 v1 = *(const ushort4*)(h1b + (size_t)s1 * NN_HF + lane * 4);
        ushort4 v2 = *(const ushort4*)(h1b + (size_t)s2 * NN_HF + lane * 4);
        ushort4 v3 = *(const ushort4*)(h1b + (size_t)s3 * NN_HF + lane * 4);
        a0.x = fmaf(w0, bfu2f(v0.x), a0.x); a0.y = fmaf(w0, bfu2f(v0.y), a0.y);
        a0.z = fmaf(w0, bfu2f(v0.z), a0.z); a0.w = fmaf(w0, bfu2f(v0.w), a0.w);
        a1.x = fmaf(w1, bfu2f(v1.x), a1.x); a1.y = fmaf(w1, bfu2f(v1.y), a1.y);
        a1.z = fmaf(w1, bfu2f(v1.z), a1.z); a1.w = fmaf(w1, bfu2f(v1.w), a1.w);
        a2.x = fmaf(w2, bfu2f(v2.x), a2.x); a2.y = fmaf(w2, bfu2f(v2.y), a2.y);
        a2.z = fmaf(w2, bfu2f(v2.z), a2.z); a2.w = fmaf(w2, bfu2f(v2.w), a2.w);
        a3.x = fmaf(w3, bfu2f(v3.x), a3.x); a3.y = fmaf(w3, bfu2f(v3.y), a3.y);
        a3.z = fmaf(w3, bfu2f(v3.z), a3.z); a3.w = fmaf(w3, bfu2f(v3.w), a3.w);
    }
    for (; k < end; ++k) {
        int s0 = srcs[k];
        float w0 = alpha1[(size_t)k * NN_H + h];
        ushort4 v0 = *(const ushort4*)(h1b + (size_t)s0 * NN_HF + lane * 4);
        a0.x = fmaf(w0, bfu2f(v0.x), a0.x); a0.y = fmaf(w0, bfu2f(v0.y), a0.y);
        a0.z = fmaf(w0, bfu2f(v0.z), a0.z); a0.w = fmaf(w0, bfu2f(v0.w), a0.w);
    }
    f32x4 acc;
    acc[0] = (a0.x + a1.x) + (a2.x + a3.x);
    acc[1] = (a0.y + a1.y) + (a2.y + a3.y);
    acc[2] = (a0.z + a1.z) + (a2.z + a3.z);
    acc[3] = (a0.w + a1.w) + (a2.w + a3.w);
    float4 bb = *(const float4*)(b1 + lane * 4);
    float r0 = acc[0] + bb.x, r1 = acc[1] + bb.y;
    float r2 = acc[2] + bb.z, r3 = acc[3] + bb.w;
    r0 = r0 > 0.f ? r0 : __expf(r0) - 1.f;
    r1 = r1 > 0.f ? r1 : __expf(r1) - 1.f;
    r2 = r2 > 0.f ? r2 : __expf(r2) - 1.f;
    r3 = r3 > 0.f ? r3 : __expf(r3) - 1.f;
    ushort4 o = make_ushort4(f2bf_rne(r0), f2bf_rne(r1), f2bf_rne(r2), f2bf_rne(r3));
    *(ushort4*)(hp1b + (size_t)n * NN_HF + lane * 4) = o;
}

// ---------------- GEMM2: h2 = hp1 @ W2  (bf16 in, fp32 math), fused a2s/a2d ----
#define G2_ROWS 64
#define G2_KC   64

__global__ __launch_bounds__(256) void gemm2_kernel(
    const unsigned short* __restrict__ Ab, const float* __restrict__ W2,
    const float* __restrict__ att_s, const float* __restrict__ att_d,
    float* __restrict__ h2, float* __restrict__ a2s, float* __restrict__ a2d,
    int M)
{
    __shared__ float As[G2_ROWS][G2_KC + 1];
    __shared__ float Ws[G2_KC][NN_C];
    int m0 = blockIdx.x * G2_ROWS;
    int t = threadIdx.x;
    int rp = t >> 3;
    int cg = t & 7;
    int c0 = cg * 5;
    int r0 = rp * 2, r1 = r0 + 1;
    float acc[2][5] = {};
    for (int kc = 0; kc < NN_HF; kc += G2_KC) {
        #pragma unroll
        for (int i = 0; i < 4; ++i) {
            int g = t + i * 256;
            int r = g >> 4;
            int k4 = (g & 15) << 2;
            ushort4 v = make_ushort4(0, 0, 0, 0);
            if (m0 + r < M)
                v = *(const ushort4*)(Ab + (size_t)(m0 + r) * NN_HF + kc + k4);
            As[r][k4 + 0] = bfu2f(v.x); As[r][k4 + 1] = bfu2f(v.y);
            As[r][k4 + 2] = bfu2f(v.z); As[r][k4 + 3] = bfu2f(v.w);
        }
        #pragma unroll
        for (int i = 0; i < 10; ++i) {
            int g = t + i * 256;
            int k = g / NN_C, c = g % NN_C;
            Ws[k][c] = W2[(size_t)(kc + k) * NN_C + c];
        }
        __syncthreads();
        #pragma unroll 4
        for (int k = 0; k < G2_KC; ++k) {
            float a0 = As[r0][k];
            float a1 = As[r1][k];
            #pragma unroll
            for (int j = 0; j < 5; ++j) {
                float w = Ws[k][c0 + j];
                acc[0][j] += a0 * w;
                acc[1][j] += a1 * w;
            }
        }
        __syncthreads();
    }
    #pragma unroll
    for (int i = 0; i < 2; ++i) {
        int m = m0 + r0 + i;
        float ps = 0.f, pd = 0.f;
        #pragma unroll
        for (int j = 0; j < 5; ++j) {
            float v = acc[i][j];
            ps += v * att_s[c0 + j];
            pd += v * att_d[c0 + j];
            if (m < M) h2[(size_t)m * NN_C + c0 + j] = v;
        }
        #pragma unroll
        for (int off = 4; off >= 1; off >>= 1) {
            ps += __shfl_down(ps, off, 8);
            pd += __shfl_down(pd, off, 8);
        }
        if (cg == 0 && m < M) { a2s[m] = ps; a2d[m] = pd; }
    }
}

// ---------------- layer-2 edge weights (H=1, 4 nodes/block) ----------------
__global__ __launch_bounds__(256) void attw2_kernel(
    const float* __restrict__ a2s, const float* __restrict__ a2d,
    const int* __restrict__ offs, const int* __restrict__ srcs,
    float* __restrict__ alpha2, int Nn)
{
    int n = blockIdx.x * 4 + (threadIdx.x >> 6);
    if (n >= Nn) return;
    int lane = threadIdx.x & 63;
    int beg = offs[n], end = offs[n + 1];
    float adn = a2d[n];
    float m = -3.0e38f, s = 0.f;
    for (int k = beg + lane; k < end; k += 64) {
        int sN = srcs[k];
        float e = a2s[sN] + adn;
        e = e > 0.f ? e : 0.2f * e;
        float nm = fmaxf(m, e);
        float sc = __expf(m - nm);
        s = s * sc + __expf(e - nm);
        m = nm;
    }
    #pragma unroll
    for (int off = 1; off < 64; off <<= 1) {
        float mo = __shfl_xor(m, off);
        float so = __shfl_xor(s, off);
        float nm = fmaxf(m, mo);
        s = s * __expf(m - nm) + so * __expf(mo - nm);
        m = nm;
    }
    float inv = 1.f / (s + 1e-16f);
    for (int k = beg + lane; k < end; k += 64) {
        int sN = srcs[k];
        float e = a2s[sN] + adn;
        e = e > 0.f ? e : 0.2f * e;
        alpha2[k] = __expf(e - m) * inv;
    }
}

// ---------------- layer-2 aggregate: wave-per-node + bias + log_softmax ----------
__global__ __launch_bounds__(256) void agg2_kernel(
    const float* __restrict__ h2, const float* __restrict__ alpha2,
    const int* __restrict__ offs, const int* __restrict__ srcs,
    const float* __restrict__ b2, float* __restrict__ out, int Nn)
{
    int n = blockIdx.x * 4 + (threadIdx.x >> 6);
    if (n >= Nn) return;
    int f = threadIdx.x & 63;
    int beg = offs[n], end = offs[n + 1];
    float a0 = 0.f, a1 = 0.f, a2 = 0.f, a3 = 0.f;
    int k = beg;
    for (; k + 3 < end; k += 4) {
        int s0 = srcs[k], s1 = srcs[k+1], s2 = srcs[k+2], s3 = srcs[k+3];
        float w0 = alpha2[k], w1 = alpha2[k+1], w2 = alpha2[k+2], w3 = alpha2[k+3];
        float h0 = (f < NN_C) ? h2[(size_t)s0 * NN_C + f] : 0.f;
        float h1 = (f < NN_C) ? h2[(size_t)s1 * NN_C + f] : 0.f;
        float h2v = (f < NN_C) ? h2[(size_t)s2 * NN_C + f] : 0.f;
        float h3 = (f < NN_C) ? h2[(size_t)s3 * NN_C + f] : 0.f;
        a0 = fmaf(w0, h0, a0); a1 = fmaf(w1, h1, a1);
        a2 = fmaf(w2, h2v, a2); a3 = fmaf(w3, h3, a3);
    }
    for (; k < end; ++k) {
        int s0 = srcs[k];
        float w0 = alpha2[k];
        float h0 = (f < NN_C) ? h2[(size_t)s0 * NN_C + f] : 0.f;
        a0 = fmaf(w0, h0, a0);
    }
    float acc = (a0 + a1) + (a2 + a3);
    float v = acc + ((f < NN_C) ? b2[f] : 0.f);
    float lg = (f < NN_C) ? v : -INFINITY;
    float mx = lg;
    #pragma unroll
    for (int off = 32; off >= 1; off >>= 1) mx = fmaxf(mx, __shfl_xor(mx, off));
    float w2e = (f < NN_C) ? __expf(lg - mx) : 0.f;
    float sum = w2e;
    #pragma unroll
    for (int off = 32; off >= 1; off >>= 1) sum += __shfl_xor(sum, off);
    if (f < NN_C) out[(size_t)n * NN_C + f] = lg - mx - __logf(sum);
}

// ---------------- launcher ----------------
extern "C" void kernel_launch(void* const* d_in, const int* in_sizes, int n_in,
                              void* d_out, int out_size, void* d_ws, size_t ws_size,
                              hipStream_t stream)
{
    const float* x    = (const float*)d_in[0];
    const int*   ei   = (const int*)d_in[1];
    const float* W1   = (const float*)d_in[2];
    const float* as1  = (const float*)d_in[3];
    const float* ad1  = (const float*)d_in[4];
    const float* b1   = (const float*)d_in[5];
    const float* W2   = (const float*)d_in[6];
    const float* as2  = (const float*)d_in[7];
    const float* ad2  = (const float*)d_in[8];
    const float* b2   = (const float*)d_in[9];
    float* out = (float*)d_out;

    int Nn = in_sizes[0] / NN_DIN;      // 50000
    int E  = in_sizes[1] / 2;           // 800000
    int Et = E + Nn;
    const int* srcIdx = ei;
    const int* dstIdx = ei + E;

    char* ws = (char*)d_ws;
    size_t off = 0;
    auto alloc = [&](size_t bytes) {
        void* p = ws + off;
        off = (off + bytes + 255) & ~(size_t)255;
        return p;
    };
    unsigned short* h1b  = (unsigned short*)alloc((size_t)Nn * NN_HF * 2);
    unsigned short* W1T  = (unsigned short*)alloc((size_t)NN_HF * NN_DIN * 2);
    unsigned short* hp1b = (unsigned short*)alloc((size_t)Nn * NN_HF * 2);
    float* a1s  = (float*)alloc((size_t)Nn * NN_H * 4);
    float* a1d  = (float*)alloc((size_t)Nn * NN_H * 4);
    float* h2   = (float*)alloc((size_t)Nn * NN_C * 4);
    float* a2s  = (float*)alloc((size_t)Nn * 4);
    float* a2d  = (float*)alloc((size_t)Nn * 4);
    float* alpha1 = (float*)alloc((size_t)Et * NN_H * 4);
    float* alpha2 = (float*)alloc((size_t)Et * 4);
    int*   deg  = (int*)alloc((size_t)Nn * 4);
    int*   offs = (int*)alloc((size_t)(Nn + 1) * 4);
    int*   bsums= (int*)alloc(1024 * 4);
    int*   curs = (int*)alloc((size_t)Nn * 4);
    int*   srcs = (int*)alloc((size_t)Et * 4);

    hipMemsetAsync(deg, 0, (size_t)Nn * 4, stream);
    hipMemsetAsync(curs, 0, (size_t)Nn * 4, stream);

    // W1 transpose + RNE bf16
    w1rne_kernel<<<dim3(NN_DIN / 32, NN_HF / 32), 256, 0, stream>>>(W1, W1T);

    // GEMM1 (MFMA, x read once) -> h1b
    gemm1_kernel<<<(Nn + G1_BM - 1) / G1_BM, 256, 0, stream>>>(x, W1T, h1b, Nn);

    // attention coefficients
    attn1_kernel<<<Nn, 256, 0, stream>>>(h1b, as1, ad1, a1s, a1d);

    // CSR build
    count_kernel<<<(Et + 255) / 256, 256, 0, stream>>>(dstIdx, deg, E, Nn);
    int nb = (Nn + SCAN_CHUNK - 1) / SCAN_CHUNK;
    scan1_kernel<<<nb, 256, 0, stream>>>(deg, offs, bsums, Nn);
    scan2_kernel<<<1, 64, 0, stream>>>(bsums, nb);
    scan3_kernel<<<(Nn + 255) / 256, 256, 0, stream>>>(offs, bsums, Nn, Et);
    fill_kernel<<<(Et + 255) / 256, 256, 0, stream>>>(srcIdx, dstIdx, offs, curs, srcs, E, Nn);

    // layer-1 edge weights, then weighted aggregate (+bias+ELU) -> bf16
    attw1_kernel<<<(Nn + 3) / 4, 256, 0, stream>>>(a1s, a1d, offs, srcs, alpha1, Nn);
    agg1_kernel<<<(Nn + 3) / 4, 256, 0, stream>>>(h1b, alpha1, offs, srcs, b1, hp1b, Nn);

    // GEMM2 (+fused a2s/a2d)
    gemm2_kernel<<<(Nn + G2_ROWS - 1) / G2_ROWS, 256, 0, stream>>>(
        hp1b, W2, as2, ad2, h2, a2s, a2d, Nn);

    // layer-2 edge weights, then aggregate + bias + log_softmax
    attw2_kernel<<<(Nn + 3) / 4, 256, 0, stream>>>(a2s, a2d, offs, srcs, alpha2, Nn);
    agg2_kernel<<<(Nn + 3) / 4, 256, 0, stream>>>(h2, alpha2, offs, srcs, b2, out, Nn);
}

// Round 9
// 440.171 us; speedup vs baseline: 1.6709x; 1.1230x over previous
//
#include <hip/hip_runtime.h>
#include <hip/hip_bf16.h>
#include <math.h>

#define NN_DIN 512
#define NN_HF  256
#define NN_H   8
#define NN_F   32
#define NN_C   40

typedef short bf16x8 __attribute__((ext_vector_type(8)));
typedef float f32x4 __attribute__((ext_vector_type(4)));

__device__ __forceinline__ unsigned short f2bf_rne(float x) {
    unsigned u = __builtin_bit_cast(unsigned, x);
    unsigned r = u + 0x7FFFu + ((u >> 16) & 1u);
    return (unsigned short)(r >> 16);
}
__device__ __forceinline__ float bfu2f(unsigned short s) {
    unsigned u = ((unsigned)s) << 16;
    return __builtin_bit_cast(float, u);
}

// ---------------- W1 transpose + RNE bf16: [512][256] f32 -> [256][512] bf16 ----
__global__ __launch_bounds__(256) void w1rne_kernel(
    const float* __restrict__ W1, unsigned short* __restrict__ Wh)
{
    __shared__ float tile[32][33];
    int bk = blockIdx.x * 32;
    int bn = blockIdx.y * 32;
    int tx = threadIdx.x & 31, ty = threadIdx.x >> 5;   // ty 0..7
    #pragma unroll
    for (int i = 0; i < 32; i += 8)
        tile[ty + i][tx] = W1[(size_t)(bk + ty + i) * NN_HF + bn + tx];
    __syncthreads();
    #pragma unroll
    for (int i = 0; i < 32; i += 8) {
        float v = tile[tx][ty + i];
        Wh[(size_t)(bn + ty + i) * NN_DIN + bk + tx] = f2bf_rne(v);
    }
}

// ---------------- W2 transpose + RNE bf16: [256][40] f32 -> [48][256] bf16 (pad 0) ----
__global__ __launch_bounds__(256) void w2rne_kernel(
    const float* __restrict__ W2, unsigned short* __restrict__ W2T)
{
    int idx = blockIdx.x * 256 + threadIdx.x;    // 48*256 = 12288
    if (idx >= 48 * 256) return;
    int c = idx >> 8;       // output col (row of W2T), 0..47
    int k = idx & 255;
    unsigned short v = 0;
    if (c < NN_C) v = f2bf_rne(W2[(size_t)k * NN_C + c]);
    W2T[idx] = v;
}

// ---------------- GEMM1 (MFMA, reg-prefetch dbuf, x read ONCE): h1b = bf16(x@W1) ----
#define G1_BM 64
#define G1_BN 256
#define G1_BK 64
#define G1_LDK 72

__global__ __launch_bounds__(256) void gemm1_kernel(
    const float* __restrict__ A, const unsigned short* __restrict__ BT,
    unsigned short* __restrict__ Cb, int M)
{
    __shared__ unsigned short Ah[G1_BM][G1_LDK];
    __shared__ unsigned short Bh[G1_BN][G1_LDK];
    const int m0 = blockIdx.x * G1_BM;
    const int tid = threadIdx.x;
    const int wave = tid >> 6, lane = tid & 63;
    const int wn = wave;
    const int lr = lane & 15, lg = lane >> 4;

    const int amr[4] = { (tid + 0*256) >> 4, (tid + 1*256) >> 4,
                         (tid + 2*256) >> 4, (tid + 3*256) >> 4 };
    const int akc = (tid & 15) << 2;
    const int bnr[8] = { (tid + 0*256) >> 3, (tid + 1*256) >> 3,
                         (tid + 2*256) >> 3, (tid + 3*256) >> 3,
                         (tid + 4*256) >> 3, (tid + 5*256) >> 3,
                         (tid + 6*256) >> 3, (tid + 7*256) >> 3 };
    const int bkc = (tid & 7) << 3;

    f32x4 acc[4][4];
    #pragma unroll
    for (int i = 0; i < 4; ++i)
        #pragma unroll
        for (int j = 0; j < 4; ++j) acc[i][j] = (f32x4){0.f, 0.f, 0.f, 0.f};

    float4 ra[4];
    bf16x8 rb[8];

    #pragma unroll
    for (int i = 0; i < 4; ++i) {
        ra[i] = make_float4(0.f, 0.f, 0.f, 0.f);
        if (m0 + amr[i] < M)
            ra[i] = *(const float4*)(A + (size_t)(m0 + amr[i]) * NN_DIN + akc);
    }
    #pragma unroll
    for (int i = 0; i < 8; ++i)
        rb[i] = *(const bf16x8*)(BT + (size_t)bnr[i] * NN_DIN + bkc);
    #pragma unroll
    for (int i = 0; i < 4; ++i) {
        ushort4 hv;
        hv.x = f2bf_rne(ra[i].x); hv.y = f2bf_rne(ra[i].y);
        hv.z = f2bf_rne(ra[i].z); hv.w = f2bf_rne(ra[i].w);
        *reinterpret_cast<ushort4*>(&Ah[amr[i]][akc]) = hv;
    }
    #pragma unroll
    for (int i = 0; i < 8; ++i)
        *reinterpret_cast<bf16x8*>(&Bh[bnr[i]][bkc]) = rb[i];
    __syncthreads();

    const int NSTEP = NN_DIN / G1_BK;   // 8
    for (int step = 0; step < NSTEP; ++step) {
        const bool last = (step == NSTEP - 1);
        if (!last) {
            int k0 = (step + 1) * G1_BK;
            #pragma unroll
            for (int i = 0; i < 4; ++i) {
                ra[i] = make_float4(0.f, 0.f, 0.f, 0.f);
                if (m0 + amr[i] < M)
                    ra[i] = *(const float4*)(A + (size_t)(m0 + amr[i]) * NN_DIN + k0 + akc);
            }
            #pragma unroll
            for (int i = 0; i < 8; ++i)
                rb[i] = *(const bf16x8*)(BT + (size_t)bnr[i] * NN_DIN + k0 + bkc);
        }
        #pragma unroll
        for (int ks = 0; ks < 2; ++ks) {
            const int kb = (ks << 5) + (lg << 3);
            bf16x8 fah[4], fbh[4];
            #pragma unroll
            for (int mi = 0; mi < 4; ++mi) {
                int m = (mi << 4) + lr;
                fah[mi] = *reinterpret_cast<const bf16x8*>(&Ah[m][kb]);
            }
            #pragma unroll
            for (int ni = 0; ni < 4; ++ni) {
                int n = (wn << 6) + (ni << 4) + lr;
                fbh[ni] = *reinterpret_cast<const bf16x8*>(&Bh[n][kb]);
            }
            #pragma unroll
            for (int mi = 0; mi < 4; ++mi)
                #pragma unroll
                for (int ni = 0; ni < 4; ++ni)
                    acc[mi][ni] = __builtin_amdgcn_mfma_f32_16x16x32_bf16(
                        fah[mi], fbh[ni], acc[mi][ni], 0, 0, 0);
        }
        __syncthreads();
        if (!last) {
            #pragma unroll
            for (int i = 0; i < 4; ++i) {
                ushort4 hv;
                hv.x = f2bf_rne(ra[i].x); hv.y = f2bf_rne(ra[i].y);
                hv.z = f2bf_rne(ra[i].z); hv.w = f2bf_rne(ra[i].w);
                *reinterpret_cast<ushort4*>(&Ah[amr[i]][akc]) = hv;
            }
            #pragma unroll
            for (int i = 0; i < 8; ++i)
                *reinterpret_cast<bf16x8*>(&Bh[bnr[i]][bkc]) = rb[i];
            __syncthreads();
        }
    }
    #pragma unroll
    for (int mi = 0; mi < 4; ++mi)
        #pragma unroll
        for (int ni = 0; ni < 4; ++ni)
            #pragma unroll
            for (int r = 0; r < 4; ++r) {
                int row = m0 + (mi << 4) + (lg << 2) + r;
                int col = (wn << 6) + (ni << 4) + lr;
                if (row < M)
                    Cb[(size_t)row * NN_HF + col] = f2bf_rne(acc[mi][ni][r]);
            }
}

// ---------------- attention coefficients layer 1 (reads bf16 h1) ----------------
__global__ __launch_bounds__(256) void attn1_kernel(
    const unsigned short* __restrict__ h1b, const float* __restrict__ att_s,
    const float* __restrict__ att_d, float* __restrict__ a1s,
    float* __restrict__ a1d)
{
    int n = blockIdx.x;
    int t = threadIdx.x;            // t = h*32 + f
    float hv = bfu2f(h1b[(size_t)n * NN_HF + t]);
    float ps = hv * att_s[t];
    float pd = hv * att_d[t];
    #pragma unroll
    for (int off = 16; off >= 1; off >>= 1) {
        ps += __shfl_down(ps, off, 32);
        pd += __shfl_down(pd, off, 32);
    }
    if ((t & 31) == 0) {
        a1s[n * NN_H + (t >> 5)] = ps;
        a1d[n * NN_H + (t >> 5)] = pd;
    }
}

// ---------------- CSR build ----------------
__global__ void count_kernel(const int* __restrict__ dst, int* __restrict__ deg,
                             int E, int Nn)
{
    int e = blockIdx.x * blockDim.x + threadIdx.x;
    int Et = E + Nn;
    if (e >= Et) return;
    int d = (e < E) ? dst[e] : (e - E);     // self-loops appended
    atomicAdd(&deg[d], 1);
}

#define SCAN_CHUNK 1024
__global__ __launch_bounds__(256) void scan1_kernel(
    const int* __restrict__ deg, int* __restrict__ offs,
    int* __restrict__ bsums, int Nn)
{
    __shared__ int sh[256];
    int b = blockIdx.x, t = threadIdx.x;
    int base = b * SCAN_CHUNK + t * 4;
    int v[4];
    int tot = 0;
    #pragma unroll
    for (int i = 0; i < 4; ++i) {
        v[i] = (base + i < Nn) ? deg[base + i] : 0;
        tot += v[i];
    }
    sh[t] = tot;
    __syncthreads();
    for (int off = 1; off < 256; off <<= 1) {
        int y = (t >= off) ? sh[t - off] : 0;
        __syncthreads();
        sh[t] += y;
        __syncthreads();
    }
    int p = sh[t] - tot;
    #pragma unroll
    for (int i = 0; i < 4; ++i) {
        if (base + i < Nn) offs[base + i] = p;
        p += v[i];
    }
    if (t == 255) bsums[b] = sh[255];
}

__global__ void scan2_kernel(int* __restrict__ bsums, int nb)
{
    if (threadIdx.x == 0) {
        int run = 0;
        for (int i = 0; i < nb; ++i) {
            int tmp = bsums[i];
            bsums[i] = run;
            run += tmp;
        }
    }
}

__global__ void scan3_kernel(int* __restrict__ offs, const int* __restrict__ bsums,
                             int Nn, int Et)
{
    int i = blockIdx.x * blockDim.x + threadIdx.x;
    if (i < Nn) offs[i] += bsums[i >> 10];
    if (i == 0) offs[Nn] = Et;
}

__global__ void fill_kernel(const int* __restrict__ src, const int* __restrict__ dst,
                            const int* __restrict__ offs, int* __restrict__ cursor,
                            int* __restrict__ srcs, int E, int Nn)
{
    int e = blockIdx.x * blockDim.x + threadIdx.x;
    int Et = E + Nn;
    if (e >= Et) return;
    int d, s;
    if (e < E) { d = dst[e]; s = src[e]; }
    else       { d = e - E;  s = e - E;  }
    int pos = offs[d] + atomicAdd(&cursor[d], 1);
    srcs[pos] = s;
}

// ---------------- layer-1 FUSED softmax+aggregate (+bias+ELU) -> bf16 --------
// pass 1: per-head (m,s) via 8 edge-groups x 8 heads; pass 2: weighted gather
__global__ __launch_bounds__(256) void agg1_kernel(
    const unsigned short* __restrict__ h1b, const float* __restrict__ a1s,
    const float* __restrict__ a1d, const int* __restrict__ offs,
    const int* __restrict__ srcs, const float* __restrict__ b1,
    unsigned short* __restrict__ hp1b, int Nn)
{
    int n = blockIdx.x * 4 + (threadIdx.x >> 6);
    if (n >= Nn) return;
    int lane = threadIdx.x & 63;
    int beg = offs[n], end = offs[n + 1];

    // ---- pass 1 ----
    int g = lane >> 3, hh = lane & 7;
    float adn1 = a1d[n * NN_H + hh];
    float m = -3.0e38f, s = 0.f;
    for (int k = beg + g; k < end; k += 8) {
        float e = a1s[srcs[k] * NN_H + hh] + adn1;
        e = e > 0.f ? e : 0.2f * e;
        float nm = fmaxf(m, e);
        s = s * __expf(m - nm) + __expf(e - nm);
        m = nm;
    }
    #pragma unroll
    for (int off = 8; off < 64; off <<= 1) {
        float mo = __shfl_xor(m, off);
        float so = __shfl_xor(s, off);
        float nm = fmaxf(m, mo);
        s = s * __expf(m - nm) + so * __expf(mo - nm);
        m = nm;
    }
    float inv = 1.f / (s + 1e-16f);

    // redistribute to pass-2 layout (head h = lane>>3 is held by lane h)
    int h = lane >> 3;
    float mh   = __shfl(m, h);
    float invh = __shfl(inv, h);
    float adn  = __shfl(adn1, h);

    // ---- pass 2: weighted gather, 4-way unroll ----
    f32x4 a0 = {0.f,0.f,0.f,0.f}, a1 = a0, a2 = a0, a3 = a0;
    int k = beg;
    for (; k + 3 < end; k += 4) {
        int s0 = srcs[k], s1 = srcs[k+1], s2 = srcs[k+2], s3 = srcs[k+3];
        float e0 = a1s[s0 * NN_H + h] + adn;
        float e1 = a1s[s1 * NN_H + h] + adn;
        float e2 = a1s[s2 * NN_H + h] + adn;
        float e3 = a1s[s3 * NN_H + h] + adn;
        e0 = e0 > 0.f ? e0 : 0.2f * e0;  e1 = e1 > 0.f ? e1 : 0.2f * e1;
        e2 = e2 > 0.f ? e2 : 0.2f * e2;  e3 = e3 > 0.f ? e3 : 0.2f * e3;
        float w0 = __expf(e0 - mh) * invh;
        float w1 = __expf(e1 - mh) * invh;
        float w2 = __expf(e2 - mh) * invh;
        float w3 = __expf(e3 - mh) * invh;
        ushort4 v0 = *(const ushort4*)(h1b + (size_t)s0 * NN_HF + lane * 4);
        ushort4 v1 = *(const ushort4*)(h1b + (size_t)s1 * NN_HF + lane * 4);
        ushort4 v2 = *(const ushort4*)(h1b + (size_t)s2 * NN_HF + lane * 4);
        ushort4 v3 = *(const ushort4*)(h1b + (size_t)s3 * NN_HF + lane * 4);
        a0.x = fmaf(w0, bfu2f(v0.x), a0.x); a0.y = fmaf(w0, bfu2f(v0.y), a0.y);
        a0.z = fmaf(w0, bfu2f(v0.z), a0.z); a0.w = fmaf(w0, bfu2f(v0.w), a0.w);
        a1.x = fmaf(w1, bfu2f(v1.x), a1.x); a1.y = fmaf(w1, bfu2f(v1.y), a1.y);
        a1.z = fmaf(w1, bfu2f(v1.z), a1.z); a1.w = fmaf(w1, bfu2f(v1.w), a1.w);
        a2.x = fmaf(w2, bfu2f(v2.x), a2.x); a2.y = fmaf(w2, bfu2f(v2.y), a2.y);
        a2.z = fmaf(w2, bfu2f(v2.z), a2.z); a2.w = fmaf(w2, bfu2f(v2.w), a2.w);
        a3.x = fmaf(w3, bfu2f(v3.x), a3.x); a3.y = fmaf(w3, bfu2f(v3.y), a3.y);
        a3.z = fmaf(w3, bfu2f(v3.z), a3.z); a3.w = fmaf(w3, bfu2f(v3.w), a3.w);
    }
    for (; k < end; ++k) {
        int s0 = srcs[k];
        float e0 = a1s[s0 * NN_H + h] + adn;
        e0 = e0 > 0.f ? e0 : 0.2f * e0;
        float w0 = __expf(e0 - mh) * invh;
        ushort4 v0 = *(const ushort4*)(h1b + (size_t)s0 * NN_HF + lane * 4);
        a0.x = fmaf(w0, bfu2f(v0.x), a0.x); a0.y = fmaf(w0, bfu2f(v0.y), a0.y);
        a0.z = fmaf(w0, bfu2f(v0.z), a0.z); a0.w = fmaf(w0, bfu2f(v0.w), a0.w);
    }
    f32x4 acc;
    acc[0] = (a0.x + a1.x) + (a2.x + a3.x);
    acc[1] = (a0.y + a1.y) + (a2.y + a3.y);
    acc[2] = (a0.z + a1.z) + (a2.z + a3.z);
    acc[3] = (a0.w + a1.w) + (a2.w + a3.w);
    float4 bb = *(const float4*)(b1 + lane * 4);
    float r0 = acc[0] + bb.x, r1 = acc[1] + bb.y;
    float r2 = acc[2] + bb.z, r3 = acc[3] + bb.w;
    r0 = r0 > 0.f ? r0 : __expf(r0) - 1.f;
    r1 = r1 > 0.f ? r1 : __expf(r1) - 1.f;
    r2 = r2 > 0.f ? r2 : __expf(r2) - 1.f;
    r3 = r3 > 0.f ? r3 : __expf(r3) - 1.f;
    ushort4 o = make_ushort4(f2bf_rne(r0), f2bf_rne(r1), f2bf_rne(r2), f2bf_rne(r3));
    *(ushort4*)(hp1b + (size_t)n * NN_HF + lane * 4) = o;
}

// ---------------- GEMM2 (MFMA): h2 = hp1b @ W2, fused a2s/a2d epilogue --------
// tile 128 rows, 4 waves x (32 rows x 48 cols), K=256 in 4 chunks of 64
#define G2_BM 128

__global__ __launch_bounds__(256) void gemm2_kernel(
    const unsigned short* __restrict__ Ab, const unsigned short* __restrict__ W2T,
    const float* __restrict__ att_s, const float* __restrict__ att_d,
    float* __restrict__ h2, float* __restrict__ a2s, float* __restrict__ a2d,
    int M)
{
    __shared__ unsigned short Ah[G2_BM][72];
    __shared__ unsigned short Bh[48][72];
    const int m0 = blockIdx.x * G2_BM;
    const int tid = threadIdx.x;
    const int wave = tid >> 6, lane = tid & 63;
    const int lr = lane & 15, lg = lane >> 4;

    f32x4 acc[2][3];
    #pragma unroll
    for (int i = 0; i < 2; ++i)
        #pragma unroll
        for (int j = 0; j < 3; ++j) acc[i][j] = (f32x4){0.f, 0.f, 0.f, 0.f};

    for (int kc = 0; kc < NN_HF; kc += 64) {
        // stage A: 128 rows x 64 cols bf16 (1024 short8, 4/thread)
        #pragma unroll
        for (int i = 0; i < 4; ++i) {
            int gi = tid + i * 256;
            int r = gi >> 3;
            int k8 = (gi & 7) << 3;
            bf16x8 v = (bf16x8){0,0,0,0,0,0,0,0};
            if (m0 + r < M)
                v = *(const bf16x8*)(Ab + (size_t)(m0 + r) * NN_HF + kc + k8);
            *reinterpret_cast<bf16x8*>(&Ah[r][k8]) = v;
        }
        // stage B: 48 rows x 64 cols (384 short8)
        #pragma unroll
        for (int i = 0; i < 2; ++i) {
            int gi = tid + i * 256;
            if (gi < 384) {
                int r = gi >> 3;
                int k8 = (gi & 7) << 3;
                *reinterpret_cast<bf16x8*>(&Bh[r][k8]) =
                    *(const bf16x8*)(W2T + (size_t)r * NN_HF + kc + k8);
            }
        }
        __syncthreads();
        #pragma unroll
        for (int ks = 0; ks < 2; ++ks) {
            const int kb = (ks << 5) + (lg << 3);
            bf16x8 fa[2], fb[3];
            #pragma unroll
            for (int mi = 0; mi < 2; ++mi) {
                int r = (wave << 5) + (mi << 4) + lr;
                fa[mi] = *reinterpret_cast<const bf16x8*>(&Ah[r][kb]);
            }
            #pragma unroll
            for (int ni = 0; ni < 3; ++ni) {
                int c = (ni << 4) + lr;
                fb[ni] = *reinterpret_cast<const bf16x8*>(&Bh[c][kb]);
            }
            #pragma unroll
            for (int mi = 0; mi < 2; ++mi)
                #pragma unroll
                for (int ni = 0; ni < 3; ++ni)
                    acc[mi][ni] = __builtin_amdgcn_mfma_f32_16x16x32_bf16(
                        fa[mi], fb[ni], acc[mi][ni], 0, 0, 0);
        }
        __syncthreads();
    }

    // epilogue: write h2 (cols<40) + fused a2s/a2d row-reductions
    float asv[3], adv[3];
    #pragma unroll
    for (int ni = 0; ni < 3; ++ni) {
        int c = (ni << 4) + lr;
        asv[ni] = (c < NN_C) ? att_s[c] : 0.f;
        adv[ni] = (c < NN_C) ? att_d[c] : 0.f;
    }
    #pragma unroll
    for (int mi = 0; mi < 2; ++mi) {
        float ps[4] = {0.f,0.f,0.f,0.f}, pd[4] = {0.f,0.f,0.f,0.f};
        #pragma unroll
        for (int ni = 0; ni < 3; ++ni) {
            int c = (ni << 4) + lr;
            #pragma unroll
            for (int r = 0; r < 4; ++r) {
                float v = acc[mi][ni][r];
                ps[r] = fmaf(v, asv[ni], ps[r]);
                pd[r] = fmaf(v, adv[ni], pd[r]);
                int row = m0 + (wave << 5) + (mi << 4) + (lg << 2) + r;
                if (c < NN_C && row < M)
                    h2[(size_t)row * NN_C + c] = v;
            }
        }
        #pragma unroll
        for (int off = 1; off < 16; off <<= 1) {
            #pragma unroll
            for (int r = 0; r < 4; ++r) {
                ps[r] += __shfl_xor(ps[r], off);
                pd[r] += __shfl_xor(pd[r], off);
            }
        }
        if (lr == 0) {
            #pragma unroll
            for (int r = 0; r < 4; ++r) {
                int row = m0 + (wave << 5) + (mi << 4) + (lg << 2) + r;
                if (row < M) { a2s[row] = ps[r]; a2d[row] = pd[r]; }
            }
        }
    }
}

// ---------------- layer-2 FUSED softmax+aggregate + bias + log_softmax --------
__global__ __launch_bounds__(256) void agg2_kernel(
    const float* __restrict__ h2, const float* __restrict__ a2s,
    const float* __restrict__ a2d, const int* __restrict__ offs,
    const int* __restrict__ srcs, const float* __restrict__ b2,
    float* __restrict__ out, int Nn)
{
    int n = blockIdx.x * 4 + (threadIdx.x >> 6);
    if (n >= Nn) return;
    int f = threadIdx.x & 63;
    int beg = offs[n], end = offs[n + 1];
    float adn = a2d[n];

    // ---- pass 1: (m,s) over edges, all 64 lanes ----
    float m = -3.0e38f, s = 0.f;
    for (int k = beg + f; k < end; k += 64) {
        float e = a2s[srcs[k]] + adn;
        e = e > 0.f ? e : 0.2f * e;
        float nm = fmaxf(m, e);
        s = s * __expf(m - nm) + __expf(e - nm);
        m = nm;
    }
    #pragma unroll
    for (int off = 1; off < 64; off <<= 1) {
        float mo = __shfl_xor(m, off);
        float so = __shfl_xor(s, off);
        float nm = fmaxf(m, mo);
        s = s * __expf(m - nm) + so * __expf(mo - nm);
        m = nm;
    }
    float inv = 1.f / (s + 1e-16f);

    // ---- pass 2: weighted gather + bias + log_softmax ----
    float a0 = 0.f, a1 = 0.f, a2 = 0.f, a3 = 0.f;
    int k = beg;
    for (; k + 3 < end; k += 4) {
        int s0 = srcs[k], s1 = srcs[k+1], s2 = srcs[k+2], s3 = srcs[k+3];
        float e0 = a2s[s0] + adn, e1 = a2s[s1] + adn;
        float e2 = a2s[s2] + adn, e3 = a2s[s3] + adn;
        e0 = e0 > 0.f ? e0 : 0.2f * e0;  e1 = e1 > 0.f ? e1 : 0.2f * e1;
        e2 = e2 > 0.f ? e2 : 0.2f * e2;  e3 = e3 > 0.f ? e3 : 0.2f * e3;
        float w0 = __expf(e0 - m) * inv, w1 = __expf(e1 - m) * inv;
        float w2 = __expf(e2 - m) * inv, w3 = __expf(e3 - m) * inv;
        float h0 = (f < NN_C) ? h2[(size_t)s0 * NN_C + f] : 0.f;
        float h1 = (f < NN_C) ? h2[(size_t)s1 * NN_C + f] : 0.f;
        float h2v = (f < NN_C) ? h2[(size_t)s2 * NN_C + f] : 0.f;
        float h3 = (f < NN_C) ? h2[(size_t)s3 * NN_C + f] : 0.f;
        a0 = fmaf(w0, h0, a0); a1 = fmaf(w1, h1, a1);
        a2 = fmaf(w2, h2v, a2); a3 = fmaf(w3, h3, a3);
    }
    for (; k < end; ++k) {
        int s0 = srcs[k];
        float e0 = a2s[s0] + adn;
        e0 = e0 > 0.f ? e0 : 0.2f * e0;
        float w0 = __expf(e0 - m) * inv;
        float h0 = (f < NN_C) ? h2[(size_t)s0 * NN_C + f] : 0.f;
        a0 = fmaf(w0, h0, a0);
    }
    float acc = (a0 + a1) + (a2 + a3);
    float v = acc + ((f < NN_C) ? b2[f] : 0.f);
    float lg = (f < NN_C) ? v : -INFINITY;
    float mx = lg;
    #pragma unroll
    for (int off = 32; off >= 1; off >>= 1) mx = fmaxf(mx, __shfl_xor(mx, off));
    float w2e = (f < NN_C) ? __expf(lg - mx) : 0.f;
    float sum = w2e;
    #pragma unroll
    for (int off = 32; off >= 1; off >>= 1) sum += __shfl_xor(sum, off);
    if (f < NN_C) out[(size_t)n * NN_C + f] = lg - mx - __logf(sum);
}

// ---------------- launcher ----------------
extern "C" void kernel_launch(void* const* d_in, const int* in_sizes, int n_in,
                              void* d_out, int out_size, void* d_ws, size_t ws_size,
                              hipStream_t stream)
{
    const float* x    = (const float*)d_in[0];
    const int*   ei   = (const int*)d_in[1];
    const float* W1   = (const float*)d_in[2];
    const float* as1  = (const float*)d_in[3];
    const float* ad1  = (const float*)d_in[4];
    const float* b1   = (const float*)d_in[5];
    const float* W2   = (const float*)d_in[6];
    const float* as2  = (const float*)d_in[7];
    const float* ad2  = (const float*)d_in[8];
    const float* b2   = (const float*)d_in[9];
    float* out = (float*)d_out;

    int Nn = in_sizes[0] / NN_DIN;      // 50000
    int E  = in_sizes[1] / 2;           // 800000
    int Et = E + Nn;
    const int* srcIdx = ei;
    const int* dstIdx = ei + E;

    char* ws = (char*)d_ws;
    size_t off = 0;
    auto alloc = [&](size_t bytes) {
        void* p = ws + off;
        off = (off + bytes + 255) & ~(size_t)255;
        return p;
    };
    unsigned short* h1b  = (unsigned short*)alloc((size_t)Nn * NN_HF * 2);
    unsigned short* W1T  = (unsigned short*)alloc((size_t)NN_HF * NN_DIN * 2);
    unsigned short* W2T  = (unsigned short*)alloc((size_t)48 * NN_HF * 2);
    unsigned short* hp1b = (unsigned short*)alloc((size_t)Nn * NN_HF * 2);
    float* a1s  = (float*)alloc((size_t)Nn * NN_H * 4);
    float* a1d  = (float*)alloc((size_t)Nn * NN_H * 4);
    float* h2   = (float*)alloc((size_t)Nn * NN_C * 4);
    float* a2s  = (float*)alloc((size_t)Nn * 4);
    float* a2d  = (float*)alloc((size_t)Nn * 4);
    int*   deg  = (int*)alloc((size_t)Nn * 4);
    int*   offs = (int*)alloc((size_t)(Nn + 1) * 4);
    int*   bsums= (int*)alloc(1024 * 4);
    int*   curs = (int*)alloc((size_t)Nn * 4);
    int*   srcs = (int*)alloc((size_t)Et * 4);

    hipMemsetAsync(deg, 0, (size_t)Nn * 4, stream);
    hipMemsetAsync(curs, 0, (size_t)Nn * 4, stream);

    // weight prep
    w1rne_kernel<<<dim3(NN_DIN / 32, NN_HF / 32), 256, 0, stream>>>(W1, W1T);
    w2rne_kernel<<<48, 256, 0, stream>>>(W2, W2T);

    // GEMM1 (MFMA, x read once) -> h1b
    gemm1_kernel<<<(Nn + G1_BM - 1) / G1_BM, 256, 0, stream>>>(x, W1T, h1b, Nn);

    // attention coefficients
    attn1_kernel<<<Nn, 256, 0, stream>>>(h1b, as1, ad1, a1s, a1d);

    // CSR build
    count_kernel<<<(Et + 255) / 256, 256, 0, stream>>>(dstIdx, deg, E, Nn);
    int nb = (Nn + SCAN_CHUNK - 1) / SCAN_CHUNK;
    scan1_kernel<<<nb, 256, 0, stream>>>(deg, offs, bsums, Nn);
    scan2_kernel<<<1, 64, 0, stream>>>(bsums, nb);
    scan3_kernel<<<(Nn + 255) / 256, 256, 0, stream>>>(offs, bsums, Nn, Et);
    fill_kernel<<<(Et + 255) / 256, 256, 0, stream>>>(srcIdx, dstIdx, offs, curs, srcs, E, Nn);

    // layer-1 fused softmax + aggregate (+bias+ELU) -> bf16
    agg1_kernel<<<(Nn + 3) / 4, 256, 0, stream>>>(h1b, a1s, a1d, offs, srcs, b1, hp1b, Nn);

    // GEMM2 (MFMA, fused a2s/a2d)
    gemm2_kernel<<<(Nn + G2_BM - 1) / G2_BM, 256, 0, stream>>>(
        hp1b, W2T, as2, ad2, h2, a2s, a2d, Nn);

    // layer-2 fused softmax + aggregate + bias + log_softmax
    agg2_kernel<<<(Nn + 3) / 4, 256, 0, stream>>>(h2, a2s, a2d, offs, srcs, b2, out, Nn);
}

// Round 10
// 420.507 us; speedup vs baseline: 1.7490x; 1.0468x over previous
//
#include <hip/hip_runtime.h>
#include <hip/hip_bf16.h>
#include <math.h>

#define NN_DIN 512
#define NN_HF  256
#define NN_H   8
#define NN_F   32
#define NN_C   40

typedef short bf16x8 __attribute__((ext_vector_type(8)));
typedef float f32x4 __attribute__((ext_vector_type(4)));

__device__ __forceinline__ unsigned short f2bf_rne(float x) {
    unsigned u = __builtin_bit_cast(unsigned, x);
    unsigned r = u + 0x7FFFu + ((u >> 16) & 1u);
    return (unsigned short)(r >> 16);
}
__device__ __forceinline__ float bfu2f(unsigned short s) {
    unsigned u = ((unsigned)s) << 16;
    return __builtin_bit_cast(float, u);
}

// ---------------- W1 transpose + RNE bf16: [512][256] f32 -> [256][512] bf16 ----
__global__ __launch_bounds__(256) void w1rne_kernel(
    const float* __restrict__ W1, unsigned short* __restrict__ Wh)
{
    __shared__ float tile[32][33];
    int bk = blockIdx.x * 32;
    int bn = blockIdx.y * 32;
    int tx = threadIdx.x & 31, ty = threadIdx.x >> 5;   // ty 0..7
    #pragma unroll
    for (int i = 0; i < 32; i += 8)
        tile[ty + i][tx] = W1[(size_t)(bk + ty + i) * NN_HF + bn + tx];
    __syncthreads();
    #pragma unroll
    for (int i = 0; i < 32; i += 8) {
        float v = tile[tx][ty + i];
        Wh[(size_t)(bn + ty + i) * NN_DIN + bk + tx] = f2bf_rne(v);
    }
}

// ---------------- W2 transpose + RNE bf16: [256][40] f32 -> [48][256] bf16 (pad 0) ----
__global__ __launch_bounds__(256) void w2rne_kernel(
    const float* __restrict__ W2, unsigned short* __restrict__ W2T)
{
    int idx = blockIdx.x * 256 + threadIdx.x;    // 48*256 = 12288
    if (idx >= 48 * 256) return;
    int c = idx >> 8;       // output col (row of W2T), 0..47
    int k = idx & 255;
    unsigned short v = 0;
    if (c < NN_C) v = f2bf_rne(W2[(size_t)k * NN_C + c]);
    W2T[idx] = v;
}

// ---------------- GEMM1 (MFMA, x read once) + fused a1s/a1d epilogue ----------
#define G1_BM 64
#define G1_BN 256
#define G1_BK 64
#define G1_LDK 72

__global__ __launch_bounds__(256) void gemm1_kernel(
    const float* __restrict__ A, const unsigned short* __restrict__ BT,
    const float* __restrict__ as1, const float* __restrict__ ad1,
    unsigned short* __restrict__ Cb, float* __restrict__ a1s,
    float* __restrict__ a1d, int M)
{
    __shared__ unsigned short Ah[G1_BM][G1_LDK];
    __shared__ unsigned short Bh[G1_BN][G1_LDK];
    const int m0 = blockIdx.x * G1_BM;
    const int tid = threadIdx.x;
    const int wave = tid >> 6, lane = tid & 63;
    const int wn = wave;
    const int lr = lane & 15, lg = lane >> 4;

    const int amr[4] = { (tid + 0*256) >> 4, (tid + 1*256) >> 4,
                         (tid + 2*256) >> 4, (tid + 3*256) >> 4 };
    const int akc = (tid & 15) << 2;
    const int bnr[8] = { (tid + 0*256) >> 3, (tid + 1*256) >> 3,
                         (tid + 2*256) >> 3, (tid + 3*256) >> 3,
                         (tid + 4*256) >> 3, (tid + 5*256) >> 3,
                         (tid + 6*256) >> 3, (tid + 7*256) >> 3 };
    const int bkc = (tid & 7) << 3;

    f32x4 acc[4][4];
    #pragma unroll
    for (int i = 0; i < 4; ++i)
        #pragma unroll
        for (int j = 0; j < 4; ++j) acc[i][j] = (f32x4){0.f, 0.f, 0.f, 0.f};

    float4 ra[4];
    bf16x8 rb[8];

    #pragma unroll
    for (int i = 0; i < 4; ++i) {
        ra[i] = make_float4(0.f, 0.f, 0.f, 0.f);
        if (m0 + amr[i] < M)
            ra[i] = *(const float4*)(A + (size_t)(m0 + amr[i]) * NN_DIN + akc);
    }
    #pragma unroll
    for (int i = 0; i < 8; ++i)
        rb[i] = *(const bf16x8*)(BT + (size_t)bnr[i] * NN_DIN + bkc);
    #pragma unroll
    for (int i = 0; i < 4; ++i) {
        ushort4 hv;
        hv.x = f2bf_rne(ra[i].x); hv.y = f2bf_rne(ra[i].y);
        hv.z = f2bf_rne(ra[i].z); hv.w = f2bf_rne(ra[i].w);
        *reinterpret_cast<ushort4*>(&Ah[amr[i]][akc]) = hv;
    }
    #pragma unroll
    for (int i = 0; i < 8; ++i)
        *reinterpret_cast<bf16x8*>(&Bh[bnr[i]][bkc]) = rb[i];
    __syncthreads();

    const int NSTEP = NN_DIN / G1_BK;   // 8
    for (int step = 0; step < NSTEP; ++step) {
        const bool last = (step == NSTEP - 1);
        if (!last) {
            int k0 = (step + 1) * G1_BK;
            #pragma unroll
            for (int i = 0; i < 4; ++i) {
                ra[i] = make_float4(0.f, 0.f, 0.f, 0.f);
                if (m0 + amr[i] < M)
                    ra[i] = *(const float4*)(A + (size_t)(m0 + amr[i]) * NN_DIN + k0 + akc);
            }
            #pragma unroll
            for (int i = 0; i < 8; ++i)
                rb[i] = *(const bf16x8*)(BT + (size_t)bnr[i] * NN_DIN + k0 + bkc);
        }
        #pragma unroll
        for (int ks = 0; ks < 2; ++ks) {
            const int kb = (ks << 5) + (lg << 3);
            bf16x8 fah[4], fbh[4];
            #pragma unroll
            for (int mi = 0; mi < 4; ++mi) {
                int m = (mi << 4) + lr;
                fah[mi] = *reinterpret_cast<const bf16x8*>(&Ah[m][kb]);
            }
            #pragma unroll
            for (int ni = 0; ni < 4; ++ni) {
                int n = (wn << 6) + (ni << 4) + lr;
                fbh[ni] = *reinterpret_cast<const bf16x8*>(&Bh[n][kb]);
            }
            #pragma unroll
            for (int mi = 0; mi < 4; ++mi)
                #pragma unroll
                for (int ni = 0; ni < 4; ++ni)
                    acc[mi][ni] = __builtin_amdgcn_mfma_f32_16x16x32_bf16(
                        fah[mi], fbh[ni], acc[mi][ni], 0, 0, 0);
        }
        __syncthreads();
        if (!last) {
            #pragma unroll
            for (int i = 0; i < 4; ++i) {
                ushort4 hv;
                hv.x = f2bf_rne(ra[i].x); hv.y = f2bf_rne(ra[i].y);
                hv.z = f2bf_rne(ra[i].z); hv.w = f2bf_rne(ra[i].w);
                *reinterpret_cast<ushort4*>(&Ah[amr[i]][akc]) = hv;
            }
            #pragma unroll
            for (int i = 0; i < 8; ++i)
                *reinterpret_cast<bf16x8*>(&Bh[bnr[i]][bkc]) = rb[i];
            __syncthreads();
        }
    }
    // epilogue: C write + fused attention-coefficient reduction.
    // col = (wn<<6)+(ni<<4)+lr; head = col>>5 -> wave wn owns heads 2wn, 2wn+1
    float asv[4], adv[4];
    #pragma unroll
    for (int ni = 0; ni < 4; ++ni) {
        int c = (wn << 6) + (ni << 4) + lr;
        asv[ni] = as1[c]; adv[ni] = ad1[c];
    }
    #pragma unroll
    for (int mi = 0; mi < 4; ++mi)
        #pragma unroll
        for (int r = 0; r < 4; ++r) {
            int row = m0 + (mi << 4) + (lg << 2) + r;
            float v0 = acc[mi][0][r], v1 = acc[mi][1][r];
            float v2 = acc[mi][2][r], v3 = acc[mi][3][r];
            if (row < M) {
                Cb[(size_t)row * NN_HF + (wn << 6) + (0 << 4) + lr] = f2bf_rne(v0);
                Cb[(size_t)row * NN_HF + (wn << 6) + (1 << 4) + lr] = f2bf_rne(v1);
                Cb[(size_t)row * NN_HF + (wn << 6) + (2 << 4) + lr] = f2bf_rne(v2);
                Cb[(size_t)row * NN_HF + (wn << 6) + (3 << 4) + lr] = f2bf_rne(v3);
            }
            float ps0 = v0 * asv[0] + v1 * asv[1];
            float pd0 = v0 * adv[0] + v1 * adv[1];
            float ps1 = v2 * asv[2] + v3 * asv[3];
            float pd1 = v2 * adv[2] + v3 * adv[3];
            #pragma unroll
            for (int off = 1; off < 16; off <<= 1) {
                ps0 += __shfl_xor(ps0, off); pd0 += __shfl_xor(pd0, off);
                ps1 += __shfl_xor(ps1, off); pd1 += __shfl_xor(pd1, off);
            }
            if (lr == 0 && row < M) {
                a1s[row * NN_H + 2 * wn]     = ps0;
                a1s[row * NN_H + 2 * wn + 1] = ps1;
                a1d[row * NN_H + 2 * wn]     = pd0;
                a1d[row * NN_H + 2 * wn + 1] = pd1;
            }
        }
}

// ---------------- CSR build ----------------
__global__ void count_kernel(const int* __restrict__ dst, int* __restrict__ deg,
                             int E, int Nn)
{
    int e = blockIdx.x * blockDim.x + threadIdx.x;
    int Et = E + Nn;
    if (e >= Et) return;
    int d = (e < E) ? dst[e] : (e - E);     // self-loops appended
    atomicAdd(&deg[d], 1);
}

#define SCAN_CHUNK 1024
__global__ __launch_bounds__(256) void scan1_kernel(
    const int* __restrict__ deg, int* __restrict__ offs,
    int* __restrict__ bsums, int Nn)
{
    __shared__ int sh[256];
    int b = blockIdx.x, t = threadIdx.x;
    int base = b * SCAN_CHUNK + t * 4;
    int v[4];
    int tot = 0;
    #pragma unroll
    for (int i = 0; i < 4; ++i) {
        v[i] = (base + i < Nn) ? deg[base + i] : 0;
        tot += v[i];
    }
    sh[t] = tot;
    __syncthreads();
    for (int off = 1; off < 256; off <<= 1) {
        int y = (t >= off) ? sh[t - off] : 0;
        __syncthreads();
        sh[t] += y;
        __syncthreads();
    }
    int p = sh[t] - tot;
    #pragma unroll
    for (int i = 0; i < 4; ++i) {
        if (base + i < Nn) offs[base + i] = p;
        p += v[i];
    }
    if (t == 255) bsums[b] = sh[255];
}

__global__ void scan2_kernel(int* __restrict__ bsums, int nb)
{
    if (threadIdx.x == 0) {
        int run = 0;
        for (int i = 0; i < nb; ++i) {
            int tmp = bsums[i];
            bsums[i] = run;
            run += tmp;
        }
    }
}

__global__ void scan3_kernel(int* __restrict__ offs, const int* __restrict__ bsums,
                             int Nn, int Et)
{
    int i = blockIdx.x * blockDim.x + threadIdx.x;
    if (i < Nn) offs[i] += bsums[i >> 10];
    if (i == 0) offs[Nn] = Et;
}

__global__ void fill_kernel(const int* __restrict__ src, const int* __restrict__ dst,
                            const int* __restrict__ offs, int* __restrict__ cursor,
                            int* __restrict__ srcs, int E, int Nn)
{
    int e = blockIdx.x * blockDim.x + threadIdx.x;
    int Et = E + Nn;
    if (e >= Et) return;
    int d, s;
    if (e < E) { d = dst[e]; s = src[e]; }
    else       { d = e - E;  s = e - E;  }
    int pos = offs[d] + atomicAdd(&cursor[d], 1);
    srcs[pos] = s;
}

// ---------------- layer-1 FUSED softmax+aggregate (max-free) -> bf16 ---------
// pass 1: s=sum(exp) per head (8 groups x 8 heads). pass 2: half-wave per edge,
// lane covers 8 features (bf16x8 load = 2 rows per wave instruction).
__global__ __launch_bounds__(256) void agg1_kernel(
    const unsigned short* __restrict__ h1b, const float* __restrict__ a1s,
    const float* __restrict__ a1d, const int* __restrict__ offs,
    const int* __restrict__ srcs, const float* __restrict__ b1,
    unsigned short* __restrict__ hp1b, int Nn)
{
    int n = blockIdx.x * 4 + (threadIdx.x >> 6);
    if (n >= Nn) return;
    int lane = threadIdx.x & 63;
    int beg = offs[n], end = offs[n + 1];

    // ---- pass 1: max-free exp-sum per head ----
    int g = lane >> 3, hh = lane & 7;
    float adn1 = a1d[n * NN_H + hh];
    float s = 0.f;
    for (int k = beg + g; k < end; k += 8) {
        float e = a1s[srcs[k] * NN_H + hh] + adn1;
        e = e > 0.f ? e : 0.2f * e;
        s += __expf(e);
    }
    #pragma unroll
    for (int off = 8; off < 64; off <<= 1) s += __shfl_xor(s, off);
    float inv = 1.f / (s + 1e-16f);

    // ---- pass 2 layout ----
    int hl = lane & 31;          // position in half-wave; features 8*hl..8*hl+7
    int h = hl >> 2;             // head (4 lanes x 8 feats = 32 feats)
    int half = lane >> 5;        // which edge of the pair
    float invh = __shfl(inv, h);     // lane h holds head h's sum (g=0 slot)
    float adn  = __shfl(adn1, h);

    float c0[8] = {0,0,0,0,0,0,0,0};
    float c1[8] = {0,0,0,0,0,0,0,0};
    int k = beg;
    for (; k + 3 < end; k += 4) {
        int s0 = srcs[k + half];
        int s1 = srcs[k + 2 + half];
        float e0 = a1s[s0 * NN_H + h] + adn;
        float e1 = a1s[s1 * NN_H + h] + adn;
        e0 = e0 > 0.f ? e0 : 0.2f * e0;
        e1 = e1 > 0.f ? e1 : 0.2f * e1;
        float w0 = __expf(e0) * invh;
        float w1 = __expf(e1) * invh;
        bf16x8 v0 = *(const bf16x8*)(h1b + (size_t)s0 * NN_HF + hl * 8);
        bf16x8 v1 = *(const bf16x8*)(h1b + (size_t)s1 * NN_HF + hl * 8);
        #pragma unroll
        for (int j = 0; j < 8; ++j) {
            c0[j] = fmaf(w0, bfu2f((unsigned short)v0[j]), c0[j]);
            c1[j] = fmaf(w1, bfu2f((unsigned short)v1[j]), c1[j]);
        }
    }
    for (; k + 1 < end; k += 2) {
        int s0 = srcs[k + half];
        float e0 = a1s[s0 * NN_H + h] + adn;
        e0 = e0 > 0.f ? e0 : 0.2f * e0;
        float w0 = __expf(e0) * invh;
        bf16x8 v0 = *(const bf16x8*)(h1b + (size_t)s0 * NN_HF + hl * 8);
        #pragma unroll
        for (int j = 0; j < 8; ++j)
            c0[j] = fmaf(w0, bfu2f((unsigned short)v0[j]), c0[j]);
    }
    if (k < end) {
        int s0 = srcs[k];
        float e0 = a1s[s0 * NN_H + h] + adn;
        e0 = e0 > 0.f ? e0 : 0.2f * e0;
        float w0 = (half == 0) ? __expf(e0) * invh : 0.f;
        bf16x8 v0 = *(const bf16x8*)(h1b + (size_t)s0 * NN_HF + hl * 8);
        #pragma unroll
        for (int j = 0; j < 8; ++j)
            c0[j] = fmaf(w0, bfu2f((unsigned short)v0[j]), c0[j]);
    }
    // combine pair accumulators + cross-half reduce
    #pragma unroll
    for (int j = 0; j < 8; ++j) {
        c0[j] += c1[j];
        c0[j] += __shfl_xor(c0[j], 32);
    }
    if (half == 0) {
        float4 bb0 = *(const float4*)(b1 + hl * 8);
        float4 bb1 = *(const float4*)(b1 + hl * 8 + 4);
        float r[8];
        r[0] = c0[0] + bb0.x; r[1] = c0[1] + bb0.y;
        r[2] = c0[2] + bb0.z; r[3] = c0[3] + bb0.w;
        r[4] = c0[4] + bb1.x; r[5] = c0[5] + bb1.y;
        r[6] = c0[6] + bb1.z; r[7] = c0[7] + bb1.w;
        bf16x8 ov;
        #pragma unroll
        for (int j = 0; j < 8; ++j) {
            float v = r[j] > 0.f ? r[j] : __expf(r[j]) - 1.f;   // ELU
            ov[j] = (short)f2bf_rne(v);
        }
        *(bf16x8*)(hp1b + (size_t)n * NN_HF + hl * 8) = ov;
    }
}

// ---------------- GEMM2 (MFMA): h2 = hp1b @ W2, fused a2s/a2d epilogue --------
#define G2_BM 128

__global__ __launch_bounds__(256) void gemm2_kernel(
    const unsigned short* __restrict__ Ab, const unsigned short* __restrict__ W2T,
    const float* __restrict__ att_s, const float* __restrict__ att_d,
    float* __restrict__ h2, float* __restrict__ a2s, float* __restrict__ a2d,
    int M)
{
    __shared__ unsigned short Ah[G2_BM][72];
    __shared__ unsigned short Bh[48][72];
    const int m0 = blockIdx.x * G2_BM;
    const int tid = threadIdx.x;
    const int wave = tid >> 6, lane = tid & 63;
    const int lr = lane & 15, lg = lane >> 4;

    f32x4 acc[2][3];
    #pragma unroll
    for (int i = 0; i < 2; ++i)
        #pragma unroll
        for (int j = 0; j < 3; ++j) acc[i][j] = (f32x4){0.f, 0.f, 0.f, 0.f};

    for (int kc = 0; kc < NN_HF; kc += 64) {
        #pragma unroll
        for (int i = 0; i < 4; ++i) {
            int gi = tid + i * 256;
            int r = gi >> 3;
            int k8 = (gi & 7) << 3;
            bf16x8 v = (bf16x8){0,0,0,0,0,0,0,0};
            if (m0 + r < M)
                v = *(const bf16x8*)(Ab + (size_t)(m0 + r) * NN_HF + kc + k8);
            *reinterpret_cast<bf16x8*>(&Ah[r][k8]) = v;
        }
        #pragma unroll
        for (int i = 0; i < 2; ++i) {
            int gi = tid + i * 256;
            if (gi < 384) {
                int r = gi >> 3;
                int k8 = (gi & 7) << 3;
                *reinterpret_cast<bf16x8*>(&Bh[r][k8]) =
                    *(const bf16x8*)(W2T + (size_t)r * NN_HF + kc + k8);
            }
        }
        __syncthreads();
        #pragma unroll
        for (int ks = 0; ks < 2; ++ks) {
            const int kb = (ks << 5) + (lg << 3);
            bf16x8 fa[2], fb[3];
            #pragma unroll
            for (int mi = 0; mi < 2; ++mi) {
                int r = (wave << 5) + (mi << 4) + lr;
                fa[mi] = *reinterpret_cast<const bf16x8*>(&Ah[r][kb]);
            }
            #pragma unroll
            for (int ni = 0; ni < 3; ++ni) {
                int c = (ni << 4) + lr;
                fb[ni] = *reinterpret_cast<const bf16x8*>(&Bh[c][kb]);
            }
            #pragma unroll
            for (int mi = 0; mi < 2; ++mi)
                #pragma unroll
                for (int ni = 0; ni < 3; ++ni)
                    acc[mi][ni] = __builtin_amdgcn_mfma_f32_16x16x32_bf16(
                        fa[mi], fb[ni], acc[mi][ni], 0, 0, 0);
        }
        __syncthreads();
    }

    float asv[3], adv[3];
    #pragma unroll
    for (int ni = 0; ni < 3; ++ni) {
        int c = (ni << 4) + lr;
        asv[ni] = (c < NN_C) ? att_s[c] : 0.f;
        adv[ni] = (c < NN_C) ? att_d[c] : 0.f;
    }
    #pragma unroll
    for (int mi = 0; mi < 2; ++mi) {
        float ps[4] = {0.f,0.f,0.f,0.f}, pd[4] = {0.f,0.f,0.f,0.f};
        #pragma unroll
        for (int ni = 0; ni < 3; ++ni) {
            int c = (ni << 4) + lr;
            #pragma unroll
            for (int r = 0; r < 4; ++r) {
                float v = acc[mi][ni][r];
                ps[r] = fmaf(v, asv[ni], ps[r]);
                pd[r] = fmaf(v, adv[ni], pd[r]);
                int row = m0 + (wave << 5) + (mi << 4) + (lg << 2) + r;
                if (c < NN_C && row < M)
                    h2[(size_t)row * NN_C + c] = v;
            }
        }
        #pragma unroll
        for (int off = 1; off < 16; off <<= 1) {
            #pragma unroll
            for (int r = 0; r < 4; ++r) {
                ps[r] += __shfl_xor(ps[r], off);
                pd[r] += __shfl_xor(pd[r], off);
            }
        }
        if (lr == 0) {
            #pragma unroll
            for (int r = 0; r < 4; ++r) {
                int row = m0 + (wave << 5) + (mi << 4) + (lg << 2) + r;
                if (row < M) { a2s[row] = ps[r]; a2d[row] = pd[r]; }
            }
        }
    }
}

// ---------------- layer-2 FUSED softmax+aggregate (max-free) + log_softmax ----
__global__ __launch_bounds__(256) void agg2_kernel(
    const float* __restrict__ h2, const float* __restrict__ a2s,
    const float* __restrict__ a2d, const int* __restrict__ offs,
    const int* __restrict__ srcs, const float* __restrict__ b2,
    float* __restrict__ out, int Nn)
{
    int n = blockIdx.x * 4 + (threadIdx.x >> 6);
    if (n >= Nn) return;
    int f = threadIdx.x & 63;
    int beg = offs[n], end = offs[n + 1];
    float adn = a2d[n];

    // ---- pass 1: max-free exp-sum ----
    float s = 0.f;
    for (int k = beg + f; k < end; k += 64) {
        float e = a2s[srcs[k]] + adn;
        e = e > 0.f ? e : 0.2f * e;
        s += __expf(e);
    }
    #pragma unroll
    for (int off = 1; off < 64; off <<= 1) s += __shfl_xor(s, off);
    float inv = 1.f / (s + 1e-16f);

    // ---- pass 2: weighted gather + bias + log_softmax ----
    float a0 = 0.f, a1 = 0.f, a2 = 0.f, a3 = 0.f;
    int k = beg;
    for (; k + 3 < end; k += 4) {
        int s0 = srcs[k], s1 = srcs[k+1], s2 = srcs[k+2], s3 = srcs[k+3];
        float e0 = a2s[s0] + adn, e1 = a2s[s1] + adn;
        float e2 = a2s[s2] + adn, e3 = a2s[s3] + adn;
        e0 = e0 > 0.f ? e0 : 0.2f * e0;  e1 = e1 > 0.f ? e1 : 0.2f * e1;
        e2 = e2 > 0.f ? e2 : 0.2f * e2;  e3 = e3 > 0.f ? e3 : 0.2f * e3;
        float w0 = __expf(e0) * inv, w1 = __expf(e1) * inv;
        float w2 = __expf(e2) * inv, w3 = __expf(e3) * inv;
        float h0 = (f < NN_C) ? h2[(size_t)s0 * NN_C + f] : 0.f;
        float h1 = (f < NN_C) ? h2[(size_t)s1 * NN_C + f] : 0.f;
        float h2v = (f < NN_C) ? h2[(size_t)s2 * NN_C + f] : 0.f;
        float h3 = (f < NN_C) ? h2[(size_t)s3 * NN_C + f] : 0.f;
        a0 = fmaf(w0, h0, a0); a1 = fmaf(w1, h1, a1);
        a2 = fmaf(w2, h2v, a2); a3 = fmaf(w3, h3, a3);
    }
    for (; k < end; ++k) {
        int s0 = srcs[k];
        float e0 = a2s[s0] + adn;
        e0 = e0 > 0.f ? e0 : 0.2f * e0;
        float w0 = __expf(e0) * inv;
        float h0 = (f < NN_C) ? h2[(size_t)s0 * NN_C + f] : 0.f;
        a0 = fmaf(w0, h0, a0);
    }
    float acc = (a0 + a1) + (a2 + a3);
    float v = acc + ((f < NN_C) ? b2[f] : 0.f);
    float lg = (f < NN_C) ? v : -INFINITY;
    float mx = lg;
    #pragma unroll
    for (int off = 32; off >= 1; off >>= 1) mx = fmaxf(mx, __shfl_xor(mx, off));
    float w2e = (f < NN_C) ? __expf(lg - mx) : 0.f;
    float sum = w2e;
    #pragma unroll
    for (int off = 32; off >= 1; off >>= 1) sum += __shfl_xor(sum, off);
    if (f < NN_C) out[(size_t)n * NN_C + f] = lg - mx - __logf(sum);
}

// ---------------- launcher ----------------
extern "C" void kernel_launch(void* const* d_in, const int* in_sizes, int n_in,
                              void* d_out, int out_size, void* d_ws, size_t ws_size,
                              hipStream_t stream)
{
    const float* x    = (const float*)d_in[0];
    const int*   ei   = (const int*)d_in[1];
    const float* W1   = (const float*)d_in[2];
    const float* as1  = (const float*)d_in[3];
    const float* ad1  = (const float*)d_in[4];
    const float* b1   = (const float*)d_in[5];
    const float* W2   = (const float*)d_in[6];
    const float* as2  = (const float*)d_in[7];
    const float* ad2  = (const float*)d_in[8];
    const float* b2   = (const float*)d_in[9];
    float* out = (float*)d_out;

    int Nn = in_sizes[0] / NN_DIN;      // 50000
    int E  = in_sizes[1] / 2;           // 800000
    int Et = E + Nn;
    const int* srcIdx = ei;
    const int* dstIdx = ei + E;

    char* ws = (char*)d_ws;
    size_t off = 0;
    auto alloc = [&](size_t bytes) {
        void* p = ws + off;
        off = (off + bytes + 255) & ~(size_t)255;
        return p;
    };
    unsigned short* h1b  = (unsigned short*)alloc((size_t)Nn * NN_HF * 2);
    unsigned short* W1T  = (unsigned short*)alloc((size_t)NN_HF * NN_DIN * 2);
    unsigned short* W2T  = (unsigned short*)alloc((size_t)48 * NN_HF * 2);
    unsigned short* hp1b = (unsigned short*)alloc((size_t)Nn * NN_HF * 2);
    float* a1s  = (float*)alloc((size_t)Nn * NN_H * 4);
    float* a1d  = (float*)alloc((size_t)Nn * NN_H * 4);
    float* h2   = (float*)alloc((size_t)Nn * NN_C * 4);
    float* a2s  = (float*)alloc((size_t)Nn * 4);
    float* a2d  = (float*)alloc((size_t)Nn * 4);
    int*   deg  = (int*)alloc((size_t)Nn * 4);
    int*   offs = (int*)alloc((size_t)(Nn + 1) * 4);
    int*   bsums= (int*)alloc(1024 * 4);
    int*   curs = (int*)alloc((size_t)Nn * 4);
    int*   srcs = (int*)alloc((size_t)Et * 4);

    hipMemsetAsync(deg, 0, (size_t)Nn * 4, stream);
    hipMemsetAsync(curs, 0, (size_t)Nn * 4, stream);

    // weight prep
    w1rne_kernel<<<dim3(NN_DIN / 32, NN_HF / 32), 256, 0, stream>>>(W1, W1T);
    w2rne_kernel<<<48, 256, 0, stream>>>(W2, W2T);

    // GEMM1 (MFMA, x read once, fused a1s/a1d) -> h1b
    gemm1_kernel<<<(Nn + G1_BM - 1) / G1_BM, 256, 0, stream>>>(
        x, W1T, as1, ad1, h1b, a1s, a1d, Nn);

    // CSR build
    count_kernel<<<(Et + 255) / 256, 256, 0, stream>>>(dstIdx, deg, E, Nn);
    int nb = (Nn + SCAN_CHUNK - 1) / SCAN_CHUNK;
    scan1_kernel<<<nb, 256, 0, stream>>>(deg, offs, bsums, Nn);
    scan2_kernel<<<1, 64, 0, stream>>>(bsums, nb);
    scan3_kernel<<<(Nn + 255) / 256, 256, 0, stream>>>(offs, bsums, Nn, Et);
    fill_kernel<<<(Et + 255) / 256, 256, 0, stream>>>(srcIdx, dstIdx, offs, curs, srcs, E, Nn);

    // layer-1 fused softmax + aggregate (+bias+ELU) -> bf16
    agg1_kernel<<<(Nn + 3) / 4, 256, 0, stream>>>(h1b, a1s, a1d, offs, srcs, b1, hp1b, Nn);

    // GEMM2 (MFMA, fused a2s/a2d)
    gemm2_kernel<<<(Nn + G2_BM - 1) / G2_BM, 256, 0, stream>>>(
        hp1b, W2T, as2, ad2, h2, a2s, a2d, Nn);

    // layer-2 fused softmax + aggregate + bias + log_softmax
    agg2_kernel<<<(Nn + 3) / 4, 256, 0, stream>>>(h2, a2s, a2d, offs, srcs, b2, out, Nn);
}